// Round 10
// baseline (424.901 us; speedup 1.0000x reference)
//
#include <hip/hip_runtime.h>
#include <cstddef>

// Problem constants (fixed by setup_inputs)
#define NN   20000     // nodes
#define FEAT 128
#define NH   8         // heads layer 1
#define NE   200000    // edges
#define EE   220000    // edges + self loops

typedef _Float16 f16;
typedef _Float16 f16x2 __attribute__((ext_vector_type(2)));
typedef _Float16 f16x4 __attribute__((ext_vector_type(4)));
typedef _Float16 f16x8 __attribute__((ext_vector_type(8)));
typedef float    f32x4 __attribute__((ext_vector_type(4)));

__device__ __forceinline__ float lrelu(float a) { return a > 0.f ? a : 0.2f * a; }
__device__ __forceinline__ float rdlane(float v, int l) {
  return __int_as_float(__builtin_amdgcn_readlane(__float_as_int(v), l));
}
// async global->LDS, 16B per lane; LDS dest = wave-uniform base + lane*16
__device__ __forceinline__ void gld_lds16(const f16* g, f16* l) {
  __builtin_amdgcn_global_load_lds(
      (const __attribute__((address_space(1))) void*)g,
      (__attribute__((address_space(3))) void*)l, 16, 0, 0);
}

// ================= preamble: ALL input-only precompute in one launch =================
// Ordered longest-latency-first so small late sections hide under the bulk:
// [0,QB0) gemm3in1 | [QB0,QB1) small_vec | [QB1,QB2) Wc2t | [QB2,QB3) W1t |
// [QB3,QB4) maxpool+count_deg (fused edge pass) | [QB4,QB5) xph cvt x8
#define QB0 128
#define QB1 (QB0 + 8)
#define QB2 (QB1 + 80)
#define QB3 (QB2 + 64)
#define QB4 (QB3 + 782)
#define QB5 (QB4 + 1250)
__global__ __launch_bounds__(256) void preamble(
    const int* __restrict__ ei, const float* __restrict__ syn,
    const float* __restrict__ W1, const float* __restrict__ xparam,
    const float* __restrict__ W2, const float* __restrict__ We2,
    const float* __restrict__ Wc1, const float* __restrict__ Wc2,
    const float* __restrict__ b2, const float* __restrict__ be2,
    const float* __restrict__ as2, const float* __restrict__ ad2,
    int* __restrict__ dL, int* __restrict__ dR,
    float* __restrict__ xp, f16* __restrict__ W1t, f16* __restrict__ xph,
    f16* __restrict__ WzAt, f16* __restrict__ McatT, f16* __restrict__ Wc2t,
    float* __restrict__ vB, float* __restrict__ vL, float* __restrict__ vR,
    float* __restrict__ ws2, float* __restrict__ wd2)
{
  __shared__ float smem[2112];
  const int b = blockIdx.x, t = threadIdx.x;
  if (b < QB0) {                                   // ---- gemm3in1 (folded weights) ----
    float (*As)[68] = (float(*)[68])smem;
    float (*Bs)[64] = (float(*)[64])(smem + 16 * 68);
    const int bb = b;
    const float* A; const float* B; f16* dst; int dstOff, m0, n0;
    if (bb < 64)      { A = W2;  B = Wc1;  dst = WzAt;  dstOff = 0;
                        m0 = (bb >> 3) * 64; n0 = (bb & 7) * 64; }
    else if (bb < 96) { int i = bb - 64; A = We2; B = Wc1 + (size_t)512 * 512;
                        dst = McatT; dstOff = 0;
                        m0 = (i >> 3) * 64; n0 = (i & 7) * 64; }
    else              { int i = bb - 96; A = We2; B = Wc1 + (size_t)1024 * 512;
                        dst = McatT; dstOff = 256;
                        m0 = (i >> 3) * 64; n0 = (i & 7) * 64; }
    const int tx = t & 15, ty = t >> 4;
    float acc[4][4] = {{0.f}};
    float pa[4], pb[4];
#pragma unroll
    for (int i = 0; i < 4; i++) {
      int idx = t + i * 256;
      pa[i] = A[(size_t)(m0 + (idx >> 4)) * 512 + (idx & 15)];
      pb[i] = B[(size_t)(idx >> 6) * 512 + n0 + (idx & 63)];
    }
    for (int k0 = 0; k0 < 512; k0 += 16) {
#pragma unroll
      for (int i = 0; i < 4; i++) {
        int idx = t + i * 256;
        As[idx & 15][idx >> 4] = pa[i];
        Bs[idx >> 6][idx & 63] = pb[i];
      }
      __syncthreads();
      if (k0 + 16 < 512) {
        int kn = k0 + 16;
#pragma unroll
        for (int i = 0; i < 4; i++) {
          int idx = t + i * 256;
          pa[i] = A[(size_t)(m0 + (idx >> 4)) * 512 + kn + (idx & 15)];
          pb[i] = B[(size_t)(kn + (idx >> 6)) * 512 + n0 + (idx & 63)];
        }
      }
#pragma unroll
      for (int kk = 0; kk < 16; kk++) {
        float4 a4 = *(const float4*)&As[kk][ty * 4];
        float4 b4 = *(const float4*)&Bs[kk][tx * 4];
        float av[4] = {a4.x, a4.y, a4.z, a4.w};
        float bv[4] = {b4.x, b4.y, b4.z, b4.w};
#pragma unroll
        for (int i = 0; i < 4; i++)
#pragma unroll
          for (int j = 0; j < 4; j++) acc[i][j] = fmaf(av[i], bv[j], acc[i][j]);
      }
      __syncthreads();
    }
#pragma unroll
    for (int i = 0; i < 4; i++)
#pragma unroll
      for (int j = 0; j < 4; j++)
        dst[(size_t)(n0 + tx * 4 + j) * 512 + dstOff + m0 + ty * 4 + i] = (f16)acc[i][j];
  } else if (b < QB1) {                            // ---- small_vec (4 segs) ----
    int g = (b - QB0) * 256 + t;
    int seg = g >> 9, j = g & 511;
    if (seg == 0) {
      float a = 0.f;
      for (int k = 0; k < 512; k++) a = fmaf(b2[k], Wc1[(size_t)k * 512 + j], a);
      vB[j] = a;
    } else if (seg == 1) {
      float a = 0.f;
      for (int k = 0; k < 512; k++) a = fmaf(be2[k], Wc1[(size_t)(512 + k) * 512 + j], a);
      vL[j] = a;
    } else if (seg == 2) {
      float a = 0.f;
      for (int k = 0; k < 512; k++) a = fmaf(be2[k], Wc1[(size_t)(1024 + k) * 512 + j], a);
      vR[j] = a;
    } else {
      float a = 0.f, c2 = 0.f;
      for (int c = 0; c < 512; c++) {
        float w = W2[(size_t)j * 512 + c];
        a = fmaf(w, as2[c], a);
        c2 = fmaf(w, ad2[c], c2);
      }
      ws2[j] = a; wd2[j] = c2;
    }
  } else if (b < QB2) {                            // ---- Wc2 transpose-cvt ----
    float (*tile)[33] = (float(*)[33])smem;
    int i0 = b - QB1;                              // 80 blocks: 5 n-tiles x 16 k-tiles
    const int n0 = (i0 % 5) * 32, k0 = (i0 / 5) * 32;
    const int tx = t & 31, ty = t >> 5;
#pragma unroll
    for (int i = 0; i < 4; i++) {
      int k = k0 + ty + i * 8, n = n0 + tx;
      tile[ty + i * 8][tx] = (n < 133) ? Wc2[(size_t)k * 133 + n] : 0.f;
    }
    __syncthreads();
#pragma unroll
    for (int i = 0; i < 4; i++) {
      int n = n0 + ty + i * 8, k = k0 + tx;
      if (n < 133) Wc2t[(size_t)n * 512 + k] = (f16)tile[tx][ty + i * 8];
    }
  } else if (b < QB3) {                            // ---- W1 transpose-cvt ----
    float (*tile)[33] = (float(*)[33])smem;
    int bb = b - QB2;
    const int n0 = (bb & 15) * 32, k0 = (bb >> 4) * 32;
    const int tx = t & 31, ty = t >> 5;
#pragma unroll
    for (int i = 0; i < 4; i++)
      tile[ty + i * 8][tx] = W1[(size_t)(k0 + ty + i * 8) * 512 + n0 + tx];
    __syncthreads();
#pragma unroll
    for (int i = 0; i < 4; i++)
      W1t[(size_t)(n0 + ty + i * 8) * 128 + k0 + tx] = (f16)tile[tx][ty + i * 8];
  } else if (b < QB4) {                            // ---- maxpool + count_deg fused ----
    int e = (b - QB3) * 256 + t;
    if (e >= NE) return;
    const float* p = syn + (size_t)e * 24;
    float v[24];
#pragma unroll
    for (int i = 0; i < 6; i++) {
      float4 q = *(const float4*)(p + i * 4);
      v[i*4+0] = q.x; v[i*4+1] = q.y; v[i*4+2] = q.z; v[i*4+3] = q.w;
    }
#pragma unroll
    for (int dd = 0; dd < 6; dd++)
      xp[(size_t)e * 6 + dd] = fmaxf(fmaxf(v[dd], v[6 + dd]), fmaxf(v[12 + dd], v[18 + dd]));
    atomicAdd(&dL[ei[e]], 1);
    atomicAdd(&dR[ei[NE + e]], 1);
  } else {                                         // ---- xph cvt, 8 elem/thread ----
    int idx = ((b - QB4) * 256 + t) * 8;           // NN*FEAT = 2,560,000 = 1250*2048
    float4 q0 = *(const float4*)(xparam + idx);
    float4 q1 = *(const float4*)(xparam + idx + 4);
    f16x8 o;
    o[0] = (f16)q0.x; o[1] = (f16)q0.y; o[2] = (f16)q0.z; o[3] = (f16)q0.w;
    o[4] = (f16)q1.x; o[5] = (f16)q1.y; o[6] = (f16)q1.z; o[7] = (f16)q1.w;
    *(f16x8*)(xph + idx) = o;
  }
}

// ================= fused1: xl1 MFMA-GEMM (blocks<1252) + h1 readlane gather ==========
__global__ __launch_bounds__(256) void fused1(
    const f16* __restrict__ xph, const f16* __restrict__ W1t, f16* __restrict__ xl1h,
    const float* __restrict__ xp, const float* __restrict__ We1,
    const float* __restrict__ be1,
    const int* __restrict__ oL, const int* __restrict__ eL,
    const int* __restrict__ oR, const int* __restrict__ eR,
    f16* __restrict__ hlrh)
{
  __shared__ __align__(16) f16 smem[7680];
  const int t = threadIdx.x;
  if (blockIdx.x < 1252) {
    f16 (*As)[40] = (f16(*)[40])smem;
    f16 (*Bs)[40] = (f16(*)[40])(smem + 64 * 40);
    const int wave = t >> 6, lane = t & 63;
    const int quad = lane >> 4, mrow = lane & 15;
    const int m0 = (blockIdx.x >> 2) * 64, n0 = (blockIdx.x & 3) * 128;
    f32x4 acc[4][2];
    f32x4 zero4 = {0.f, 0.f, 0.f, 0.f};
#pragma unroll
    for (int i = 0; i < 4; i++)
#pragma unroll
      for (int j = 0; j < 2; j++) acc[i][j] = zero4;
    const int ar = t >> 2, ac = (t & 3) * 8;
    for (int k0 = 0; k0 < FEAT; k0 += 32) {
      {
        int gm = m0 + ar;
        f16x8 v = {0, 0, 0, 0, 0, 0, 0, 0};
        if (gm < NN) v = *(const f16x8*)(xph + (size_t)gm * FEAT + k0 + ac);
        *(f16x8*)&As[ar][ac] = v;
      }
#pragma unroll
      for (int i = 0; i < 2; i++) {
        int idx = t + i * 256;
        int r = idx >> 2, c = (idx & 3) * 8;
        *(f16x8*)&Bs[r][c] = *(const f16x8*)(W1t + (size_t)(n0 + r) * FEAT + k0 + c);
      }
      __syncthreads();
      f16x8 af[4], bf[2];
#pragma unroll
      for (int mt = 0; mt < 4; mt++) af[mt] = *(const f16x8*)&As[mt * 16 + mrow][quad * 8];
#pragma unroll
      for (int nt = 0; nt < 2; nt++) bf[nt] = *(const f16x8*)&Bs[wave * 32 + nt * 16 + mrow][quad * 8];
#pragma unroll
      for (int mt = 0; mt < 4; mt++)
#pragma unroll
        for (int nt = 0; nt < 2; nt++)
          acc[mt][nt] = __builtin_amdgcn_mfma_f32_16x16x32_f16(af[mt], bf[nt], acc[mt][nt], 0, 0, 0);
      __syncthreads();
    }
#pragma unroll
    for (int mt = 0; mt < 4; mt++)
#pragma unroll
      for (int nt = 0; nt < 2; nt++) {
        int col = n0 + wave * 32 + nt * 16 + mrow;
#pragma unroll
        for (int reg = 0; reg < 4; reg++) {
          int row = m0 + mt * 16 + quad * 4 + reg;
          if (row < NN) xl1h[(size_t)row * 512 + col] = (f16)acc[mt][nt][reg];
        }
      }
  } else {
    // ---- h1 mean-gather: readlane broadcast, 4 node-sides per wave ----
    const int wave = t >> 6, lane = t & 63;
    const int w = (blockIdx.x - 1252) * 4 + wave;        // 0..9999
    float4 wv[6];
#pragma unroll
    for (int j = 0; j < 6; j++) wv[j] = *(const float4*)(We1 + j * 256 + 4 * lane);
    const float4 bv = *(const float4*)(be1 + 4 * lane);
#pragma unroll 1
    for (int i = 0; i < 4; i++) {
      const int b = w + i * 10000;                       // node-side in [0, 2*NN)
      const int* off; const int* lst; int n;
      if (b < NN) { off = oL; lst = eL; n = b; } else { off = oR; lst = eR; n = b - NN; }
      const int beg = off[n], deg = off[n + 1] - beg;
      float a0 = 0.f, a1 = 0.f, a2 = 0.f, a3 = 0.f;
      for (int base = 0; base < deg; base += 32) {
        const int m = min(32, deg - base);
        float x0 = 0.f, x1 = 0.f, x2 = 0.f, x3 = 0.f, x4 = 0.f, x5 = 0.f;
        if (lane < m) {
          const int e = lst[beg + base + lane];
          const float* pr = xp + (size_t)e * 6;
          float2 p0 = *(const float2*)pr;
          float2 p1 = *(const float2*)(pr + 2);
          float2 p2 = *(const float2*)(pr + 4);
          x0 = p0.x; x1 = p0.y; x2 = p1.x; x3 = p1.y; x4 = p2.x; x5 = p2.y;
        }
        const int ms = __builtin_amdgcn_readfirstlane(m);
        for (int s = 0; s < ms; s++) {
          const float f0 = rdlane(x0, s), f1 = rdlane(x1, s), f2 = rdlane(x2, s);
          const float f3 = rdlane(x3, s), f4 = rdlane(x4, s), f5 = rdlane(x5, s);
          float v0 = bv.x, v1 = bv.y, v2 = bv.z, v3 = bv.w;
          v0 = fmaf(f0, wv[0].x, v0); v1 = fmaf(f0, wv[0].y, v1);
          v2 = fmaf(f0, wv[0].z, v2); v3 = fmaf(f0, wv[0].w, v3);
          v0 = fmaf(f1, wv[1].x, v0); v1 = fmaf(f1, wv[1].y, v1);
          v2 = fmaf(f1, wv[1].z, v2); v3 = fmaf(f1, wv[1].w, v3);
          v0 = fmaf(f2, wv[2].x, v0); v1 = fmaf(f2, wv[2].y, v1);
          v2 = fmaf(f2, wv[2].z, v2); v3 = fmaf(f2, wv[2].w, v3);
          v0 = fmaf(f3, wv[3].x, v0); v1 = fmaf(f3, wv[3].y, v1);
          v2 = fmaf(f3, wv[3].z, v2); v3 = fmaf(f3, wv[3].w, v3);
          v0 = fmaf(f4, wv[4].x, v0); v1 = fmaf(f4, wv[4].y, v1);
          v2 = fmaf(f4, wv[4].z, v2); v3 = fmaf(f4, wv[4].w, v3);
          v0 = fmaf(f5, wv[5].x, v0); v1 = fmaf(f5, wv[5].y, v1);
          v2 = fmaf(f5, wv[5].z, v2); v3 = fmaf(f5, wv[5].w, v3);
          a0 += fmaxf(v0, 0.f); a1 += fmaxf(v1, 0.f);
          a2 += fmaxf(v2, 0.f); a3 += fmaxf(v3, 0.f);
        }
      }
      const float rn = deg > 0 ? 1.f / (float)deg : 0.f;
      f16x4 o;
      o[0] = (f16)(a0 * rn); o[1] = (f16)(a1 * rn);
      o[2] = (f16)(a2 * rn); o[3] = (f16)(a3 * rn);
      *(f16x4*)(hlrh + (size_t)b * 256 + 4 * lane) = o;
    }
  }
}

// ================= fused2: z-GEMM + class_pre, BK=64 + dbuf prefetch ================
// 128x128 tile, BK=64, TWO 32KB LDS buffers (64KB). 2-phase schedule (guide T3
// minimum recipe): per K-step, issue next tile's global_load_lds into the OTHER
// buffer FIRST, then ds_read+MFMA the current buffer, then one vmcnt(0)+barrier
// (from __syncthreads) -- the staged loads' latency hides under the ~350cy of
// ds_read+MFMA instead of being fully exposed. st-swizzle retained (source chunk
// cs = (l&7)^((l>>3)&7), read chunk (ksub*4+quad)^(mrow&7)): bank-conflict-free.
// 2x2 waves, acc[4][4]; bijective XCD swizzle (1256 = 8*157); A-rows >= NN read
// workspace garbage and are never stored.
__global__ __launch_bounds__(256) void fused2(
    const f16* __restrict__ x1h, const f16* __restrict__ WzAt, f16* __restrict__ zh,
    const f16* __restrict__ hlrh, const f16* __restrict__ McatT,
    const int* __restrict__ degL, const int* __restrict__ degR,
    const float* __restrict__ bc1, const float* __restrict__ vB,
    const float* __restrict__ vL, const float* __restrict__ vR, f16* __restrict__ Ph)
{
  __shared__ __align__(16) f16 smem[32768];        // 2 x (As 8192 f16 | Bs 8192 f16)
  const int t = threadIdx.x;
  const int logical = (blockIdx.x & 7) * 157 + (blockIdx.x >> 3);
  const bool isZ = logical < 628;
  const int bb = isZ ? logical : logical - 628;
  const int wave = t >> 6, lane = t & 63;
  const int wr = wave >> 1, wc = wave & 1;
  const int quad = lane >> 4, mrow = lane & 15;
  const int m0 = (bb >> 2) * 128, n0 = (bb & 3) * 128;
  const f16* Bt = isZ ? WzAt : McatT;
  const int srow = wave * 8 + (lane >> 3);           // 0..31 within issue block
  const int cs = (lane & 7) ^ ((lane >> 3) & 7);     // swizzled source chunk
  const int mswz = mrow & 7;                         // read-side XOR key

  f32x4 acc[4][4];
  f32x4 zero4 = {0.f, 0.f, 0.f, 0.f};
#pragma unroll
  for (int i = 0; i < 4; i++)
#pragma unroll
    for (int j = 0; j < 4; j++) acc[i][j] = zero4;

  auto STAGE = [&](int buf, int it) {
    const int k0 = it * 64;
    f16* bA = smem + buf * 16384 + wave * 512;
    f16* bB = smem + buf * 16384 + 8192 + wave * 512;
#pragma unroll
    for (int i = 0; i < 4; i++) {
      const int garow = m0 + i * 32 + srow;
      const f16* gA;
      if (isZ) {
        gA = x1h + (size_t)garow * 512 + k0 + cs * 8;
      } else {
        const int roff = (k0 >> 8) ? NN : 0;         // K half selects L/R hlrh bank
        gA = hlrh + (size_t)(garow + roff) * 256 + (k0 & 255) + cs * 8;
      }
      gld_lds16(gA, bA + i * 2048);
      const f16* gB = Bt + (size_t)(n0 + i * 32 + srow) * 512 + k0 + cs * 8;
      gld_lds16(gB, bB + i * 2048);
    }
  };

  STAGE(0, 0);
  __syncthreads();                                   // drain prologue loads
#pragma unroll 1
  for (int it = 0; it < 8; ++it) {
    const int cur = it & 1;
    if (it < 7) STAGE(cur ^ 1, it + 1);              // issue next-tile loads FIRST
    const f16* bufA = smem + cur * 16384;
    const f16* bufB = bufA + 8192;
#pragma unroll
    for (int ksub = 0; ksub < 2; ++ksub) {
      f16x8 af[4], bf[4];
#pragma unroll
      for (int mt = 0; mt < 4; mt++)
        af[mt] = *(const f16x8*)(bufA + (wr * 64 + mt * 16 + mrow) * 64 +
                                 ((ksub * 4 + quad) ^ mswz) * 8);
#pragma unroll
      for (int nt = 0; nt < 4; nt++)
        bf[nt] = *(const f16x8*)(bufB + (wc * 64 + nt * 16 + mrow) * 64 +
                                 ((ksub * 4 + quad) ^ mswz) * 8);
#pragma unroll
      for (int mt = 0; mt < 4; mt++)
#pragma unroll
        for (int nt = 0; nt < 4; nt++)
          acc[mt][nt] = __builtin_amdgcn_mfma_f32_16x16x32_f16(af[mt], bf[nt], acc[mt][nt], 0, 0, 0);
    }
    __syncthreads();                                 // one vmcnt(0)+barrier per step
  }
  if (isZ) {
#pragma unroll
    for (int mt = 0; mt < 4; mt++)
#pragma unroll
      for (int nt = 0; nt < 4; nt++) {
        int col = n0 + wc * 64 + nt * 16 + mrow;
#pragma unroll
        for (int reg = 0; reg < 4; reg++) {
          int row = m0 + wr * 64 + mt * 16 + quad * 4 + reg;
          if (row < NN) zh[(size_t)row * 512 + col] = (f16)acc[mt][nt][reg];
        }
      }
  } else {
#pragma unroll
    for (int mt = 0; mt < 4; mt++)
#pragma unroll
      for (int nt = 0; nt < 4; nt++) {
        int col = n0 + wc * 64 + nt * 16 + mrow;
        float bb2 = bc1[col] + vB[col];
        float vl = vL[col], vr = vR[col];
#pragma unroll
        for (int reg = 0; reg < 4; reg++) {
          int row = m0 + wr * 64 + mt * 16 + quad * 4 + reg;
          if (row >= NN) continue;
          float v = acc[mt][nt][reg] + bb2;
          if (degL[row] > 0) v += vl;
          if (degR[row] > 0) v += vr;
          Ph[(size_t)row * 512 + col] = (f16)v;
        }
      }
  }
}

// ---------------- MFMA output GEMM: out(f32)[M,133] = h2h @ Wc2t^T + bc2 -------------
__global__ __launch_bounds__(256) void mfma_out(
    const f16* __restrict__ A, const f16* __restrict__ Bt,
    const float* __restrict__ bias, float* __restrict__ C, int M)
{
  __shared__ __align__(16) f16 As[64][40];
  __shared__ __align__(16) f16 Bs[128][40];
  const int t = threadIdx.x;
  const int wave = t >> 6, lane = t & 63;
  const int quad = lane >> 4, mrow = lane & 15;
  const int m0 = blockIdx.y * 64, n0 = blockIdx.x * 128;
  f32x4 acc[4][2];
  f32x4 zero4 = {0.f, 0.f, 0.f, 0.f};
#pragma unroll
  for (int i = 0; i < 4; i++)
#pragma unroll
    for (int j = 0; j < 2; j++) acc[i][j] = zero4;
  const int ar = t >> 2, ac = (t & 3) * 8;
  for (int k0 = 0; k0 < 512; k0 += 32) {
    {
      int gm = m0 + ar;
      f16x8 v = {0, 0, 0, 0, 0, 0, 0, 0};
      if (gm < M) v = *(const f16x8*)(A + (size_t)gm * 512 + k0 + ac);
      *(f16x8*)&As[ar][ac] = v;
    }
#pragma unroll
    for (int i = 0; i < 2; i++) {
      int idx = t + i * 256;
      int r = idx >> 2, c = (idx & 3) * 8;
      f16x8 v = {0, 0, 0, 0, 0, 0, 0, 0};
      if (n0 + r < 133) v = *(const f16x8*)(Bt + (size_t)(n0 + r) * 512 + k0 + c);
      *(f16x8*)&Bs[r][c] = v;
    }
    __syncthreads();
    f16x8 af[4], bf[2];
#pragma unroll
    for (int mt = 0; mt < 4; mt++) af[mt] = *(const f16x8*)&As[mt * 16 + mrow][quad * 8];
#pragma unroll
    for (int nt = 0; nt < 2; nt++) bf[nt] = *(const f16x8*)&Bs[wave * 32 + nt * 16 + mrow][quad * 8];
#pragma unroll
    for (int mt = 0; mt < 4; mt++)
#pragma unroll
      for (int nt = 0; nt < 2; nt++)
        acc[mt][nt] = __builtin_amdgcn_mfma_f32_16x16x32_f16(af[mt], bf[nt], acc[mt][nt], 0, 0, 0);
    __syncthreads();
  }
#pragma unroll
  for (int mt = 0; mt < 4; mt++)
#pragma unroll
    for (int nt = 0; nt < 2; nt++) {
      int col = n0 + wave * 32 + nt * 16 + mrow;
      if (col >= 133) continue;
      float bb = bias[col];
#pragma unroll
      for (int reg = 0; reg < 4; reg++) {
        int row = m0 + mt * 16 + quad * 4 + reg;
        if (row < M) C[(size_t)row * 133 + col] = acc[mt][nt][reg] + bb;
      }
    }
}

// ------------- CSR scan (2 blocks; offA derived as offR + n) -------------------------
__global__ __launch_bounds__(1024) void scan_csr(
    const int* __restrict__ dL, const int* __restrict__ dR,
    int* __restrict__ oL, int* __restrict__ oR, int* __restrict__ oA)
{
  const int b = blockIdx.x;
  const int* deg = b == 0 ? dL : dR;
  __shared__ int part[1024];
  const int t = threadIdx.x;
  const int chunk = 20;
  int base = t * chunk;
  int sum = 0;
  for (int i = 0; i < chunk; i++) { int idx = base + i; if (idx < NN) sum += deg[idx]; }
  part[t] = sum;
  __syncthreads();
  for (int o = 1; o < 1024; o <<= 1) {
    int v = (t >= o) ? part[t - o] : 0;
    __syncthreads();
    part[t] += v;
    __syncthreads();
  }
  int run = part[t] - sum;
  if (b == 0) {
    for (int i = 0; i < chunk; i++) {
      int idx = base + i;
      if (idx < NN) { oL[idx] = run; run += deg[idx]; }
    }
    if (t == 0) oL[NN] = part[1023];
  } else {
    for (int i = 0; i < chunk; i++) {
      int idx = base + i;
      if (idx < NN) { oR[idx] = run; oA[idx] = run + idx; run += deg[idx]; }
    }
    if (t == 0) { oR[NN] = part[1023]; oA[NN] = part[1023] + NN; }
  }
}

// ------------- fill: 2 atomics/edge; self-loops atomic-free (slot 0 of A-segment) ----
__global__ __launch_bounds__(256) void fill_csr(
    const int* __restrict__ ei,
    const int* __restrict__ oL, const int* __restrict__ oR, const int* __restrict__ oA,
    int* __restrict__ cL, int* __restrict__ cR,
    int* __restrict__ eL, int* __restrict__ eR, int* __restrict__ snA)
{
  int e = blockIdx.x * 256 + threadIdx.x;
  if (e >= EE) return;
  if (e < NE) {
    int s = ei[e], d = ei[NE + e];
    int p = atomicAdd(&cL[s], 1); eL[oL[s] + p] = e;
    p = atomicAdd(&cR[d], 1);
    eR[oR[d] + p] = e;
    snA[oA[d] + 1 + p] = s;       // A-segment: [selfloop, dst-edges...]
  } else {
    int n = e - NE;
    snA[oA[n]] = n;
  }
}

// ------------- attention dot products, layer 1 ---------------------------------------
__global__ __launch_bounds__(256) void attn_dots1(
    const f16* __restrict__ xlh, const float* __restrict__ asrc,
    const float* __restrict__ adst, float* __restrict__ s, float* __restrict__ d)
{
  int gid = blockIdx.x * 256 + threadIdx.x;       // n*8 + h
  if (gid >= NN * NH) return;
  int n = gid >> 3, h = gid & 7;
  const f16x2* row = (const f16x2*)(xlh + (size_t)n * 512 + h * 64);
  const float* a1 = asrc + h * 64;
  const float* a2 = adst + h * 64;
  float ss = 0.f, dd = 0.f;
#pragma unroll 8
  for (int j = 0; j < 32; j++) {
    f16x2 p = row[j];
    float v0 = (float)p[0], v1 = (float)p[1];
    ss += v0 * a1[2 * j] + v1 * a1[2 * j + 1];
    dd += v0 * a2[2 * j] + v1 * a2[2 * j + 1];
  }
  s[gid] = ss; d[gid] = dd;
}

// ------------- GAT layer 1 gather: WAVE-per-node, no LDS, no barriers ----------------
__global__ __launch_bounds__(256) void gat_gather1(
    const int* __restrict__ snA, const int* __restrict__ offA,
    const float* __restrict__ s1, const float* __restrict__ d1,
    const f16* __restrict__ xlh, const float* __restrict__ b1,
    const float* __restrict__ ws2, const float* __restrict__ wd2,
    f16* __restrict__ x1h, float* __restrict__ s2, float* __restrict__ d2)
{
  const int t = threadIdx.x;
  const int wave = t >> 6, lane = t & 63;
  const int n = blockIdx.x * 4 + wave;             // 20000 = 5000*4 exact
  const int hf = lane >> 3;
  const float dnw = d1[n * 8 + hf];
  const int beg = offA[n], deg = offA[n + 1] - beg;
  float acc[8] = {0.f};
  float den = 0.f;
  for (int base = 0; base < deg; base += 64) {
    const int m = min(64, deg - base);
    int me = 0;
    if (lane < m) me = snA[beg + base + lane];
    const int ms = __builtin_amdgcn_readfirstlane(m);
    int s = 0;
    for (; s + 4 <= ms; s += 4) {
      int sn[4]; float sv[4]; f16x8 row[4];
#pragma unroll
      for (int u = 0; u < 4; u++) sn[u] = __builtin_amdgcn_readlane(me, s + u);
#pragma unroll
      for (int u = 0; u < 4; u++) sv[u] = s1[sn[u] * 8 + hf];
#pragma unroll
      for (int u = 0; u < 4; u++) row[u] = *(const f16x8*)(xlh + (size_t)sn[u] * 512 + lane * 8);
#pragma unroll
      for (int u = 0; u < 4; u++) {
        float w = __expf(lrelu(sv[u] + dnw));
        den += w;
#pragma unroll
        for (int j = 0; j < 8; j++) acc[j] = fmaf(w, (float)row[u][j], acc[j]);
      }
    }
    for (; s < ms; ++s) {
      int sn = __builtin_amdgcn_readlane(me, s);
      float sv = s1[sn * 8 + hf];
      f16x8 row = *(const f16x8*)(xlh + (size_t)sn * 512 + lane * 8);
      float w = __expf(lrelu(sv + dnw));
      den += w;
#pragma unroll
      for (int j = 0; j < 8; j++) acc[j] = fmaf(w, (float)row[j], acc[j]);
    }
  }
  const float rh = 1.f / (den + 1e-16f);
  float4 bv0 = *(const float4*)(b1 + lane * 8);
  float4 bv1 = *(const float4*)(b1 + lane * 8 + 4);
  float bb[8] = {bv0.x, bv0.y, bv0.z, bv0.w, bv1.x, bv1.y, bv1.z, bv1.w};
  float4 wsa = *(const float4*)(ws2 + lane * 8);
  float4 wsb = *(const float4*)(ws2 + lane * 8 + 4);
  float4 wda = *(const float4*)(wd2 + lane * 8);
  float4 wdb = *(const float4*)(wd2 + lane * 8 + 4);
  float wsv[8] = {wsa.x, wsa.y, wsa.z, wsa.w, wsb.x, wsb.y, wsb.z, wsb.w};
  float wdv[8] = {wda.x, wda.y, wda.z, wda.w, wdb.x, wdb.y, wdb.z, wdb.w};
  f16x8 o;
  float ps = 0.f, pd = 0.f;
#pragma unroll
  for (int j = 0; j < 8; j++) {
    float v = acc[j] * rh + bb[j];
    v = v > 0.f ? v : (__expf(v) - 1.f);
    o[j] = (f16)v;
    ps = fmaf(v, wsv[j], ps);
    pd = fmaf(v, wdv[j], pd);
  }
  *(f16x8*)(x1h + (size_t)n * 512 + lane * 8) = o;
#pragma unroll
  for (int off = 32; off > 0; off >>= 1) {
    ps += __shfl_xor(ps, off);
    pd += __shfl_xor(pd, off);
  }
  if (lane == 0) { s2[n] = ps; d2[n] = pd; }
}

// ------------- GAT layer 2 gather: WAVE-per-node, no LDS, no barriers ----------------
__global__ __launch_bounds__(256) void gat_gather2(
    const int* __restrict__ snA, const int* __restrict__ offA,
    const float* __restrict__ s2, const float* __restrict__ d2,
    const f16* __restrict__ zh, const f16* __restrict__ Ph,
    f16* __restrict__ h2h)
{
  const int t = threadIdx.x;
  const int wave = t >> 6, lane = t & 63;
  const int n = blockIdx.x * 4 + wave;             // 20000 = 5000*4 exact
  const float dn = d2[n];
  const int beg = offA[n], deg = offA[n + 1] - beg;
  float acc[8] = {0.f};
  float den = 0.f;
  for (int base = 0; base < deg; base += 64) {
    const int m = min(64, deg - base);
    int me = 0;
    if (lane < m) me = snA[beg + base + lane];
    const int ms = __builtin_amdgcn_readfirstlane(m);
    int s = 0;
    for (; s + 4 <= ms; s += 4) {
      int sn[4]; float sv[4]; f16x8 row[4];
#pragma unroll
      for (int u = 0; u < 4; u++) sn[u] = __builtin_amdgcn_readlane(me, s + u);
#pragma unroll
      for (int u = 0; u < 4; u++) sv[u] = s2[sn[u]];
#pragma unroll
      for (int u = 0; u < 4; u++) row[u] = *(const f16x8*)(zh + (size_t)sn[u] * 512 + lane * 8);
#pragma unroll
      for (int u = 0; u < 4; u++) {
        float w = __expf(lrelu(sv[u] + dn));
        den += w;
#pragma unroll
        for (int j = 0; j < 8; j++) acc[j] = fmaf(w, (float)row[u][j], acc[j]);
      }
    }
    for (; s < ms; ++s) {
      int sn = __builtin_amdgcn_readlane(me, s);
      float sv = s2[sn];
      f16x8 row = *(const f16x8*)(zh + (size_t)sn * 512 + lane * 8);
      float w = __expf(lrelu(sv + dn));
      den += w;
#pragma unroll
      for (int j = 0; j < 8; j++) acc[j] = fmaf(w, (float)row[j], acc[j]);
    }
  }
  const float rn = 1.f / (den + 1e-16f);
  f16x8 pv = *(const f16x8*)(Ph + (size_t)n * 512 + lane * 8);
  f16x8 o;
#pragma unroll
  for (int j = 0; j < 8; j++) {
    float v = fmaxf(acc[j] * rn + (float)pv[j], 0.f);
    o[j] = (f16)v;
  }
  *(f16x8*)(h2h + (size_t)n * 512 + lane * 8) = o;
}

extern "C" void kernel_launch(void* const* d_in, const int* in_sizes, int n_in,
                              void* d_out, int out_size, void* d_ws, size_t ws_size,
                              hipStream_t stream) {
  const int*   edge_index = (const int*)d_in[0];
  const float* synapse    = (const float*)d_in[2];
  const float* x_param = (const float*)d_in[5];
  const float* W1      = (const float*)d_in[6];
  const float* as1     = (const float*)d_in[7];
  const float* ad1     = (const float*)d_in[8];
  const float* b1      = (const float*)d_in[9];
  const float* W2      = (const float*)d_in[10];
  const float* as2     = (const float*)d_in[11];
  const float* ad2     = (const float*)d_in[12];
  const float* b2      = (const float*)d_in[13];
  const float* We1     = (const float*)d_in[14];
  const float* be1     = (const float*)d_in[15];
  const float* We2     = (const float*)d_in[16];
  const float* be2     = (const float*)d_in[17];
  const float* Wc1     = (const float*)d_in[18];
  const float* bc1     = (const float*)d_in[19];
  const float* Wc2     = (const float*)d_in[20];
  const float* bc2     = (const float*)d_in[21];
  float* out_p = (float*)d_out;

  // ---- workspace layout (~125 MB) ----
  char* p = (char*)d_ws;
  float* xp    = (float*)p; p += (size_t)NE * 6 * 4;
  float* s1    = (float*)p; p += (size_t)NN * 8 * 4;
  float* d1    = (float*)p; p += (size_t)NN * 8 * 4;
  float* s2    = (float*)p; p += (size_t)NN * 4;
  float* d2    = (float*)p; p += (size_t)NN * 4;
  float* vB    = (float*)p; p += 512 * 4;
  float* vL    = (float*)p; p += 512 * 4;
  float* vR    = (float*)p; p += 512 * 4;
  float* ws2   = (float*)p; p += 512 * 4;
  float* wd2   = (float*)p; p += 512 * 4;
  f16* xph     = (f16*)p; p += (size_t)NN * FEAT * 2;
  f16* xl1h    = (f16*)p; p += (size_t)NN * 512 * 2;
  f16* x1h     = (f16*)p; p += (size_t)NN * 512 * 2;
  f16* zh      = (f16*)p; p += (size_t)NN * 512 * 2;
  f16* h2h     = (f16*)p; p += (size_t)NN * 512 * 2;
  f16* Phb     = (f16*)p; p += (size_t)NN * 512 * 2;
  f16* hlrh    = (f16*)p; p += (size_t)2 * NN * 256 * 2;
  f16* W1t     = (f16*)p; p += (size_t)512 * FEAT * 2;
  f16* WzAt    = (f16*)p; p += (size_t)512 * 512 * 2;
  f16* McatT   = (f16*)p; p += (size_t)512 * 512 * 2;
  f16* Wc2t    = (f16*)p; p += (size_t)133 * 512 * 2;
  int* degL    = (int*)p;                 // N  (zero group start)
  int* degR    = degL + NN;               // N
  int* curL    = degR + NN;               // N
  int* curR    = curL + NN;               // N  (zero group: 4N ints)
  int* offL    = curR + NN;               // N+1
  int* offR    = offL + NN + 1;           // N+1
  int* offA    = offR + NN + 1;           // N+1
  int* edgeL   = offA + NN + 1;           // E
  int* edgeR   = edgeL + NE;              // E
  int* snA     = edgeR + NE;              // EE

  hipMemsetAsync(degL, 0, (size_t)4 * NN * sizeof(int), stream);

  preamble<<<QB5, 256, 0, stream>>>(
      edge_index, synapse, W1, x_param, W2, We2, Wc1, Wc2, b2, be2, as2, ad2,
      degL, degR, xp, W1t, xph, WzAt, McatT, Wc2t, vB, vL, vR, ws2, wd2);
  scan_csr<<<2, 1024, 0, stream>>>(degL, degR, offL, offR, offA);
  fill_csr<<<(EE + 255) / 256, 256, 0, stream>>>(edge_index, offL, offR, offA,
                                                 curL, curR, edgeL, edgeR, snA);
  fused1<<<1252 + 2500, 256, 0, stream>>>(xph, W1t, xl1h, xp, We1, be1,
                                          offL, edgeL, offR, edgeR, hlrh);
  attn_dots1<<<(NN * NH + 255) / 256, 256, 0, stream>>>(xl1h, as1, ad1, s1, d1);
  gat_gather1<<<5000, 256, 0, stream>>>(snA, offA, s1, d1, xl1h, b1, ws2, wd2,
                                        x1h, s2, d2);
  fused2<<<1256, 256, 0, stream>>>(x1h, WzAt, zh, hlrh, McatT,
                                   degL, degR, bc1, vB, vL, vR, Phb);
  gat_gather2<<<5000, 256, 0, stream>>>(snA, offA, s2, d2, zh, Phb, h2h);
  mfma_out<<<dim3(2, 313), 256, 0, stream>>>(h2h, Wc2t, bc2, out_p, NN);
}

// Round 11
// 422.674 us; speedup vs baseline: 1.0053x; 1.0053x over previous
//
#include <hip/hip_runtime.h>
#include <cstddef>

// Problem constants (fixed by setup_inputs)
#define NN   20000     // nodes
#define FEAT 128
#define NH   8         // heads layer 1
#define NE   200000    // edges
#define EE   220000    // edges + self loops

typedef _Float16 f16;
typedef _Float16 f16x2 __attribute__((ext_vector_type(2)));
typedef _Float16 f16x4 __attribute__((ext_vector_type(4)));
typedef _Float16 f16x8 __attribute__((ext_vector_type(8)));
typedef float    f32x4 __attribute__((ext_vector_type(4)));

__device__ __forceinline__ float lrelu(float a) { return a > 0.f ? a : 0.2f * a; }
__device__ __forceinline__ float rdlane(float v, int l) {
  return __int_as_float(__builtin_amdgcn_readlane(__float_as_int(v), l));
}
// async global->LDS, 16B per lane; LDS dest = wave-uniform base + lane*16
__device__ __forceinline__ void gld_lds16(const f16* g, f16* l) {
  __builtin_amdgcn_global_load_lds(
      (const __attribute__((address_space(1))) void*)g,
      (__attribute__((address_space(3))) void*)l, 16, 0, 0);
}

// ================= preamble: ALL input-only precompute in one launch =================
// Ordered longest-latency-first so small late sections hide under the bulk:
// [0,QB0) gemm3in1 | [QB0,QB1) small_vec | [QB1,QB2) Wc2t | [QB2,QB3) W1t |
// [QB3,QB4) maxpool+count_deg (fused edge pass) | [QB4,QB5) xph cvt x8
#define QB0 128
#define QB1 (QB0 + 8)
#define QB2 (QB1 + 80)
#define QB3 (QB2 + 64)
#define QB4 (QB3 + 782)
#define QB5 (QB4 + 1250)
__global__ __launch_bounds__(256) void preamble(
    const int* __restrict__ ei, const float* __restrict__ syn,
    const float* __restrict__ W1, const float* __restrict__ xparam,
    const float* __restrict__ W2, const float* __restrict__ We2,
    const float* __restrict__ Wc1, const float* __restrict__ Wc2,
    const float* __restrict__ b2, const float* __restrict__ be2,
    const float* __restrict__ as2, const float* __restrict__ ad2,
    int* __restrict__ dL, int* __restrict__ dR,
    float* __restrict__ xp, f16* __restrict__ W1t, f16* __restrict__ xph,
    f16* __restrict__ WzAt, f16* __restrict__ McatT, f16* __restrict__ Wc2t,
    float* __restrict__ vB, float* __restrict__ vL, float* __restrict__ vR,
    float* __restrict__ ws2, float* __restrict__ wd2)
{
  __shared__ float smem[2112];
  const int b = blockIdx.x, t = threadIdx.x;
  if (b < QB0) {                                   // ---- gemm3in1 (folded weights) ----
    float (*As)[68] = (float(*)[68])smem;
    float (*Bs)[64] = (float(*)[64])(smem + 16 * 68);
    const int bb = b;
    const float* A; const float* B; f16* dst; int dstOff, m0, n0;
    if (bb < 64)      { A = W2;  B = Wc1;  dst = WzAt;  dstOff = 0;
                        m0 = (bb >> 3) * 64; n0 = (bb & 7) * 64; }
    else if (bb < 96) { int i = bb - 64; A = We2; B = Wc1 + (size_t)512 * 512;
                        dst = McatT; dstOff = 0;
                        m0 = (i >> 3) * 64; n0 = (i & 7) * 64; }
    else              { int i = bb - 96; A = We2; B = Wc1 + (size_t)1024 * 512;
                        dst = McatT; dstOff = 256;
                        m0 = (i >> 3) * 64; n0 = (i & 7) * 64; }
    const int tx = t & 15, ty = t >> 4;
    float acc[4][4] = {{0.f}};
    float pa[4], pb[4];
#pragma unroll
    for (int i = 0; i < 4; i++) {
      int idx = t + i * 256;
      pa[i] = A[(size_t)(m0 + (idx >> 4)) * 512 + (idx & 15)];
      pb[i] = B[(size_t)(idx >> 6) * 512 + n0 + (idx & 63)];
    }
    for (int k0 = 0; k0 < 512; k0 += 16) {
#pragma unroll
      for (int i = 0; i < 4; i++) {
        int idx = t + i * 256;
        As[idx & 15][idx >> 4] = pa[i];
        Bs[idx >> 6][idx & 63] = pb[i];
      }
      __syncthreads();
      if (k0 + 16 < 512) {
        int kn = k0 + 16;
#pragma unroll
        for (int i = 0; i < 4; i++) {
          int idx = t + i * 256;
          pa[i] = A[(size_t)(m0 + (idx >> 4)) * 512 + kn + (idx & 15)];
          pb[i] = B[(size_t)(kn + (idx >> 6)) * 512 + n0 + (idx & 63)];
        }
      }
#pragma unroll
      for (int kk = 0; kk < 16; kk++) {
        float4 a4 = *(const float4*)&As[kk][ty * 4];
        float4 b4 = *(const float4*)&Bs[kk][tx * 4];
        float av[4] = {a4.x, a4.y, a4.z, a4.w};
        float bv[4] = {b4.x, b4.y, b4.z, b4.w};
#pragma unroll
        for (int i = 0; i < 4; i++)
#pragma unroll
          for (int j = 0; j < 4; j++) acc[i][j] = fmaf(av[i], bv[j], acc[i][j]);
      }
      __syncthreads();
    }
#pragma unroll
    for (int i = 0; i < 4; i++)
#pragma unroll
      for (int j = 0; j < 4; j++)
        dst[(size_t)(n0 + tx * 4 + j) * 512 + dstOff + m0 + ty * 4 + i] = (f16)acc[i][j];
  } else if (b < QB1) {                            // ---- small_vec (4 segs) ----
    int g = (b - QB0) * 256 + t;
    int seg = g >> 9, j = g & 511;
    if (seg == 0) {
      float a = 0.f;
      for (int k = 0; k < 512; k++) a = fmaf(b2[k], Wc1[(size_t)k * 512 + j], a);
      vB[j] = a;
    } else if (seg == 1) {
      float a = 0.f;
      for (int k = 0; k < 512; k++) a = fmaf(be2[k], Wc1[(size_t)(512 + k) * 512 + j], a);
      vL[j] = a;
    } else if (seg == 2) {
      float a = 0.f;
      for (int k = 0; k < 512; k++) a = fmaf(be2[k], Wc1[(size_t)(1024 + k) * 512 + j], a);
      vR[j] = a;
    } else {
      float a = 0.f, c2 = 0.f;
      for (int c = 0; c < 512; c++) {
        float w = W2[(size_t)j * 512 + c];
        a = fmaf(w, as2[c], a);
        c2 = fmaf(w, ad2[c], c2);
      }
      ws2[j] = a; wd2[j] = c2;
    }
  } else if (b < QB2) {                            // ---- Wc2 transpose-cvt ----
    float (*tile)[33] = (float(*)[33])smem;
    int i0 = b - QB1;                              // 80 blocks: 5 n-tiles x 16 k-tiles
    const int n0 = (i0 % 5) * 32, k0 = (i0 / 5) * 32;
    const int tx = t & 31, ty = t >> 5;
#pragma unroll
    for (int i = 0; i < 4; i++) {
      int k = k0 + ty + i * 8, n = n0 + tx;
      tile[ty + i * 8][tx] = (n < 133) ? Wc2[(size_t)k * 133 + n] : 0.f;
    }
    __syncthreads();
#pragma unroll
    for (int i = 0; i < 4; i++) {
      int n = n0 + ty + i * 8, k = k0 + tx;
      if (n < 133) Wc2t[(size_t)n * 512 + k] = (f16)tile[tx][ty + i * 8];
    }
  } else if (b < QB3) {                            // ---- W1 transpose-cvt ----
    float (*tile)[33] = (float(*)[33])smem;
    int bb = b - QB2;
    const int n0 = (bb & 15) * 32, k0 = (bb >> 4) * 32;
    const int tx = t & 31, ty = t >> 5;
#pragma unroll
    for (int i = 0; i < 4; i++)
      tile[ty + i * 8][tx] = W1[(size_t)(k0 + ty + i * 8) * 512 + n0 + tx];
    __syncthreads();
#pragma unroll
    for (int i = 0; i < 4; i++)
      W1t[(size_t)(n0 + ty + i * 8) * 128 + k0 + tx] = (f16)tile[tx][ty + i * 8];
  } else if (b < QB4) {                            // ---- maxpool + count_deg fused ----
    int e = (b - QB3) * 256 + t;
    if (e >= NE) return;
    const float* p = syn + (size_t)e * 24;
    float v[24];
#pragma unroll
    for (int i = 0; i < 6; i++) {
      float4 q = *(const float4*)(p + i * 4);
      v[i*4+0] = q.x; v[i*4+1] = q.y; v[i*4+2] = q.z; v[i*4+3] = q.w;
    }
#pragma unroll
    for (int dd = 0; dd < 6; dd++)
      xp[(size_t)e * 6 + dd] = fmaxf(fmaxf(v[dd], v[6 + dd]), fmaxf(v[12 + dd], v[18 + dd]));
    atomicAdd(&dL[ei[e]], 1);
    atomicAdd(&dR[ei[NE + e]], 1);
  } else {                                         // ---- xph cvt, 8 elem/thread ----
    int idx = ((b - QB4) * 256 + t) * 8;           // NN*FEAT = 2,560,000 = 1250*2048
    float4 q0 = *(const float4*)(xparam + idx);
    float4 q1 = *(const float4*)(xparam + idx + 4);
    f16x8 o;
    o[0] = (f16)q0.x; o[1] = (f16)q0.y; o[2] = (f16)q0.z; o[3] = (f16)q0.w;
    o[4] = (f16)q1.x; o[5] = (f16)q1.y; o[6] = (f16)q1.z; o[7] = (f16)q1.w;
    *(f16x8*)(xph + idx) = o;
  }
}

// ================= fused1: xl1 MFMA-GEMM (blocks<1252) + h1 readlane gather ==========
__global__ __launch_bounds__(256) void fused1(
    const f16* __restrict__ xph, const f16* __restrict__ W1t, f16* __restrict__ xl1h,
    const float* __restrict__ xp, const float* __restrict__ We1,
    const float* __restrict__ be1,
    const int* __restrict__ oL, const int* __restrict__ eL,
    const int* __restrict__ oR, const int* __restrict__ eR,
    f16* __restrict__ hlrh)
{
  __shared__ __align__(16) f16 smem[7680];
  const int t = threadIdx.x;
  if (blockIdx.x < 1252) {
    f16 (*As)[40] = (f16(*)[40])smem;
    f16 (*Bs)[40] = (f16(*)[40])(smem + 64 * 40);
    const int wave = t >> 6, lane = t & 63;
    const int quad = lane >> 4, mrow = lane & 15;
    const int m0 = (blockIdx.x >> 2) * 64, n0 = (blockIdx.x & 3) * 128;
    f32x4 acc[4][2];
    f32x4 zero4 = {0.f, 0.f, 0.f, 0.f};
#pragma unroll
    for (int i = 0; i < 4; i++)
#pragma unroll
      for (int j = 0; j < 2; j++) acc[i][j] = zero4;
    const int ar = t >> 2, ac = (t & 3) * 8;
    for (int k0 = 0; k0 < FEAT; k0 += 32) {
      {
        int gm = m0 + ar;
        f16x8 v = {0, 0, 0, 0, 0, 0, 0, 0};
        if (gm < NN) v = *(const f16x8*)(xph + (size_t)gm * FEAT + k0 + ac);
        *(f16x8*)&As[ar][ac] = v;
      }
#pragma unroll
      for (int i = 0; i < 2; i++) {
        int idx = t + i * 256;
        int r = idx >> 2, c = (idx & 3) * 8;
        *(f16x8*)&Bs[r][c] = *(const f16x8*)(W1t + (size_t)(n0 + r) * FEAT + k0 + c);
      }
      __syncthreads();
      f16x8 af[4], bf[2];
#pragma unroll
      for (int mt = 0; mt < 4; mt++) af[mt] = *(const f16x8*)&As[mt * 16 + mrow][quad * 8];
#pragma unroll
      for (int nt = 0; nt < 2; nt++) bf[nt] = *(const f16x8*)&Bs[wave * 32 + nt * 16 + mrow][quad * 8];
#pragma unroll
      for (int mt = 0; mt < 4; mt++)
#pragma unroll
        for (int nt = 0; nt < 2; nt++)
          acc[mt][nt] = __builtin_amdgcn_mfma_f32_16x16x32_f16(af[mt], bf[nt], acc[mt][nt], 0, 0, 0);
      __syncthreads();
    }
#pragma unroll
    for (int mt = 0; mt < 4; mt++)
#pragma unroll
      for (int nt = 0; nt < 2; nt++) {
        int col = n0 + wave * 32 + nt * 16 + mrow;
#pragma unroll
        for (int reg = 0; reg < 4; reg++) {
          int row = m0 + mt * 16 + quad * 4 + reg;
          if (row < NN) xl1h[(size_t)row * 512 + col] = (f16)acc[mt][nt][reg];
        }
      }
  } else {
    // ---- h1 mean-gather: readlane broadcast, 4 node-sides per wave ----
    const int wave = t >> 6, lane = t & 63;
    const int w = (blockIdx.x - 1252) * 4 + wave;        // 0..9999
    float4 wv[6];
#pragma unroll
    for (int j = 0; j < 6; j++) wv[j] = *(const float4*)(We1 + j * 256 + 4 * lane);
    const float4 bv = *(const float4*)(be1 + 4 * lane);
#pragma unroll 1
    for (int i = 0; i < 4; i++) {
      const int b = w + i * 10000;                       // node-side in [0, 2*NN)
      const int* off; const int* lst; int n;
      if (b < NN) { off = oL; lst = eL; n = b; } else { off = oR; lst = eR; n = b - NN; }
      const int beg = off[n], deg = off[n + 1] - beg;
      float a0 = 0.f, a1 = 0.f, a2 = 0.f, a3 = 0.f;
      for (int base = 0; base < deg; base += 32) {
        const int m = min(32, deg - base);
        float x0 = 0.f, x1 = 0.f, x2 = 0.f, x3 = 0.f, x4 = 0.f, x5 = 0.f;
        if (lane < m) {
          const int e = lst[beg + base + lane];
          const float* pr = xp + (size_t)e * 6;
          float2 p0 = *(const float2*)pr;
          float2 p1 = *(const float2*)(pr + 2);
          float2 p2 = *(const float2*)(pr + 4);
          x0 = p0.x; x1 = p0.y; x2 = p1.x; x3 = p1.y; x4 = p2.x; x5 = p2.y;
        }
        const int ms = __builtin_amdgcn_readfirstlane(m);
        for (int s = 0; s < ms; s++) {
          const float f0 = rdlane(x0, s), f1 = rdlane(x1, s), f2 = rdlane(x2, s);
          const float f3 = rdlane(x3, s), f4 = rdlane(x4, s), f5 = rdlane(x5, s);
          float v0 = bv.x, v1 = bv.y, v2 = bv.z, v3 = bv.w;
          v0 = fmaf(f0, wv[0].x, v0); v1 = fmaf(f0, wv[0].y, v1);
          v2 = fmaf(f0, wv[0].z, v2); v3 = fmaf(f0, wv[0].w, v3);
          v0 = fmaf(f1, wv[1].x, v0); v1 = fmaf(f1, wv[1].y, v1);
          v2 = fmaf(f1, wv[1].z, v2); v3 = fmaf(f1, wv[1].w, v3);
          v0 = fmaf(f2, wv[2].x, v0); v1 = fmaf(f2, wv[2].y, v1);
          v2 = fmaf(f2, wv[2].z, v2); v3 = fmaf(f2, wv[2].w, v3);
          v0 = fmaf(f3, wv[3].x, v0); v1 = fmaf(f3, wv[3].y, v1);
          v2 = fmaf(f3, wv[3].z, v2); v3 = fmaf(f3, wv[3].w, v3);
          v0 = fmaf(f4, wv[4].x, v0); v1 = fmaf(f4, wv[4].y, v1);
          v2 = fmaf(f4, wv[4].z, v2); v3 = fmaf(f4, wv[4].w, v3);
          v0 = fmaf(f5, wv[5].x, v0); v1 = fmaf(f5, wv[5].y, v1);
          v2 = fmaf(f5, wv[5].z, v2); v3 = fmaf(f5, wv[5].w, v3);
          a0 += fmaxf(v0, 0.f); a1 += fmaxf(v1, 0.f);
          a2 += fmaxf(v2, 0.f); a3 += fmaxf(v3, 0.f);
        }
      }
      const float rn = deg > 0 ? 1.f / (float)deg : 0.f;
      f16x4 o;
      o[0] = (f16)(a0 * rn); o[1] = (f16)(a1 * rn);
      o[2] = (f16)(a2 * rn); o[3] = (f16)(a3 * rn);
      *(f16x4*)(hlrh + (size_t)b * 256 + 4 * lane) = o;
    }
  }
}

// ================= fused2: z-GEMM + class_pre, BK=64 dbuf + COUNTED vmcnt ===========
// 128x128 tile, BK=64, two 32KB LDS buffers. T4 schedule: per K-step issue next
// tile's 8 global_load_lds, then "s_waitcnt vmcnt(8)" (wait ONLY for the current
// tile's 8 loads issued last step -- next-tile loads stay in flight across the
// barrier and under the whole compute phase), raw s_barrier. After compute:
// lgkmcnt(0) + s_barrier (ds_reads drained, NO vmem drain) before the buffer is
// overwritten next step. This is the counted-vmcnt pipeline __syncthreads defeats
// (it emits vmcnt(0), which drained R10's prefetch -- the 64->53 regression).
// st-swizzle retained; 2x2 waves, acc[4][4]; bijective XCD swizzle (1256=8*157).
__global__ __launch_bounds__(256) void fused2(
    const f16* __restrict__ x1h, const f16* __restrict__ WzAt, f16* __restrict__ zh,
    const f16* __restrict__ hlrh, const f16* __restrict__ McatT,
    const int* __restrict__ degL, const int* __restrict__ degR,
    const float* __restrict__ bc1, const float* __restrict__ vB,
    const float* __restrict__ vL, const float* __restrict__ vR, f16* __restrict__ Ph)
{
  __shared__ __align__(16) f16 smem[32768];        // 2 x (As 8192 f16 | Bs 8192 f16)
  const int t = threadIdx.x;
  const int logical = (blockIdx.x & 7) * 157 + (blockIdx.x >> 3);
  const bool isZ = logical < 628;
  const int bb = isZ ? logical : logical - 628;
  const int wave = t >> 6, lane = t & 63;
  const int wr = wave >> 1, wc = wave & 1;
  const int quad = lane >> 4, mrow = lane & 15;
  const int m0 = (bb >> 2) * 128, n0 = (bb & 3) * 128;
  const f16* Bt = isZ ? WzAt : McatT;
  const int srow = wave * 8 + (lane >> 3);           // 0..31 within issue block
  const int cs = (lane & 7) ^ ((lane >> 3) & 7);     // swizzled source chunk
  const int mswz = mrow & 7;                         // read-side XOR key

  f32x4 acc[4][4];
  f32x4 zero4 = {0.f, 0.f, 0.f, 0.f};
#pragma unroll
  for (int i = 0; i < 4; i++)
#pragma unroll
    for (int j = 0; j < 4; j++) acc[i][j] = zero4;

  auto STAGE = [&](int buf, int it) {
    const int k0 = it * 64;
    f16* bA = smem + buf * 16384 + wave * 512;
    f16* bB = smem + buf * 16384 + 8192 + wave * 512;
#pragma unroll
    for (int i = 0; i < 4; i++) {
      const int garow = m0 + i * 32 + srow;
      const f16* gA;
      if (isZ) {
        gA = x1h + (size_t)garow * 512 + k0 + cs * 8;
      } else {
        const int roff = (k0 >> 8) ? NN : 0;         // K half selects L/R hlrh bank
        gA = hlrh + (size_t)(garow + roff) * 256 + (k0 & 255) + cs * 8;
      }
      gld_lds16(gA, bA + i * 2048);
      const f16* gB = Bt + (size_t)(n0 + i * 32 + srow) * 512 + k0 + cs * 8;
      gld_lds16(gB, bB + i * 2048);
    }
  };

  STAGE(0, 0);                                       // tile 0 in flight
#pragma unroll 1
  for (int it = 0; it < 8; ++it) {
    const int cur = it & 1;
    if (it < 7) {
      STAGE(cur ^ 1, it + 1);                        // issue next-tile loads FIRST
      asm volatile("s_waitcnt vmcnt(8)" ::: "memory");   // current tile's 8 done
    } else {
      asm volatile("s_waitcnt vmcnt(0)" ::: "memory");
    }
    __builtin_amdgcn_s_barrier();
    const f16* bufA = smem + cur * 16384;
    const f16* bufB = bufA + 8192;
#pragma unroll
    for (int ksub = 0; ksub < 2; ++ksub) {
      f16x8 af[4], bf[4];
#pragma unroll
      for (int mt = 0; mt < 4; mt++)
        af[mt] = *(const f16x8*)(bufA + (wr * 64 + mt * 16 + mrow) * 64 +
                                 ((ksub * 4 + quad) ^ mswz) * 8);
#pragma unroll
      for (int nt = 0; nt < 4; nt++)
        bf[nt] = *(const f16x8*)(bufB + (wc * 64 + nt * 16 + mrow) * 64 +
                                 ((ksub * 4 + quad) ^ mswz) * 8);
#pragma unroll
      for (int mt = 0; mt < 4; mt++)
#pragma unroll
        for (int nt = 0; nt < 4; nt++)
          acc[mt][nt] = __builtin_amdgcn_mfma_f32_16x16x32_f16(af[mt], bf[nt], acc[mt][nt], 0, 0, 0);
    }
    asm volatile("s_waitcnt lgkmcnt(0)" ::: "memory"); // ds_reads drained (no vmem)
    __builtin_amdgcn_s_barrier();                      // safe to overwrite cur next it
  }
  if (isZ) {
#pragma unroll
    for (int mt = 0; mt < 4; mt++)
#pragma unroll
      for (int nt = 0; nt < 4; nt++) {
        int col = n0 + wc * 64 + nt * 16 + mrow;
#pragma unroll
        for (int reg = 0; reg < 4; reg++) {
          int row = m0 + wr * 64 + mt * 16 + quad * 4 + reg;
          if (row < NN) zh[(size_t)row * 512 + col] = (f16)acc[mt][nt][reg];
        }
      }
  } else {
#pragma unroll
    for (int mt = 0; mt < 4; mt++)
#pragma unroll
      for (int nt = 0; nt < 4; nt++) {
        int col = n0 + wc * 64 + nt * 16 + mrow;
        float bb2 = bc1[col] + vB[col];
        float vl = vL[col], vr = vR[col];
#pragma unroll
        for (int reg = 0; reg < 4; reg++) {
          int row = m0 + wr * 64 + mt * 16 + quad * 4 + reg;
          if (row >= NN) continue;
          float v = acc[mt][nt][reg] + bb2;
          if (degL[row] > 0) v += vl;
          if (degR[row] > 0) v += vr;
          Ph[(size_t)row * 512 + col] = (f16)v;
        }
      }
  }
}

// ---------------- MFMA output GEMM: out(f32)[M,133] = h2h @ Wc2t^T + bc2 -------------
__global__ __launch_bounds__(256) void mfma_out(
    const f16* __restrict__ A, const f16* __restrict__ Bt,
    const float* __restrict__ bias, float* __restrict__ C, int M)
{
  __shared__ __align__(16) f16 As[64][40];
  __shared__ __align__(16) f16 Bs[128][40];
  const int t = threadIdx.x;
  const int wave = t >> 6, lane = t & 63;
  const int quad = lane >> 4, mrow = lane & 15;
  const int m0 = blockIdx.y * 64, n0 = blockIdx.x * 128;
  f32x4 acc[4][2];
  f32x4 zero4 = {0.f, 0.f, 0.f, 0.f};
#pragma unroll
  for (int i = 0; i < 4; i++)
#pragma unroll
    for (int j = 0; j < 2; j++) acc[i][j] = zero4;
  const int ar = t >> 2, ac = (t & 3) * 8;
  for (int k0 = 0; k0 < 512; k0 += 32) {
    {
      int gm = m0 + ar;
      f16x8 v = {0, 0, 0, 0, 0, 0, 0, 0};
      if (gm < M) v = *(const f16x8*)(A + (size_t)gm * 512 + k0 + ac);
      *(f16x8*)&As[ar][ac] = v;
    }
#pragma unroll
    for (int i = 0; i < 2; i++) {
      int idx = t + i * 256;
      int r = idx >> 2, c = (idx & 3) * 8;
      f16x8 v = {0, 0, 0, 0, 0, 0, 0, 0};
      if (n0 + r < 133) v = *(const f16x8*)(Bt + (size_t)(n0 + r) * 512 + k0 + c);
      *(f16x8*)&Bs[r][c] = v;
    }
    __syncthreads();
    f16x8 af[4], bf[2];
#pragma unroll
    for (int mt = 0; mt < 4; mt++) af[mt] = *(const f16x8*)&As[mt * 16 + mrow][quad * 8];
#pragma unroll
    for (int nt = 0; nt < 2; nt++) bf[nt] = *(const f16x8*)&Bs[wave * 32 + nt * 16 + mrow][quad * 8];
#pragma unroll
    for (int mt = 0; mt < 4; mt++)
#pragma unroll
      for (int nt = 0; nt < 2; nt++)
        acc[mt][nt] = __builtin_amdgcn_mfma_f32_16x16x32_f16(af[mt], bf[nt], acc[mt][nt], 0, 0, 0);
    __syncthreads();
  }
#pragma unroll
  for (int mt = 0; mt < 4; mt++)
#pragma unroll
    for (int nt = 0; nt < 2; nt++) {
      int col = n0 + wave * 32 + nt * 16 + mrow;
      if (col >= 133) continue;
      float bb = bias[col];
#pragma unroll
      for (int reg = 0; reg < 4; reg++) {
        int row = m0 + mt * 16 + quad * 4 + reg;
        if (row < M) C[(size_t)row * 133 + col] = acc[mt][nt][reg] + bb;
      }
    }
}

// ------------- CSR scan (2 blocks; offA derived as offR + n) -------------------------
__global__ __launch_bounds__(1024) void scan_csr(
    const int* __restrict__ dL, const int* __restrict__ dR,
    int* __restrict__ oL, int* __restrict__ oR, int* __restrict__ oA)
{
  const int b = blockIdx.x;
  const int* deg = b == 0 ? dL : dR;
  __shared__ int part[1024];
  const int t = threadIdx.x;
  const int chunk = 20;
  int base = t * chunk;
  int sum = 0;
  for (int i = 0; i < chunk; i++) { int idx = base + i; if (idx < NN) sum += deg[idx]; }
  part[t] = sum;
  __syncthreads();
  for (int o = 1; o < 1024; o <<= 1) {
    int v = (t >= o) ? part[t - o] : 0;
    __syncthreads();
    part[t] += v;
    __syncthreads();
  }
  int run = part[t] - sum;
  if (b == 0) {
    for (int i = 0; i < chunk; i++) {
      int idx = base + i;
      if (idx < NN) { oL[idx] = run; run += deg[idx]; }
    }
    if (t == 0) oL[NN] = part[1023];
  } else {
    for (int i = 0; i < chunk; i++) {
      int idx = base + i;
      if (idx < NN) { oR[idx] = run; oA[idx] = run + idx; run += deg[idx]; }
    }
    if (t == 0) { oR[NN] = part[1023]; oA[NN] = part[1023] + NN; }
  }
}

// ------------- fill: 2 atomics/edge; self-loops atomic-free (slot 0 of A-segment) ----
__global__ __launch_bounds__(256) void fill_csr(
    const int* __restrict__ ei,
    const int* __restrict__ oL, const int* __restrict__ oR, const int* __restrict__ oA,
    int* __restrict__ cL, int* __restrict__ cR,
    int* __restrict__ eL, int* __restrict__ eR, int* __restrict__ snA)
{
  int e = blockIdx.x * 256 + threadIdx.x;
  if (e >= EE) return;
  if (e < NE) {
    int s = ei[e], d = ei[NE + e];
    int p = atomicAdd(&cL[s], 1); eL[oL[s] + p] = e;
    p = atomicAdd(&cR[d], 1);
    eR[oR[d] + p] = e;
    snA[oA[d] + 1 + p] = s;       // A-segment: [selfloop, dst-edges...]
  } else {
    int n = e - NE;
    snA[oA[n]] = n;
  }
}

// ------------- attention dot products, layer 1 ---------------------------------------
__global__ __launch_bounds__(256) void attn_dots1(
    const f16* __restrict__ xlh, const float* __restrict__ asrc,
    const float* __restrict__ adst, float* __restrict__ s, float* __restrict__ d)
{
  int gid = blockIdx.x * 256 + threadIdx.x;       // n*8 + h
  if (gid >= NN * NH) return;
  int n = gid >> 3, h = gid & 7;
  const f16x2* row = (const f16x2*)(xlh + (size_t)n * 512 + h * 64);
  const float* a1 = asrc + h * 64;
  const float* a2 = adst + h * 64;
  float ss = 0.f, dd = 0.f;
#pragma unroll 8
  for (int j = 0; j < 32; j++) {
    f16x2 p = row[j];
    float v0 = (float)p[0], v1 = (float)p[1];
    ss += v0 * a1[2 * j] + v1 * a1[2 * j + 1];
    dd += v0 * a2[2 * j] + v1 * a2[2 * j + 1];
  }
  s[gid] = ss; d[gid] = dd;
}

// ------------- GAT layer 1 gather: WAVE-per-node, no LDS, no barriers ----------------
__global__ __launch_bounds__(256) void gat_gather1(
    const int* __restrict__ snA, const int* __restrict__ offA,
    const float* __restrict__ s1, const float* __restrict__ d1,
    const f16* __restrict__ xlh, const float* __restrict__ b1,
    const float* __restrict__ ws2, const float* __restrict__ wd2,
    f16* __restrict__ x1h, float* __restrict__ s2, float* __restrict__ d2)
{
  const int t = threadIdx.x;
  const int wave = t >> 6, lane = t & 63;
  const int n = blockIdx.x * 4 + wave;             // 20000 = 5000*4 exact
  const int hf = lane >> 3;
  const float dnw = d1[n * 8 + hf];
  const int beg = offA[n], deg = offA[n + 1] - beg;
  float acc[8] = {0.f};
  float den = 0.f;
  for (int base = 0; base < deg; base += 64) {
    const int m = min(64, deg - base);
    int me = 0;
    if (lane < m) me = snA[beg + base + lane];
    const int ms = __builtin_amdgcn_readfirstlane(m);
    int s = 0;
    for (; s + 4 <= ms; s += 4) {
      int sn[4]; float sv[4]; f16x8 row[4];
#pragma unroll
      for (int u = 0; u < 4; u++) sn[u] = __builtin_amdgcn_readlane(me, s + u);
#pragma unroll
      for (int u = 0; u < 4; u++) sv[u] = s1[sn[u] * 8 + hf];
#pragma unroll
      for (int u = 0; u < 4; u++) row[u] = *(const f16x8*)(xlh + (size_t)sn[u] * 512 + lane * 8);
#pragma unroll
      for (int u = 0; u < 4; u++) {
        float w = __expf(lrelu(sv[u] + dnw));
        den += w;
#pragma unroll
        for (int j = 0; j < 8; j++) acc[j] = fmaf(w, (float)row[u][j], acc[j]);
      }
    }
    for (; s < ms; ++s) {
      int sn = __builtin_amdgcn_readlane(me, s);
      float sv = s1[sn * 8 + hf];
      f16x8 row = *(const f16x8*)(xlh + (size_t)sn * 512 + lane * 8);
      float w = __expf(lrelu(sv + dnw));
      den += w;
#pragma unroll
      for (int j = 0; j < 8; j++) acc[j] = fmaf(w, (float)row[j], acc[j]);
    }
  }
  const float rh = 1.f / (den + 1e-16f);
  float4 bv0 = *(const float4*)(b1 + lane * 8);
  float4 bv1 = *(const float4*)(b1 + lane * 8 + 4);
  float bb[8] = {bv0.x, bv0.y, bv0.z, bv0.w, bv1.x, bv1.y, bv1.z, bv1.w};
  float4 wsa = *(const float4*)(ws2 + lane * 8);
  float4 wsb = *(const float4*)(ws2 + lane * 8 + 4);
  float4 wda = *(const float4*)(wd2 + lane * 8);
  float4 wdb = *(const float4*)(wd2 + lane * 8 + 4);
  float wsv[8] = {wsa.x, wsa.y, wsa.z, wsa.w, wsb.x, wsb.y, wsb.z, wsb.w};
  float wdv[8] = {wda.x, wda.y, wda.z, wda.w, wdb.x, wdb.y, wdb.z, wdb.w};
  f16x8 o;
  float ps = 0.f, pd = 0.f;
#pragma unroll
  for (int j = 0; j < 8; j++) {
    float v = acc[j] * rh + bb[j];
    v = v > 0.f ? v : (__expf(v) - 1.f);
    o[j] = (f16)v;
    ps = fmaf(v, wsv[j], ps);
    pd = fmaf(v, wdv[j], pd);
  }
  *(f16x8*)(x1h + (size_t)n * 512 + lane * 8) = o;
#pragma unroll
  for (int off = 32; off > 0; off >>= 1) {
    ps += __shfl_xor(ps, off);
    pd += __shfl_xor(pd, off);
  }
  if (lane == 0) { s2[n] = ps; d2[n] = pd; }
}

// ------------- GAT layer 2 gather: WAVE-per-node, no LDS, no barriers ----------------
__global__ __launch_bounds__(256) void gat_gather2(
    const int* __restrict__ snA, const int* __restrict__ offA,
    const float* __restrict__ s2, const float* __restrict__ d2,
    const f16* __restrict__ zh, const f16* __restrict__ Ph,
    f16* __restrict__ h2h)
{
  const int t = threadIdx.x;
  const int wave = t >> 6, lane = t & 63;
  const int n = blockIdx.x * 4 + wave;             // 20000 = 5000*4 exact
  const float dn = d2[n];
  const int beg = offA[n], deg = offA[n + 1] - beg;
  float acc[8] = {0.f};
  float den = 0.f;
  for (int base = 0; base < deg; base += 64) {
    const int m = min(64, deg - base);
    int me = 0;
    if (lane < m) me = snA[beg + base + lane];
    const int ms = __builtin_amdgcn_readfirstlane(m);
    int s = 0;
    for (; s + 4 <= ms; s += 4) {
      int sn[4]; float sv[4]; f16x8 row[4];
#pragma unroll
      for (int u = 0; u < 4; u++) sn[u] = __builtin_amdgcn_readlane(me, s + u);
#pragma unroll
      for (int u = 0; u < 4; u++) sv[u] = s2[sn[u]];
#pragma unroll
      for (int u = 0; u < 4; u++) row[u] = *(const f16x8*)(zh + (size_t)sn[u] * 512 + lane * 8);
#pragma unroll
      for (int u = 0; u < 4; u++) {
        float w = __expf(lrelu(sv[u] + dn));
        den += w;
#pragma unroll
        for (int j = 0; j < 8; j++) acc[j] = fmaf(w, (float)row[u][j], acc[j]);
      }
    }
    for (; s < ms; ++s) {
      int sn = __builtin_amdgcn_readlane(me, s);
      float sv = s2[sn];
      f16x8 row = *(const f16x8*)(zh + (size_t)sn * 512 + lane * 8);
      float w = __expf(lrelu(sv + dn));
      den += w;
#pragma unroll
      for (int j = 0; j < 8; j++) acc[j] = fmaf(w, (float)row[j], acc[j]);
    }
  }
  const float rn = 1.f / (den + 1e-16f);
  f16x8 pv = *(const f16x8*)(Ph + (size_t)n * 512 + lane * 8);
  f16x8 o;
#pragma unroll
  for (int j = 0; j < 8; j++) {
    float v = fmaxf(acc[j] * rn + (float)pv[j], 0.f);
    o[j] = (f16)v;
  }
  *(f16x8*)(h2h + (size_t)n * 512 + lane * 8) = o;
}

extern "C" void kernel_launch(void* const* d_in, const int* in_sizes, int n_in,
                              void* d_out, int out_size, void* d_ws, size_t ws_size,
                              hipStream_t stream) {
  const int*   edge_index = (const int*)d_in[0];
  const float* synapse    = (const float*)d_in[2];
  const float* x_param = (const float*)d_in[5];
  const float* W1      = (const float*)d_in[6];
  const float* as1     = (const float*)d_in[7];
  const float* ad1     = (const float*)d_in[8];
  const float* b1      = (const float*)d_in[9];
  const float* W2      = (const float*)d_in[10];
  const float* as2     = (const float*)d_in[11];
  const float* ad2     = (const float*)d_in[12];
  const float* b2      = (const float*)d_in[13];
  const float* We1     = (const float*)d_in[14];
  const float* be1     = (const float*)d_in[15];
  const float* We2     = (const float*)d_in[16];
  const float* be2     = (const float*)d_in[17];
  const float* Wc1     = (const float*)d_in[18];
  const float* bc1     = (const float*)d_in[19];
  const float* Wc2     = (const float*)d_in[20];
  const float* bc2     = (const float*)d_in[21];
  float* out_p = (float*)d_out;

  // ---- workspace layout (~125 MB) ----
  char* p = (char*)d_ws;
  float* xp    = (float*)p; p += (size_t)NE * 6 * 4;
  float* s1    = (float*)p; p += (size_t)NN * 8 * 4;
  float* d1    = (float*)p; p += (size_t)NN * 8 * 4;
  float* s2    = (float*)p; p += (size_t)NN * 4;
  float* d2    = (float*)p; p += (size_t)NN * 4;
  float* vB    = (float*)p; p += 512 * 4;
  float* vL    = (float*)p; p += 512 * 4;
  float* vR    = (float*)p; p += 512 * 4;
  float* ws2   = (float*)p; p += 512 * 4;
  float* wd2   = (float*)p; p += 512 * 4;
  f16* xph     = (f16*)p; p += (size_t)NN * FEAT * 2;
  f16* xl1h    = (f16*)p; p += (size_t)NN * 512 * 2;
  f16* x1h     = (f16*)p; p += (size_t)NN * 512 * 2;
  f16* zh      = (f16*)p; p += (size_t)NN * 512 * 2;
  f16* h2h     = (f16*)p; p += (size_t)NN * 512 * 2;
  f16* Phb     = (f16*)p; p += (size_t)NN * 512 * 2;
  f16* hlrh    = (f16*)p; p += (size_t)2 * NN * 256 * 2;
  f16* W1t     = (f16*)p; p += (size_t)512 * FEAT * 2;
  f16* WzAt    = (f16*)p; p += (size_t)512 * 512 * 2;
  f16* McatT   = (f16*)p; p += (size_t)512 * 512 * 2;
  f16* Wc2t    = (f16*)p; p += (size_t)133 * 512 * 2;
  int* degL    = (int*)p;                 // N  (zero group start)
  int* degR    = degL + NN;               // N
  int* curL    = degR + NN;               // N
  int* curR    = curL + NN;               // N  (zero group: 4N ints)
  int* offL    = curR + NN;               // N+1
  int* offR    = offL + NN + 1;           // N+1
  int* offA    = offR + NN + 1;           // N+1
  int* edgeL   = offA + NN + 1;           // E
  int* edgeR   = edgeL + NE;              // E
  int* snA     = edgeR + NE;              // EE

  hipMemsetAsync(degL, 0, (size_t)4 * NN * sizeof(int), stream);

  preamble<<<QB5, 256, 0, stream>>>(
      edge_index, synapse, W1, x_param, W2, We2, Wc1, Wc2, b2, be2, as2, ad2,
      degL, degR, xp, W1t, xph, WzAt, McatT, Wc2t, vB, vL, vR, ws2, wd2);
  scan_csr<<<2, 1024, 0, stream>>>(degL, degR, offL, offR, offA);
  fill_csr<<<(EE + 255) / 256, 256, 0, stream>>>(edge_index, offL, offR, offA,
                                                 curL, curR, edgeL, edgeR, snA);
  fused1<<<1252 + 2500, 256, 0, stream>>>(xph, W1t, xl1h, xp, We1, be1,
                                          offL, edgeL, offR, edgeR, hlrh);
  attn_dots1<<<(NN * NH + 255) / 256, 256, 0, stream>>>(xl1h, as1, ad1, s1, d1);
  gat_gather1<<<5000, 256, 0, stream>>>(snA, offA, s1, d1, xl1h, b1, ws2, wd2,
                                        x1h, s2, d2);
  fused2<<<1256, 256, 0, stream>>>(x1h, WzAt, zh, hlrh, McatT,
                                   degL, degR, bc1, vB, vL, vR, Phb);
  gat_gather2<<<5000, 256, 0, stream>>>(snA, offA, s2, d2, zh, Phb, h2h);
  mfma_out<<<dim3(2, 313), 256, 0, stream>>>(h2h, Wc2t, bc2, out_p, NN);
}

// Round 12
// 411.798 us; speedup vs baseline: 1.0318x; 1.0264x over previous
//
#include <hip/hip_runtime.h>
#include <cstddef>

// Problem constants (fixed by setup_inputs)
#define NN   20000     // nodes
#define FEAT 128
#define NH   8         // heads layer 1
#define NE   200000    // edges
#define EE   220000    // edges + self loops

typedef _Float16 f16;
typedef _Float16 f16x2 __attribute__((ext_vector_type(2)));
typedef _Float16 f16x4 __attribute__((ext_vector_type(4)));
typedef _Float16 f16x8 __attribute__((ext_vector_type(8)));
typedef float    f32x4 __attribute__((ext_vector_type(4)));

__device__ __forceinline__ float lrelu(float a) { return a > 0.f ? a : 0.2f * a; }
__device__ __forceinline__ float rdlane(float v, int l) {
  return __int_as_float(__builtin_amdgcn_readlane(__float_as_int(v), l));
}
// async global->LDS, 16B per lane; LDS dest = wave-uniform base + lane*16
__device__ __forceinline__ void gld_lds16(const f16* g, f16* l) {
  __builtin_amdgcn_global_load_lds(
      (const __attribute__((address_space(1))) void*)g,
      (__attribute__((address_space(3))) void*)l, 16, 0, 0);
}

// ================= preamble: ALL input-only precompute in one launch =================
// Ordered longest-latency-first so small late sections hide under the bulk:
// [0,QB0) gemm3in1 | [QB0,QB1) small_vec | [QB1,QB2) Wc2t | [QB2,QB3) W1t |
// [QB3,QB4) maxpool+count_deg (fused edge pass) | [QB4,QB5) xph cvt x8
#define QB0 128
#define QB1 (QB0 + 8)
#define QB2 (QB1 + 80)
#define QB3 (QB2 + 64)
#define QB4 (QB3 + 782)
#define QB5 (QB4 + 1250)
__global__ __launch_bounds__(256) void preamble(
    const int* __restrict__ ei, const float* __restrict__ syn,
    const float* __restrict__ W1, const float* __restrict__ xparam,
    const float* __restrict__ W2, const float* __restrict__ We2,
    const float* __restrict__ Wc1, const float* __restrict__ Wc2,
    const float* __restrict__ b2, const float* __restrict__ be2,
    const float* __restrict__ as2, const float* __restrict__ ad2,
    int* __restrict__ dL, int* __restrict__ dR,
    float* __restrict__ xp, f16* __restrict__ W1t, f16* __restrict__ xph,
    f16* __restrict__ WzAt, f16* __restrict__ McatT, f16* __restrict__ Wc2t,
    float* __restrict__ vB, float* __restrict__ vL, float* __restrict__ vR,
    float* __restrict__ ws2, float* __restrict__ wd2)
{
  __shared__ float smem[2112];
  const int b = blockIdx.x, t = threadIdx.x;
  if (b < QB0) {                                   // ---- gemm3in1 (folded weights) ----
    float (*As)[68] = (float(*)[68])smem;
    float (*Bs)[64] = (float(*)[64])(smem + 16 * 68);
    const int bb = b;
    const float* A; const float* B; f16* dst; int dstOff, m0, n0;
    if (bb < 64)      { A = W2;  B = Wc1;  dst = WzAt;  dstOff = 0;
                        m0 = (bb >> 3) * 64; n0 = (bb & 7) * 64; }
    else if (bb < 96) { int i = bb - 64; A = We2; B = Wc1 + (size_t)512 * 512;
                        dst = McatT; dstOff = 0;
                        m0 = (i >> 3) * 64; n0 = (i & 7) * 64; }
    else              { int i = bb - 96; A = We2; B = Wc1 + (size_t)1024 * 512;
                        dst = McatT; dstOff = 256;
                        m0 = (i >> 3) * 64; n0 = (i & 7) * 64; }
    const int tx = t & 15, ty = t >> 4;
    float acc[4][4] = {{0.f}};
    float pa[4], pb[4];
#pragma unroll
    for (int i = 0; i < 4; i++) {
      int idx = t + i * 256;
      pa[i] = A[(size_t)(m0 + (idx >> 4)) * 512 + (idx & 15)];
      pb[i] = B[(size_t)(idx >> 6) * 512 + n0 + (idx & 63)];
    }
    for (int k0 = 0; k0 < 512; k0 += 16) {
#pragma unroll
      for (int i = 0; i < 4; i++) {
        int idx = t + i * 256;
        As[idx & 15][idx >> 4] = pa[i];
        Bs[idx >> 6][idx & 63] = pb[i];
      }
      __syncthreads();
      if (k0 + 16 < 512) {
        int kn = k0 + 16;
#pragma unroll
        for (int i = 0; i < 4; i++) {
          int idx = t + i * 256;
          pa[i] = A[(size_t)(m0 + (idx >> 4)) * 512 + kn + (idx & 15)];
          pb[i] = B[(size_t)(kn + (idx >> 6)) * 512 + n0 + (idx & 63)];
        }
      }
#pragma unroll
      for (int kk = 0; kk < 16; kk++) {
        float4 a4 = *(const float4*)&As[kk][ty * 4];
        float4 b4 = *(const float4*)&Bs[kk][tx * 4];
        float av[4] = {a4.x, a4.y, a4.z, a4.w};
        float bv[4] = {b4.x, b4.y, b4.z, b4.w};
#pragma unroll
        for (int i = 0; i < 4; i++)
#pragma unroll
          for (int j = 0; j < 4; j++) acc[i][j] = fmaf(av[i], bv[j], acc[i][j]);
      }
      __syncthreads();
    }
#pragma unroll
    for (int i = 0; i < 4; i++)
#pragma unroll
      for (int j = 0; j < 4; j++)
        dst[(size_t)(n0 + tx * 4 + j) * 512 + dstOff + m0 + ty * 4 + i] = (f16)acc[i][j];
  } else if (b < QB1) {                            // ---- small_vec (4 segs) ----
    int g = (b - QB0) * 256 + t;
    int seg = g >> 9, j = g & 511;
    if (seg == 0) {
      float a = 0.f;
      for (int k = 0; k < 512; k++) a = fmaf(b2[k], Wc1[(size_t)k * 512 + j], a);
      vB[j] = a;
    } else if (seg == 1) {
      float a = 0.f;
      for (int k = 0; k < 512; k++) a = fmaf(be2[k], Wc1[(size_t)(512 + k) * 512 + j], a);
      vL[j] = a;
    } else if (seg == 2) {
      float a = 0.f;
      for (int k = 0; k < 512; k++) a = fmaf(be2[k], Wc1[(size_t)(1024 + k) * 512 + j], a);
      vR[j] = a;
    } else {
      float a = 0.f, c2 = 0.f;
      for (int c = 0; c < 512; c++) {
        float w = W2[(size_t)j * 512 + c];
        a = fmaf(w, as2[c], a);
        c2 = fmaf(w, ad2[c], c2);
      }
      ws2[j] = a; wd2[j] = c2;
    }
  } else if (b < QB2) {                            // ---- Wc2 transpose-cvt ----
    float (*tile)[33] = (float(*)[33])smem;
    int i0 = b - QB1;                              // 80 blocks: 5 n-tiles x 16 k-tiles
    const int n0 = (i0 % 5) * 32, k0 = (i0 / 5) * 32;
    const int tx = t & 31, ty = t >> 5;
#pragma unroll
    for (int i = 0; i < 4; i++) {
      int k = k0 + ty + i * 8, n = n0 + tx;
      tile[ty + i * 8][tx] = (n < 133) ? Wc2[(size_t)k * 133 + n] : 0.f;
    }
    __syncthreads();
#pragma unroll
    for (int i = 0; i < 4; i++) {
      int n = n0 + ty + i * 8, k = k0 + tx;
      if (n < 133) Wc2t[(size_t)n * 512 + k] = (f16)tile[tx][ty + i * 8];
    }
  } else if (b < QB3) {                            // ---- W1 transpose-cvt ----
    float (*tile)[33] = (float(*)[33])smem;
    int bb = b - QB2;
    const int n0 = (bb & 15) * 32, k0 = (bb >> 4) * 32;
    const int tx = t & 31, ty = t >> 5;
#pragma unroll
    for (int i = 0; i < 4; i++)
      tile[ty + i * 8][tx] = W1[(size_t)(k0 + ty + i * 8) * 512 + n0 + tx];
    __syncthreads();
#pragma unroll
    for (int i = 0; i < 4; i++)
      W1t[(size_t)(n0 + ty + i * 8) * 128 + k0 + tx] = (f16)tile[tx][ty + i * 8];
  } else if (b < QB4) {                            // ---- maxpool + count_deg fused ----
    int e = (b - QB3) * 256 + t;
    if (e >= NE) return;
    const float* p = syn + (size_t)e * 24;
    float v[24];
#pragma unroll
    for (int i = 0; i < 6; i++) {
      float4 q = *(const float4*)(p + i * 4);
      v[i*4+0] = q.x; v[i*4+1] = q.y; v[i*4+2] = q.z; v[i*4+3] = q.w;
    }
#pragma unroll
    for (int dd = 0; dd < 6; dd++)
      xp[(size_t)e * 6 + dd] = fmaxf(fmaxf(v[dd], v[6 + dd]), fmaxf(v[12 + dd], v[18 + dd]));
    atomicAdd(&dL[ei[e]], 1);
    atomicAdd(&dR[ei[NE + e]], 1);
  } else {                                         // ---- xph cvt, 8 elem/thread ----
    int idx = ((b - QB4) * 256 + t) * 8;           // NN*FEAT = 2,560,000 = 1250*2048
    float4 q0 = *(const float4*)(xparam + idx);
    float4 q1 = *(const float4*)(xparam + idx + 4);
    f16x8 o;
    o[0] = (f16)q0.x; o[1] = (f16)q0.y; o[2] = (f16)q0.z; o[3] = (f16)q0.w;
    o[4] = (f16)q1.x; o[5] = (f16)q1.y; o[6] = (f16)q1.z; o[7] = (f16)q1.w;
    *(f16x8*)(xph + idx) = o;
  }
}

// ================= fused1: xl1 MFMA-GEMM (blocks<1252) + h1 readlane gather ==========
__global__ __launch_bounds__(256) void fused1(
    const f16* __restrict__ xph, const f16* __restrict__ W1t, f16* __restrict__ xl1h,
    const float* __restrict__ xp, const float* __restrict__ We1,
    const float* __restrict__ be1,
    const int* __restrict__ oL, const int* __restrict__ eL,
    const int* __restrict__ oR, const int* __restrict__ eR,
    f16* __restrict__ hlrh)
{
  __shared__ __align__(16) f16 smem[7680];
  const int t = threadIdx.x;
  if (blockIdx.x < 1252) {
    f16 (*As)[40] = (f16(*)[40])smem;
    f16 (*Bs)[40] = (f16(*)[40])(smem + 64 * 40);
    const int wave = t >> 6, lane = t & 63;
    const int quad = lane >> 4, mrow = lane & 15;
    const int m0 = (blockIdx.x >> 2) * 64, n0 = (blockIdx.x & 3) * 128;
    f32x4 acc[4][2];
    f32x4 zero4 = {0.f, 0.f, 0.f, 0.f};
#pragma unroll
    for (int i = 0; i < 4; i++)
#pragma unroll
      for (int j = 0; j < 2; j++) acc[i][j] = zero4;
    const int ar = t >> 2, ac = (t & 3) * 8;
    for (int k0 = 0; k0 < FEAT; k0 += 32) {
      {
        int gm = m0 + ar;
        f16x8 v = {0, 0, 0, 0, 0, 0, 0, 0};
        if (gm < NN) v = *(const f16x8*)(xph + (size_t)gm * FEAT + k0 + ac);
        *(f16x8*)&As[ar][ac] = v;
      }
#pragma unroll
      for (int i = 0; i < 2; i++) {
        int idx = t + i * 256;
        int r = idx >> 2, c = (idx & 3) * 8;
        *(f16x8*)&Bs[r][c] = *(const f16x8*)(W1t + (size_t)(n0 + r) * FEAT + k0 + c);
      }
      __syncthreads();
      f16x8 af[4], bf[2];
#pragma unroll
      for (int mt = 0; mt < 4; mt++) af[mt] = *(const f16x8*)&As[mt * 16 + mrow][quad * 8];
#pragma unroll
      for (int nt = 0; nt < 2; nt++) bf[nt] = *(const f16x8*)&Bs[wave * 32 + nt * 16 + mrow][quad * 8];
#pragma unroll
      for (int mt = 0; mt < 4; mt++)
#pragma unroll
        for (int nt = 0; nt < 2; nt++)
          acc[mt][nt] = __builtin_amdgcn_mfma_f32_16x16x32_f16(af[mt], bf[nt], acc[mt][nt], 0, 0, 0);
      __syncthreads();
    }
#pragma unroll
    for (int mt = 0; mt < 4; mt++)
#pragma unroll
      for (int nt = 0; nt < 2; nt++) {
        int col = n0 + wave * 32 + nt * 16 + mrow;
#pragma unroll
        for (int reg = 0; reg < 4; reg++) {
          int row = m0 + mt * 16 + quad * 4 + reg;
          if (row < NN) xl1h[(size_t)row * 512 + col] = (f16)acc[mt][nt][reg];
        }
      }
  } else {
    // ---- h1 mean-gather: readlane broadcast, 4 node-sides per wave ----
    const int wave = t >> 6, lane = t & 63;
    const int w = (blockIdx.x - 1252) * 4 + wave;        // 0..9999
    float4 wv[6];
#pragma unroll
    for (int j = 0; j < 6; j++) wv[j] = *(const float4*)(We1 + j * 256 + 4 * lane);
    const float4 bv = *(const float4*)(be1 + 4 * lane);
#pragma unroll 1
    for (int i = 0; i < 4; i++) {
      const int b = w + i * 10000;                       // node-side in [0, 2*NN)
      const int* off; const int* lst; int n;
      if (b < NN) { off = oL; lst = eL; n = b; } else { off = oR; lst = eR; n = b - NN; }
      const int beg = off[n], deg = off[n + 1] - beg;
      float a0 = 0.f, a1 = 0.f, a2 = 0.f, a3 = 0.f;
      for (int base = 0; base < deg; base += 32) {
        const int m = min(32, deg - base);
        float x0 = 0.f, x1 = 0.f, x2 = 0.f, x3 = 0.f, x4 = 0.f, x5 = 0.f;
        if (lane < m) {
          const int e = lst[beg + base + lane];
          const float* pr = xp + (size_t)e * 6;
          float2 p0 = *(const float2*)pr;
          float2 p1 = *(const float2*)(pr + 2);
          float2 p2 = *(const float2*)(pr + 4);
          x0 = p0.x; x1 = p0.y; x2 = p1.x; x3 = p1.y; x4 = p2.x; x5 = p2.y;
        }
        const int ms = __builtin_amdgcn_readfirstlane(m);
        for (int s = 0; s < ms; s++) {
          const float f0 = rdlane(x0, s), f1 = rdlane(x1, s), f2 = rdlane(x2, s);
          const float f3 = rdlane(x3, s), f4 = rdlane(x4, s), f5 = rdlane(x5, s);
          float v0 = bv.x, v1 = bv.y, v2 = bv.z, v3 = bv.w;
          v0 = fmaf(f0, wv[0].x, v0); v1 = fmaf(f0, wv[0].y, v1);
          v2 = fmaf(f0, wv[0].z, v2); v3 = fmaf(f0, wv[0].w, v3);
          v0 = fmaf(f1, wv[1].x, v0); v1 = fmaf(f1, wv[1].y, v1);
          v2 = fmaf(f1, wv[1].z, v2); v3 = fmaf(f1, wv[1].w, v3);
          v0 = fmaf(f2, wv[2].x, v0); v1 = fmaf(f2, wv[2].y, v1);
          v2 = fmaf(f2, wv[2].z, v2); v3 = fmaf(f2, wv[2].w, v3);
          v0 = fmaf(f3, wv[3].x, v0); v1 = fmaf(f3, wv[3].y, v1);
          v2 = fmaf(f3, wv[3].z, v2); v3 = fmaf(f3, wv[3].w, v3);
          v0 = fmaf(f4, wv[4].x, v0); v1 = fmaf(f4, wv[4].y, v1);
          v2 = fmaf(f4, wv[4].z, v2); v3 = fmaf(f4, wv[4].w, v3);
          v0 = fmaf(f5, wv[5].x, v0); v1 = fmaf(f5, wv[5].y, v1);
          v2 = fmaf(f5, wv[5].z, v2); v3 = fmaf(f5, wv[5].w, v3);
          a0 += fmaxf(v0, 0.f); a1 += fmaxf(v1, 0.f);
          a2 += fmaxf(v2, 0.f); a3 += fmaxf(v3, 0.f);
        }
      }
      const float rn = deg > 0 ? 1.f / (float)deg : 0.f;
      f16x4 o;
      o[0] = (f16)(a0 * rn); o[1] = (f16)(a1 * rn);
      o[2] = (f16)(a2 * rn); o[3] = (f16)(a3 * rn);
      *(f16x4*)(hlrh + (size_t)b * 256 + 4 * lane) = o;
    }
  }
}

// ================= fused2: z-GEMM + class_pre, BK=64 + st-swizzle (R9 best) =========
// 128x128 tile, BK=64 (8 K-steps), 32KB linear LDS staged via global_load_lds
// width=16 (8 issues/thread/step), 2 barriers per K-step. Bank-conflict fix per
// mistake #21 (both-sides-or-neither): LDS dest linear; global SOURCE 16B-chunk
// pre-swizzled cs = (l&7)^((l>>3)&7); ds_read applies the same XOR:
// chunk' = (ksub*4+quad) ^ (mrow&7). Measured: bank conflicts 0, 53.5 us.
// NOTE: three pipelining variants (ping-pong __syncthreads dbuf, counted
// vmcnt(8)+raw barrier) all REGRESSED vs this plain loop (64/81 us) -- matches
// the guide's m131-m140 null results; do not re-attempt at HIP source level.
// 2x2 waves, acc[4][4]; bijective XCD swizzle (1256 = 8*157); A-rows >= NN read
// workspace garbage and are never stored.
__global__ __launch_bounds__(256) void fused2(
    const f16* __restrict__ x1h, const f16* __restrict__ WzAt, f16* __restrict__ zh,
    const f16* __restrict__ hlrh, const f16* __restrict__ McatT,
    const int* __restrict__ degL, const int* __restrict__ degR,
    const float* __restrict__ bc1, const float* __restrict__ vB,
    const float* __restrict__ vL, const float* __restrict__ vR, f16* __restrict__ Ph)
{
  __shared__ __align__(16) f16 smem[16384];        // As 8192 f16 | Bs 8192 f16
  const int t = threadIdx.x;
  const int logical = (blockIdx.x & 7) * 157 + (blockIdx.x >> 3);
  const bool isZ = logical < 628;
  const int bb = isZ ? logical : logical - 628;
  const int wave = t >> 6, lane = t & 63;
  const int wr = wave >> 1, wc = wave & 1;
  const int quad = lane >> 4, mrow = lane & 15;
  const int m0 = (bb >> 2) * 128, n0 = (bb & 3) * 128;
  const f16* Bt = isZ ? WzAt : McatT;
  // staging geometry: issue i covers rows i*32 + wave*8 + (lane>>3), 8 chunks/row
  const int srow = wave * 8 + (lane >> 3);           // 0..31 within issue block
  const int cs = (lane & 7) ^ ((lane >> 3) & 7);     // swizzled source chunk
  f16* ldsA = smem + wave * 512;                     // + i*2048 per issue
  f16* ldsB = smem + 8192 + wave * 512;
  const int mswz = mrow & 7;                         // read-side XOR key

  f32x4 acc[4][4];
  f32x4 zero4 = {0.f, 0.f, 0.f, 0.f};
#pragma unroll
  for (int i = 0; i < 4; i++)
#pragma unroll
    for (int j = 0; j < 4; j++) acc[i][j] = zero4;

#pragma unroll 1
  for (int it = 0; it < 8; ++it) {
    const int k0 = it * 64;
#pragma unroll
    for (int i = 0; i < 4; i++) {
      const int garow = m0 + i * 32 + srow;
      const f16* gA;
      if (isZ) {
        gA = x1h + (size_t)garow * 512 + k0 + cs * 8;
      } else {
        const int roff = (k0 >> 8) ? NN : 0;         // K half selects L/R hlrh bank
        gA = hlrh + (size_t)(garow + roff) * 256 + (k0 & 255) + cs * 8;
      }
      gld_lds16(gA, ldsA + i * 2048);
      const f16* gB = Bt + (size_t)(n0 + i * 32 + srow) * 512 + k0 + cs * 8;
      gld_lds16(gB, ldsB + i * 2048);
    }
    __syncthreads();
#pragma unroll
    for (int ksub = 0; ksub < 2; ++ksub) {
      f16x8 af[4], bf[4];
#pragma unroll
      for (int mt = 0; mt < 4; mt++)
        af[mt] = *(const f16x8*)(smem + (wr * 64 + mt * 16 + mrow) * 64 +
                                 ((ksub * 4 + quad) ^ mswz) * 8);
#pragma unroll
      for (int nt = 0; nt < 4; nt++)
        bf[nt] = *(const f16x8*)(smem + 8192 + (wc * 64 + nt * 16 + mrow) * 64 +
                                 ((ksub * 4 + quad) ^ mswz) * 8);
#pragma unroll
      for (int mt = 0; mt < 4; mt++)
#pragma unroll
        for (int nt = 0; nt < 4; nt++)
          acc[mt][nt] = __builtin_amdgcn_mfma_f32_16x16x32_f16(af[mt], bf[nt], acc[mt][nt], 0, 0, 0);
    }
    __syncthreads();
  }
  if (isZ) {
#pragma unroll
    for (int mt = 0; mt < 4; mt++)
#pragma unroll
      for (int nt = 0; nt < 4; nt++) {
        int col = n0 + wc * 64 + nt * 16 + mrow;
#pragma unroll
        for (int reg = 0; reg < 4; reg++) {
          int row = m0 + wr * 64 + mt * 16 + quad * 4 + reg;
          if (row < NN) zh[(size_t)row * 512 + col] = (f16)acc[mt][nt][reg];
        }
      }
  } else {
#pragma unroll
    for (int mt = 0; mt < 4; mt++)
#pragma unroll
      for (int nt = 0; nt < 4; nt++) {
        int col = n0 + wc * 64 + nt * 16 + mrow;
        float bb2 = bc1[col] + vB[col];
        float vl = vL[col], vr = vR[col];
#pragma unroll
        for (int reg = 0; reg < 4; reg++) {
          int row = m0 + wr * 64 + mt * 16 + quad * 4 + reg;
          if (row >= NN) continue;
          float v = acc[mt][nt][reg] + bb2;
          if (degL[row] > 0) v += vl;
          if (degR[row] > 0) v += vr;
          Ph[(size_t)row * 512 + col] = (f16)v;
        }
      }
  }
}

// ---------------- MFMA output GEMM: out(f32)[M,133] = h2h @ Wc2t^T + bc2 -------------
__global__ __launch_bounds__(256) void mfma_out(
    const f16* __restrict__ A, const f16* __restrict__ Bt,
    const float* __restrict__ bias, float* __restrict__ C, int M)
{
  __shared__ __align__(16) f16 As[64][40];
  __shared__ __align__(16) f16 Bs[128][40];
  const int t = threadIdx.x;
  const int wave = t >> 6, lane = t & 63;
  const int quad = lane >> 4, mrow = lane & 15;
  const int m0 = blockIdx.y * 64, n0 = blockIdx.x * 128;
  f32x4 acc[4][2];
  f32x4 zero4 = {0.f, 0.f, 0.f, 0.f};
#pragma unroll
  for (int i = 0; i < 4; i++)
#pragma unroll
    for (int j = 0; j < 2; j++) acc[i][j] = zero4;
  const int ar = t >> 2, ac = (t & 3) * 8;
  for (int k0 = 0; k0 < 512; k0 += 32) {
    {
      int gm = m0 + ar;
      f16x8 v = {0, 0, 0, 0, 0, 0, 0, 0};
      if (gm < M) v = *(const f16x8*)(A + (size_t)gm * 512 + k0 + ac);
      *(f16x8*)&As[ar][ac] = v;
    }
#pragma unroll
    for (int i = 0; i < 2; i++) {
      int idx = t + i * 256;
      int r = idx >> 2, c = (idx & 3) * 8;
      f16x8 v = {0, 0, 0, 0, 0, 0, 0, 0};
      if (n0 + r < 133) v = *(const f16x8*)(Bt + (size_t)(n0 + r) * 512 + k0 + c);
      *(f16x8*)&Bs[r][c] = v;
    }
    __syncthreads();
    f16x8 af[4], bf[2];
#pragma unroll
    for (int mt = 0; mt < 4; mt++) af[mt] = *(const f16x8*)&As[mt * 16 + mrow][quad * 8];
#pragma unroll
    for (int nt = 0; nt < 2; nt++) bf[nt] = *(const f16x8*)&Bs[wave * 32 + nt * 16 + mrow][quad * 8];
#pragma unroll
    for (int mt = 0; mt < 4; mt++)
#pragma unroll
      for (int nt = 0; nt < 2; nt++)
        acc[mt][nt] = __builtin_amdgcn_mfma_f32_16x16x32_f16(af[mt], bf[nt], acc[mt][nt], 0, 0, 0);
    __syncthreads();
  }
#pragma unroll
  for (int mt = 0; mt < 4; mt++)
#pragma unroll
    for (int nt = 0; nt < 2; nt++) {
      int col = n0 + wave * 32 + nt * 16 + mrow;
      if (col >= 133) continue;
      float bb = bias[col];
#pragma unroll
      for (int reg = 0; reg < 4; reg++) {
        int row = m0 + mt * 16 + quad * 4 + reg;
        if (row < M) C[(size_t)row * 133 + col] = acc[mt][nt][reg] + bb;
      }
    }
}

// ------------- CSR scan (2 blocks; offA derived as offR + n) -------------------------
__global__ __launch_bounds__(1024) void scan_csr(
    const int* __restrict__ dL, const int* __restrict__ dR,
    int* __restrict__ oL, int* __restrict__ oR, int* __restrict__ oA)
{
  const int b = blockIdx.x;
  const int* deg = b == 0 ? dL : dR;
  __shared__ int part[1024];
  const int t = threadIdx.x;
  const int chunk = 20;
  int base = t * chunk;
  int sum = 0;
  for (int i = 0; i < chunk; i++) { int idx = base + i; if (idx < NN) sum += deg[idx]; }
  part[t] = sum;
  __syncthreads();
  for (int o = 1; o < 1024; o <<= 1) {
    int v = (t >= o) ? part[t - o] : 0;
    __syncthreads();
    part[t] += v;
    __syncthreads();
  }
  int run = part[t] - sum;
  if (b == 0) {
    for (int i = 0; i < chunk; i++) {
      int idx = base + i;
      if (idx < NN) { oL[idx] = run; run += deg[idx]; }
    }
    if (t == 0) oL[NN] = part[1023];
  } else {
    for (int i = 0; i < chunk; i++) {
      int idx = base + i;
      if (idx < NN) { oR[idx] = run; oA[idx] = run + idx; run += deg[idx]; }
    }
    if (t == 0) { oR[NN] = part[1023]; oA[NN] = part[1023] + NN; }
  }
}

// ------------- fill: 2 atomics/edge; self-loops atomic-free (slot 0 of A-segment) ----
__global__ __launch_bounds__(256) void fill_csr(
    const int* __restrict__ ei,
    const int* __restrict__ oL, const int* __restrict__ oR, const int* __restrict__ oA,
    int* __restrict__ cL, int* __restrict__ cR,
    int* __restrict__ eL, int* __restrict__ eR, int* __restrict__ snA)
{
  int e = blockIdx.x * 256 + threadIdx.x;
  if (e >= EE) return;
  if (e < NE) {
    int s = ei[e], d = ei[NE + e];
    int p = atomicAdd(&cL[s], 1); eL[oL[s] + p] = e;
    p = atomicAdd(&cR[d], 1);
    eR[oR[d] + p] = e;
    snA[oA[d] + 1 + p] = s;       // A-segment: [selfloop, dst-edges...]
  } else {
    int n = e - NE;
    snA[oA[n]] = n;
  }
}

// ------------- attention dot products, layer 1 ---------------------------------------
__global__ __launch_bounds__(256) void attn_dots1(
    const f16* __restrict__ xlh, const float* __restrict__ asrc,
    const float* __restrict__ adst, float* __restrict__ s, float* __restrict__ d)
{
  int gid = blockIdx.x * 256 + threadIdx.x;       // n*8 + h
  if (gid >= NN * NH) return;
  int n = gid >> 3, h = gid & 7;
  const f16x2* row = (const f16x2*)(xlh + (size_t)n * 512 + h * 64);
  const float* a1 = asrc + h * 64;
  const float* a2 = adst + h * 64;
  float ss = 0.f, dd = 0.f;
#pragma unroll 8
  for (int j = 0; j < 32; j++) {
    f16x2 p = row[j];
    float v0 = (float)p[0], v1 = (float)p[1];
    ss += v0 * a1[2 * j] + v1 * a1[2 * j + 1];
    dd += v0 * a2[2 * j] + v1 * a2[2 * j + 1];
  }
  s[gid] = ss; d[gid] = dd;
}

// ------------- GAT layer 1 gather: WAVE-per-node, no LDS, no barriers ----------------
__global__ __launch_bounds__(256) void gat_gather1(
    const int* __restrict__ snA, const int* __restrict__ offA,
    const float* __restrict__ s1, const float* __restrict__ d1,
    const f16* __restrict__ xlh, const float* __restrict__ b1,
    const float* __restrict__ ws2, const float* __restrict__ wd2,
    f16* __restrict__ x1h, float* __restrict__ s2, float* __restrict__ d2)
{
  const int t = threadIdx.x;
  const int wave = t >> 6, lane = t & 63;
  const int n = blockIdx.x * 4 + wave;             // 20000 = 5000*4 exact
  const int hf = lane >> 3;
  const float dnw = d1[n * 8 + hf];
  const int beg = offA[n], deg = offA[n + 1] - beg;
  float acc[8] = {0.f};
  float den = 0.f;
  for (int base = 0; base < deg; base += 64) {
    const int m = min(64, deg - base);
    int me = 0;
    if (lane < m) me = snA[beg + base + lane];
    const int ms = __builtin_amdgcn_readfirstlane(m);
    int s = 0;
    for (; s + 4 <= ms; s += 4) {
      int sn[4]; float sv[4]; f16x8 row[4];
#pragma unroll
      for (int u = 0; u < 4; u++) sn[u] = __builtin_amdgcn_readlane(me, s + u);
#pragma unroll
      for (int u = 0; u < 4; u++) sv[u] = s1[sn[u] * 8 + hf];
#pragma unroll
      for (int u = 0; u < 4; u++) row[u] = *(const f16x8*)(xlh + (size_t)sn[u] * 512 + lane * 8);
#pragma unroll
      for (int u = 0; u < 4; u++) {
        float w = __expf(lrelu(sv[u] + dnw));
        den += w;
#pragma unroll
        for (int j = 0; j < 8; j++) acc[j] = fmaf(w, (float)row[u][j], acc[j]);
      }
    }
    for (; s < ms; ++s) {
      int sn = __builtin_amdgcn_readlane(me, s);
      float sv = s1[sn * 8 + hf];
      f16x8 row = *(const f16x8*)(xlh + (size_t)sn * 512 + lane * 8);
      float w = __expf(lrelu(sv + dnw));
      den += w;
#pragma unroll
      for (int j = 0; j < 8; j++) acc[j] = fmaf(w, (float)row[j], acc[j]);
    }
  }
  const float rh = 1.f / (den + 1e-16f);
  float4 bv0 = *(const float4*)(b1 + lane * 8);
  float4 bv1 = *(const float4*)(b1 + lane * 8 + 4);
  float bb[8] = {bv0.x, bv0.y, bv0.z, bv0.w, bv1.x, bv1.y, bv1.z, bv1.w};
  float4 wsa = *(const float4*)(ws2 + lane * 8);
  float4 wsb = *(const float4*)(ws2 + lane * 8 + 4);
  float4 wda = *(const float4*)(wd2 + lane * 8);
  float4 wdb = *(const float4*)(wd2 + lane * 8 + 4);
  float wsv[8] = {wsa.x, wsa.y, wsa.z, wsa.w, wsb.x, wsb.y, wsb.z, wsb.w};
  float wdv[8] = {wda.x, wda.y, wda.z, wda.w, wdb.x, wdb.y, wdb.z, wdb.w};
  f16x8 o;
  float ps = 0.f, pd = 0.f;
#pragma unroll
  for (int j = 0; j < 8; j++) {
    float v = acc[j] * rh + bb[j];
    v = v > 0.f ? v : (__expf(v) - 1.f);
    o[j] = (f16)v;
    ps = fmaf(v, wsv[j], ps);
    pd = fmaf(v, wdv[j], pd);
  }
  *(f16x8*)(x1h + (size_t)n * 512 + lane * 8) = o;
#pragma unroll
  for (int off = 32; off > 0; off >>= 1) {
    ps += __shfl_xor(ps, off);
    pd += __shfl_xor(pd, off);
  }
  if (lane == 0) { s2[n] = ps; d2[n] = pd; }
}

// ------------- GAT layer 2 gather: WAVE-per-node, no LDS, no barriers ----------------
__global__ __launch_bounds__(256) void gat_gather2(
    const int* __restrict__ snA, const int* __restrict__ offA,
    const float* __restrict__ s2, const float* __restrict__ d2,
    const f16* __restrict__ zh, const f16* __restrict__ Ph,
    f16* __restrict__ h2h)
{
  const int t = threadIdx.x;
  const int wave = t >> 6, lane = t & 63;
  const int n = blockIdx.x * 4 + wave;             // 20000 = 5000*4 exact
  const float dn = d2[n];
  const int beg = offA[n], deg = offA[n + 1] - beg;
  float acc[8] = {0.f};
  float den = 0.f;
  for (int base = 0; base < deg; base += 64) {
    const int m = min(64, deg - base);
    int me = 0;
    if (lane < m) me = snA[beg + base + lane];
    const int ms = __builtin_amdgcn_readfirstlane(m);
    int s = 0;
    for (; s + 4 <= ms; s += 4) {
      int sn[4]; float sv[4]; f16x8 row[4];
#pragma unroll
      for (int u = 0; u < 4; u++) sn[u] = __builtin_amdgcn_readlane(me, s + u);
#pragma unroll
      for (int u = 0; u < 4; u++) sv[u] = s2[sn[u]];
#pragma unroll
      for (int u = 0; u < 4; u++) row[u] = *(const f16x8*)(zh + (size_t)sn[u] * 512 + lane * 8);
#pragma unroll
      for (int u = 0; u < 4; u++) {
        float w = __expf(lrelu(sv[u] + dn));
        den += w;
#pragma unroll
        for (int j = 0; j < 8; j++) acc[j] = fmaf(w, (float)row[u][j], acc[j]);
      }
    }
    for (; s < ms; ++s) {
      int sn = __builtin_amdgcn_readlane(me, s);
      float sv = s2[sn];
      f16x8 row = *(const f16x8*)(zh + (size_t)sn * 512 + lane * 8);
      float w = __expf(lrelu(sv + dn));
      den += w;
#pragma unroll
      for (int j = 0; j < 8; j++) acc[j] = fmaf(w, (float)row[j], acc[j]);
    }
  }
  const float rn = 1.f / (den + 1e-16f);
  f16x8 pv = *(const f16x8*)(Ph + (size_t)n * 512 + lane * 8);
  f16x8 o;
#pragma unroll
  for (int j = 0; j < 8; j++) {
    float v = fmaxf(acc[j] * rn + (float)pv[j], 0.f);
    o[j] = (f16)v;
  }
  *(f16x8*)(h2h + (size_t)n * 512 + lane * 8) = o;
}

extern "C" void kernel_launch(void* const* d_in, const int* in_sizes, int n_in,
                              void* d_out, int out_size, void* d_ws, size_t ws_size,
                              hipStream_t stream) {
  const int*   edge_index = (const int*)d_in[0];
  const float* synapse    = (const float*)d_in[2];
  const float* x_param = (const float*)d_in[5];
  const float* W1      = (const float*)d_in[6];
  const float* as1     = (const float*)d_in[7];
  const float* ad1     = (const float*)d_in[8];
  const float* b1      = (const float*)d_in[9];
  const float* W2      = (const float*)d_in[10];
  const float* as2     = (const float*)d_in[11];
  const float* ad2     = (const float*)d_in[12];
  const float* b2      = (const float*)d_in[13];
  const float* We1     = (const float*)d_in[14];
  const float* be1     = (const float*)d_in[15];
  const float* We2     = (const float*)d_in[16];
  const float* be2     = (const float*)d_in[17];
  const float* Wc1     = (const float*)d_in[18];
  const float* bc1     = (const float*)d_in[19];
  const float* Wc2     = (const float*)d_in[20];
  const float* bc2     = (const float*)d_in[21];
  float* out_p = (float*)d_out;

  // ---- workspace layout (~125 MB) ----
  char* p = (char*)d_ws;
  float* xp    = (float*)p; p += (size_t)NE * 6 * 4;
  float* s1    = (float*)p; p += (size_t)NN * 8 * 4;
  float* d1    = (float*)p; p += (size_t)NN * 8 * 4;
  float* s2    = (float*)p; p += (size_t)NN * 4;
  float* d2    = (float*)p; p += (size_t)NN * 4;
  float* vB    = (float*)p; p += 512 * 4;
  float* vL    = (float*)p; p += 512 * 4;
  float* vR    = (float*)p; p += 512 * 4;
  float* ws2   = (float*)p; p += 512 * 4;
  float* wd2   = (float*)p; p += 512 * 4;
  f16* xph     = (f16*)p; p += (size_t)NN * FEAT * 2;
  f16* xl1h    = (f16*)p; p += (size_t)NN * 512 * 2;
  f16* x1h     = (f16*)p; p += (size_t)NN * 512 * 2;
  f16* zh      = (f16*)p; p += (size_t)NN * 512 * 2;
  f16* h2h     = (f16*)p; p += (size_t)NN * 512 * 2;
  f16* Phb     = (f16*)p; p += (size_t)NN * 512 * 2;
  f16* hlrh    = (f16*)p; p += (size_t)2 * NN * 256 * 2;
  f16* W1t     = (f16*)p; p += (size_t)512 * FEAT * 2;
  f16* WzAt    = (f16*)p; p += (size_t)512 * 512 * 2;
  f16* McatT   = (f16*)p; p += (size_t)512 * 512 * 2;
  f16* Wc2t    = (f16*)p; p += (size_t)133 * 512 * 2;
  int* degL    = (int*)p;                 // N  (zero group start)
  int* degR    = degL + NN;               // N
  int* curL    = degR + NN;               // N
  int* curR    = curL + NN;               // N  (zero group: 4N ints)
  int* offL    = curR + NN;               // N+1
  int* offR    = offL + NN + 1;           // N+1
  int* offA    = offR + NN + 1;           // N+1
  int* edgeL   = offA + NN + 1;           // E
  int* edgeR   = edgeL + NE;              // E
  int* snA     = edgeR + NE;              // EE

  hipMemsetAsync(degL, 0, (size_t)4 * NN * sizeof(int), stream);

  preamble<<<QB5, 256, 0, stream>>>(
      edge_index, synapse, W1, x_param, W2, We2, Wc1, Wc2, b2, be2, as2, ad2,
      degL, degR, xp, W1t, xph, WzAt, McatT, Wc2t, vB, vL, vR, ws2, wd2);
  scan_csr<<<2, 1024, 0, stream>>>(degL, degR, offL, offR, offA);
  fill_csr<<<(EE + 255) / 256, 256, 0, stream>>>(edge_index, offL, offR, offA,
                                                 curL, curR, edgeL, edgeR, snA);
  fused1<<<1252 + 2500, 256, 0, stream>>>(xph, W1t, xl1h, xp, We1, be1,
                                          offL, edgeL, offR, edgeR, hlrh);
  attn_dots1<<<(NN * NH + 255) / 256, 256, 0, stream>>>(xl1h, as1, ad1, s1, d1);
  gat_gather1<<<5000, 256, 0, stream>>>(snA, offA, s1, d1, xl1h, b1, ws2, wd2,
                                        x1h, s2, d2);
  fused2<<<1256, 256, 0, stream>>>(x1h, WzAt, zh, hlrh, McatT,
                                   degL, degR, bc1, vB, vL, vR, Phb);
  gat_gather2<<<5000, 256, 0, stream>>>(snA, offA, s2, d2, zh, Phb, h2h);
  mfma_out<<<dim3(2, 313), 256, 0, stream>>>(h2h, Wc2t, bc2, out_p, NN);
}

// Round 13
// 401.140 us; speedup vs baseline: 1.0592x; 1.0266x over previous
//
#include <hip/hip_runtime.h>
#include <cstddef>

// Problem constants (fixed by setup_inputs)
#define NN   20000     // nodes
#define FEAT 128
#define NH   8         // heads layer 1
#define NE   200000    // edges
#define EE   220000    // edges + self loops

typedef _Float16 f16;
typedef _Float16 f16x2 __attribute__((ext_vector_type(2)));
typedef _Float16 f16x4 __attribute__((ext_vector_type(4)));
typedef _Float16 f16x8 __attribute__((ext_vector_type(8)));
typedef float    f32x4 __attribute__((ext_vector_type(4)));

__device__ __forceinline__ float lrelu(float a) { return a > 0.f ? a : 0.2f * a; }
__device__ __forceinline__ float rdlane(float v, int l) {
  return __int_as_float(__builtin_amdgcn_readlane(__float_as_int(v), l));
}
// async global->LDS, 16B per lane; LDS dest = wave-uniform base + lane*16
__device__ __forceinline__ void gld_lds16(const f16* g, f16* l) {
  __builtin_amdgcn_global_load_lds(
      (const __attribute__((address_space(1))) void*)g,
      (__attribute__((address_space(3))) void*)l, 16, 0, 0);
}

// ================= preamble: ALL input-only precompute in one launch =================
// Ordered longest-latency-first so small late sections hide under the bulk:
// [0,QB0) gemm3in1 | [QB0,QB1) small_vec | [QB1,QB2) Wc2t | [QB2,QB3) W1t |
// [QB3,QB4) maxpool+count_deg (fused edge pass) | [QB4,QB5) xph cvt x8
#define QB0 128
#define QB1 (QB0 + 8)
#define QB2 (QB1 + 80)
#define QB3 (QB2 + 64)
#define QB4 (QB3 + 782)
#define QB5 (QB4 + 1250)
__global__ __launch_bounds__(256) void preamble(
    const int* __restrict__ ei, const float* __restrict__ syn,
    const float* __restrict__ W1, const float* __restrict__ xparam,
    const float* __restrict__ W2, const float* __restrict__ We2,
    const float* __restrict__ Wc1, const float* __restrict__ Wc2,
    const float* __restrict__ b2, const float* __restrict__ be2,
    const float* __restrict__ as2, const float* __restrict__ ad2,
    int* __restrict__ dL, int* __restrict__ dR,
    float* __restrict__ xp, f16* __restrict__ W1t, f16* __restrict__ xph,
    f16* __restrict__ WzAt, f16* __restrict__ McatT, f16* __restrict__ Wc2t,
    float* __restrict__ vB, float* __restrict__ vL, float* __restrict__ vR,
    float* __restrict__ ws2, float* __restrict__ wd2)
{
  __shared__ float smem[2112];
  const int b = blockIdx.x, t = threadIdx.x;
  if (b < QB0) {                                   // ---- gemm3in1 (folded weights) ----
    float (*As)[68] = (float(*)[68])smem;
    float (*Bs)[64] = (float(*)[64])(smem + 16 * 68);
    const int bb = b;
    const float* A; const float* B; f16* dst; int dstOff, m0, n0;
    if (bb < 64)      { A = W2;  B = Wc1;  dst = WzAt;  dstOff = 0;
                        m0 = (bb >> 3) * 64; n0 = (bb & 7) * 64; }
    else if (bb < 96) { int i = bb - 64; A = We2; B = Wc1 + (size_t)512 * 512;
                        dst = McatT; dstOff = 0;
                        m0 = (i >> 3) * 64; n0 = (i & 7) * 64; }
    else              { int i = bb - 96; A = We2; B = Wc1 + (size_t)1024 * 512;
                        dst = McatT; dstOff = 256;
                        m0 = (i >> 3) * 64; n0 = (i & 7) * 64; }
    const int tx = t & 15, ty = t >> 4;
    float acc[4][4] = {{0.f}};
    float pa[4], pb[4];
#pragma unroll
    for (int i = 0; i < 4; i++) {
      int idx = t + i * 256;
      pa[i] = A[(size_t)(m0 + (idx >> 4)) * 512 + (idx & 15)];
      pb[i] = B[(size_t)(idx >> 6) * 512 + n0 + (idx & 63)];
    }
    for (int k0 = 0; k0 < 512; k0 += 16) {
#pragma unroll
      for (int i = 0; i < 4; i++) {
        int idx = t + i * 256;
        As[idx & 15][idx >> 4] = pa[i];
        Bs[idx >> 6][idx & 63] = pb[i];
      }
      __syncthreads();
      if (k0 + 16 < 512) {
        int kn = k0 + 16;
#pragma unroll
        for (int i = 0; i < 4; i++) {
          int idx = t + i * 256;
          pa[i] = A[(size_t)(m0 + (idx >> 4)) * 512 + kn + (idx & 15)];
          pb[i] = B[(size_t)(kn + (idx >> 6)) * 512 + n0 + (idx & 63)];
        }
      }
#pragma unroll
      for (int kk = 0; kk < 16; kk++) {
        float4 a4 = *(const float4*)&As[kk][ty * 4];
        float4 b4 = *(const float4*)&Bs[kk][tx * 4];
        float av[4] = {a4.x, a4.y, a4.z, a4.w};
        float bv[4] = {b4.x, b4.y, b4.z, b4.w};
#pragma unroll
        for (int i = 0; i < 4; i++)
#pragma unroll
          for (int j = 0; j < 4; j++) acc[i][j] = fmaf(av[i], bv[j], acc[i][j]);
      }
      __syncthreads();
    }
#pragma unroll
    for (int i = 0; i < 4; i++)
#pragma unroll
      for (int j = 0; j < 4; j++)
        dst[(size_t)(n0 + tx * 4 + j) * 512 + dstOff + m0 + ty * 4 + i] = (f16)acc[i][j];
  } else if (b < QB1) {                            // ---- small_vec (4 segs) ----
    int g = (b - QB0) * 256 + t;
    int seg = g >> 9, j = g & 511;
    if (seg == 0) {
      float a = 0.f;
      for (int k = 0; k < 512; k++) a = fmaf(b2[k], Wc1[(size_t)k * 512 + j], a);
      vB[j] = a;
    } else if (seg == 1) {
      float a = 0.f;
      for (int k = 0; k < 512; k++) a = fmaf(be2[k], Wc1[(size_t)(512 + k) * 512 + j], a);
      vL[j] = a;
    } else if (seg == 2) {
      float a = 0.f;
      for (int k = 0; k < 512; k++) a = fmaf(be2[k], Wc1[(size_t)(1024 + k) * 512 + j], a);
      vR[j] = a;
    } else {
      float a = 0.f, c2 = 0.f;
      for (int c = 0; c < 512; c++) {
        float w = W2[(size_t)j * 512 + c];
        a = fmaf(w, as2[c], a);
        c2 = fmaf(w, ad2[c], c2);
      }
      ws2[j] = a; wd2[j] = c2;
    }
  } else if (b < QB2) {                            // ---- Wc2 transpose-cvt ----
    float (*tile)[33] = (float(*)[33])smem;
    int i0 = b - QB1;                              // 80 blocks: 5 n-tiles x 16 k-tiles
    const int n0 = (i0 % 5) * 32, k0 = (i0 / 5) * 32;
    const int tx = t & 31, ty = t >> 5;
#pragma unroll
    for (int i = 0; i < 4; i++) {
      int k = k0 + ty + i * 8, n = n0 + tx;
      tile[ty + i * 8][tx] = (n < 133) ? Wc2[(size_t)k * 133 + n] : 0.f;
    }
    __syncthreads();
#pragma unroll
    for (int i = 0; i < 4; i++) {
      int n = n0 + ty + i * 8, k = k0 + tx;
      if (n < 133) Wc2t[(size_t)n * 512 + k] = (f16)tile[tx][ty + i * 8];
    }
  } else if (b < QB3) {                            // ---- W1 transpose-cvt ----
    float (*tile)[33] = (float(*)[33])smem;
    int bb = b - QB2;
    const int n0 = (bb & 15) * 32, k0 = (bb >> 4) * 32;
    const int tx = t & 31, ty = t >> 5;
#pragma unroll
    for (int i = 0; i < 4; i++)
      tile[ty + i * 8][tx] = W1[(size_t)(k0 + ty + i * 8) * 512 + n0 + tx];
    __syncthreads();
#pragma unroll
    for (int i = 0; i < 4; i++)
      W1t[(size_t)(n0 + ty + i * 8) * 128 + k0 + tx] = (f16)tile[tx][ty + i * 8];
  } else if (b < QB4) {                            // ---- maxpool + count_deg fused ----
    int e = (b - QB3) * 256 + t;
    if (e >= NE) return;
    const float* p = syn + (size_t)e * 24;
    float v[24];
#pragma unroll
    for (int i = 0; i < 6; i++) {
      float4 q = *(const float4*)(p + i * 4);
      v[i*4+0] = q.x; v[i*4+1] = q.y; v[i*4+2] = q.z; v[i*4+3] = q.w;
    }
#pragma unroll
    for (int dd = 0; dd < 6; dd++)
      xp[(size_t)e * 6 + dd] = fmaxf(fmaxf(v[dd], v[6 + dd]), fmaxf(v[12 + dd], v[18 + dd]));
    atomicAdd(&dL[ei[e]], 1);
    atomicAdd(&dR[ei[NE + e]], 1);
  } else {                                         // ---- xph cvt, 8 elem/thread ----
    int idx = ((b - QB4) * 256 + t) * 8;           // NN*FEAT = 2,560,000 = 1250*2048
    float4 q0 = *(const float4*)(xparam + idx);
    float4 q1 = *(const float4*)(xparam + idx + 4);
    f16x8 o;
    o[0] = (f16)q0.x; o[1] = (f16)q0.y; o[2] = (f16)q0.z; o[3] = (f16)q0.w;
    o[4] = (f16)q1.x; o[5] = (f16)q1.y; o[6] = (f16)q1.z; o[7] = (f16)q1.w;
    *(f16x8*)(xph + idx) = o;
  }
}

// ================= fused1: xl1 MFMA-GEMM + FUSED attn dots + h1 readlane gather ======
// GEMM epilogue now computes s1/d1 directly from the f32 accumulators:
// each block's 128-col tile spans exactly 2 complete heads (h = n0/64 + (wave>>1));
// within a wave, cols live across the 16 mrow-lanes (shfl_xor 1/2/4/8 reduce) and
// the two waves of a head pair combine through 1KB of reused smem. This deletes
// the separate attn_dots1 kernel (20.5MB re-read + one launch).
__global__ __launch_bounds__(256) void fused1(
    const f16* __restrict__ xph, const f16* __restrict__ W1t, f16* __restrict__ xl1h,
    const float* __restrict__ xp, const float* __restrict__ We1,
    const float* __restrict__ be1,
    const int* __restrict__ oL, const int* __restrict__ eL,
    const int* __restrict__ oR, const int* __restrict__ eR,
    f16* __restrict__ hlrh,
    const float* __restrict__ as1, const float* __restrict__ ad1,
    float* __restrict__ s1, float* __restrict__ d1)
{
  __shared__ __align__(16) f16 smem[7680];
  const int t = threadIdx.x;
  if (blockIdx.x < 1252) {
    f16 (*As)[40] = (f16(*)[40])smem;
    f16 (*Bs)[40] = (f16(*)[40])(smem + 64 * 40);
    const int wave = t >> 6, lane = t & 63;
    const int quad = lane >> 4, mrow = lane & 15;
    const int m0 = (blockIdx.x >> 2) * 64, n0 = (blockIdx.x & 3) * 128;
    f32x4 acc[4][2];
    f32x4 zero4 = {0.f, 0.f, 0.f, 0.f};
#pragma unroll
    for (int i = 0; i < 4; i++)
#pragma unroll
      for (int j = 0; j < 2; j++) acc[i][j] = zero4;
    const int ar = t >> 2, ac = (t & 3) * 8;
    for (int k0 = 0; k0 < FEAT; k0 += 32) {
      {
        int gm = m0 + ar;
        f16x8 v = {0, 0, 0, 0, 0, 0, 0, 0};
        if (gm < NN) v = *(const f16x8*)(xph + (size_t)gm * FEAT + k0 + ac);
        *(f16x8*)&As[ar][ac] = v;
      }
#pragma unroll
      for (int i = 0; i < 2; i++) {
        int idx = t + i * 256;
        int r = idx >> 2, c = (idx & 3) * 8;
        *(f16x8*)&Bs[r][c] = *(const f16x8*)(W1t + (size_t)(n0 + r) * FEAT + k0 + c);
      }
      __syncthreads();
      f16x8 af[4], bf[2];
#pragma unroll
      for (int mt = 0; mt < 4; mt++) af[mt] = *(const f16x8*)&As[mt * 16 + mrow][quad * 8];
#pragma unroll
      for (int nt = 0; nt < 2; nt++) bf[nt] = *(const f16x8*)&Bs[wave * 32 + nt * 16 + mrow][quad * 8];
#pragma unroll
      for (int mt = 0; mt < 4; mt++)
#pragma unroll
        for (int nt = 0; nt < 2; nt++)
          acc[mt][nt] = __builtin_amdgcn_mfma_f32_16x16x32_f16(af[mt], bf[nt], acc[mt][nt], 0, 0, 0);
      __syncthreads();
    }
#pragma unroll
    for (int mt = 0; mt < 4; mt++)
#pragma unroll
      for (int nt = 0; nt < 2; nt++) {
        int col = n0 + wave * 32 + nt * 16 + mrow;
#pragma unroll
        for (int reg = 0; reg < 4; reg++) {
          int row = m0 + mt * 16 + quad * 4 + reg;
          if (row < NN) xl1h[(size_t)row * 512 + col] = (f16)acc[mt][nt][reg];
        }
      }
    // ---- fused attn dots: s1/d1 for this block's 64 rows x 2 heads ----
    const int h = (n0 >> 6) + (wave >> 1);           // heads n0/64, n0/64+1
    float a1v[2], a2v[2];
#pragma unroll
    for (int nt = 0; nt < 2; nt++) {
      int cw = ((wave & 1) << 5) + nt * 16 + mrow;   // col within head [0,64)
      a1v[nt] = as1[h * 64 + cw];
      a2v[nt] = ad1[h * 64 + cw];
    }
    float myS[16], myD[16];
#pragma unroll
    for (int mt = 0; mt < 4; mt++)
#pragma unroll
      for (int reg = 0; reg < 4; reg++) {
        float ps = acc[mt][0][reg] * a1v[0] + acc[mt][1][reg] * a1v[1];
        float pd = acc[mt][0][reg] * a2v[0] + acc[mt][1][reg] * a2v[1];
        ps += __shfl_xor(ps, 1);  pd += __shfl_xor(pd, 1);
        ps += __shfl_xor(ps, 2);  pd += __shfl_xor(pd, 2);
        ps += __shfl_xor(ps, 4);  pd += __shfl_xor(pd, 4);
        ps += __shfl_xor(ps, 8);  pd += __shfl_xor(pd, 8);
        myS[mt * 4 + reg] = ps;   myD[mt * 4 + reg] = pd;
      }
    float* sred = (float*)smem;                      // reuse LDS (post-K-loop barrier)
    float* dred = sred + 128;                        // [2 heads][64 rows] each
    __syncthreads();
    if ((wave & 1) == 0 && mrow == 0) {
#pragma unroll
      for (int mt = 0; mt < 4; mt++)
#pragma unroll
        for (int reg = 0; reg < 4; reg++) {
          int rr = mt * 16 + quad * 4 + reg;
          sred[(wave >> 1) * 64 + rr] = myS[mt * 4 + reg];
          dred[(wave >> 1) * 64 + rr] = myD[mt * 4 + reg];
        }
    }
    __syncthreads();
    if ((wave & 1) == 1 && mrow == 0) {
#pragma unroll
      for (int mt = 0; mt < 4; mt++)
#pragma unroll
        for (int reg = 0; reg < 4; reg++) {
          int rr = mt * 16 + quad * 4 + reg;
          int row = m0 + rr;
          if (row < NN) {
            s1[row * 8 + h] = myS[mt * 4 + reg] + sred[(wave >> 1) * 64 + rr];
            d1[row * 8 + h] = myD[mt * 4 + reg] + dred[(wave >> 1) * 64 + rr];
          }
        }
    }
  } else {
    // ---- h1 mean-gather: readlane broadcast, 4 node-sides per wave ----
    const int wave = t >> 6, lane = t & 63;
    const int w = (blockIdx.x - 1252) * 4 + wave;        // 0..9999
    float4 wv[6];
#pragma unroll
    for (int j = 0; j < 6; j++) wv[j] = *(const float4*)(We1 + j * 256 + 4 * lane);
    const float4 bv = *(const float4*)(be1 + 4 * lane);
#pragma unroll 1
    for (int i = 0; i < 4; i++) {
      const int b = w + i * 10000;                       // node-side in [0, 2*NN)
      const int* off; const int* lst; int n;
      if (b < NN) { off = oL; lst = eL; n = b; } else { off = oR; lst = eR; n = b - NN; }
      const int beg = off[n], deg = off[n + 1] - beg;
      float a0 = 0.f, a1 = 0.f, a2 = 0.f, a3 = 0.f;
      for (int base = 0; base < deg; base += 32) {
        const int m = min(32, deg - base);
        float x0 = 0.f, x1 = 0.f, x2 = 0.f, x3 = 0.f, x4 = 0.f, x5 = 0.f;
        if (lane < m) {
          const int e = lst[beg + base + lane];
          const float* pr = xp + (size_t)e * 6;
          float2 p0 = *(const float2*)pr;
          float2 p1 = *(const float2*)(pr + 2);
          float2 p2 = *(const float2*)(pr + 4);
          x0 = p0.x; x1 = p0.y; x2 = p1.x; x3 = p1.y; x4 = p2.x; x5 = p2.y;
        }
        const int ms = __builtin_amdgcn_readfirstlane(m);
        for (int s = 0; s < ms; s++) {
          const float f0 = rdlane(x0, s), f1 = rdlane(x1, s), f2 = rdlane(x2, s);
          const float f3 = rdlane(x3, s), f4 = rdlane(x4, s), f5 = rdlane(x5, s);
          float v0 = bv.x, v1 = bv.y, v2 = bv.z, v3 = bv.w;
          v0 = fmaf(f0, wv[0].x, v0); v1 = fmaf(f0, wv[0].y, v1);
          v2 = fmaf(f0, wv[0].z, v2); v3 = fmaf(f0, wv[0].w, v3);
          v0 = fmaf(f1, wv[1].x, v0); v1 = fmaf(f1, wv[1].y, v1);
          v2 = fmaf(f1, wv[1].z, v2); v3 = fmaf(f1, wv[1].w, v3);
          v0 = fmaf(f2, wv[2].x, v0); v1 = fmaf(f2, wv[2].y, v1);
          v2 = fmaf(f2, wv[2].z, v2); v3 = fmaf(f2, wv[2].w, v3);
          v0 = fmaf(f3, wv[3].x, v0); v1 = fmaf(f3, wv[3].y, v1);
          v2 = fmaf(f3, wv[3].z, v2); v3 = fmaf(f3, wv[3].w, v3);
          v0 = fmaf(f4, wv[4].x, v0); v1 = fmaf(f4, wv[4].y, v1);
          v2 = fmaf(f4, wv[4].z, v2); v3 = fmaf(f4, wv[4].w, v3);
          v0 = fmaf(f5, wv[5].x, v0); v1 = fmaf(f5, wv[5].y, v1);
          v2 = fmaf(f5, wv[5].z, v2); v3 = fmaf(f5, wv[5].w, v3);
          a0 += fmaxf(v0, 0.f); a1 += fmaxf(v1, 0.f);
          a2 += fmaxf(v2, 0.f); a3 += fmaxf(v3, 0.f);
        }
      }
      const float rn = deg > 0 ? 1.f / (float)deg : 0.f;
      f16x4 o;
      o[0] = (f16)(a0 * rn); o[1] = (f16)(a1 * rn);
      o[2] = (f16)(a2 * rn); o[3] = (f16)(a3 * rn);
      *(f16x4*)(hlrh + (size_t)b * 256 + 4 * lane) = o;
    }
  }
}

// ================= fused2: z-GEMM + class_pre, BK=64 + st-swizzle (R9 best) =========
// 128x128 tile, BK=64 (8 K-steps), 32KB linear LDS staged via global_load_lds
// width=16, 2 barriers per K-step; source/read XOR swizzle (bank-conflict 0).
// NOTE: pipelining variants (dbuf __syncthreads, counted vmcnt+raw barrier) all
// REGRESSED vs this plain loop -- matches guide m131-m140; do not re-attempt.
__global__ __launch_bounds__(256) void fused2(
    const f16* __restrict__ x1h, const f16* __restrict__ WzAt, f16* __restrict__ zh,
    const f16* __restrict__ hlrh, const f16* __restrict__ McatT,
    const int* __restrict__ degL, const int* __restrict__ degR,
    const float* __restrict__ bc1, const float* __restrict__ vB,
    const float* __restrict__ vL, const float* __restrict__ vR, f16* __restrict__ Ph)
{
  __shared__ __align__(16) f16 smem[16384];        // As 8192 f16 | Bs 8192 f16
  const int t = threadIdx.x;
  const int logical = (blockIdx.x & 7) * 157 + (blockIdx.x >> 3);
  const bool isZ = logical < 628;
  const int bb = isZ ? logical : logical - 628;
  const int wave = t >> 6, lane = t & 63;
  const int wr = wave >> 1, wc = wave & 1;
  const int quad = lane >> 4, mrow = lane & 15;
  const int m0 = (bb >> 2) * 128, n0 = (bb & 3) * 128;
  const f16* Bt = isZ ? WzAt : McatT;
  const int srow = wave * 8 + (lane >> 3);           // 0..31 within issue block
  const int cs = (lane & 7) ^ ((lane >> 3) & 7);     // swizzled source chunk
  f16* ldsA = smem + wave * 512;                     // + i*2048 per issue
  f16* ldsB = smem + 8192 + wave * 512;
  const int mswz = mrow & 7;                         // read-side XOR key

  f32x4 acc[4][4];
  f32x4 zero4 = {0.f, 0.f, 0.f, 0.f};
#pragma unroll
  for (int i = 0; i < 4; i++)
#pragma unroll
    for (int j = 0; j < 4; j++) acc[i][j] = zero4;

#pragma unroll 1
  for (int it = 0; it < 8; ++it) {
    const int k0 = it * 64;
#pragma unroll
    for (int i = 0; i < 4; i++) {
      const int garow = m0 + i * 32 + srow;
      const f16* gA;
      if (isZ) {
        gA = x1h + (size_t)garow * 512 + k0 + cs * 8;
      } else {
        const int roff = (k0 >> 8) ? NN : 0;         // K half selects L/R hlrh bank
        gA = hlrh + (size_t)(garow + roff) * 256 + (k0 & 255) + cs * 8;
      }
      gld_lds16(gA, ldsA + i * 2048);
      const f16* gB = Bt + (size_t)(n0 + i * 32 + srow) * 512 + k0 + cs * 8;
      gld_lds16(gB, ldsB + i * 2048);
    }
    __syncthreads();
#pragma unroll
    for (int ksub = 0; ksub < 2; ++ksub) {
      f16x8 af[4], bf[4];
#pragma unroll
      for (int mt = 0; mt < 4; mt++)
        af[mt] = *(const f16x8*)(smem + (wr * 64 + mt * 16 + mrow) * 64 +
                                 ((ksub * 4 + quad) ^ mswz) * 8);
#pragma unroll
      for (int nt = 0; nt < 4; nt++)
        bf[nt] = *(const f16x8*)(smem + 8192 + (wc * 64 + nt * 16 + mrow) * 64 +
                                 ((ksub * 4 + quad) ^ mswz) * 8);
#pragma unroll
      for (int mt = 0; mt < 4; mt++)
#pragma unroll
        for (int nt = 0; nt < 4; nt++)
          acc[mt][nt] = __builtin_amdgcn_mfma_f32_16x16x32_f16(af[mt], bf[nt], acc[mt][nt], 0, 0, 0);
    }
    __syncthreads();
  }
  if (isZ) {
#pragma unroll
    for (int mt = 0; mt < 4; mt++)
#pragma unroll
      for (int nt = 0; nt < 4; nt++) {
        int col = n0 + wc * 64 + nt * 16 + mrow;
#pragma unroll
        for (int reg = 0; reg < 4; reg++) {
          int row = m0 + wr * 64 + mt * 16 + quad * 4 + reg;
          if (row < NN) zh[(size_t)row * 512 + col] = (f16)acc[mt][nt][reg];
        }
      }
  } else {
#pragma unroll
    for (int mt = 0; mt < 4; mt++)
#pragma unroll
      for (int nt = 0; nt < 4; nt++) {
        int col = n0 + wc * 64 + nt * 16 + mrow;
        float bb2 = bc1[col] + vB[col];
        float vl = vL[col], vr = vR[col];
#pragma unroll
        for (int reg = 0; reg < 4; reg++) {
          int row = m0 + wr * 64 + mt * 16 + quad * 4 + reg;
          if (row >= NN) continue;
          float v = acc[mt][nt][reg] + bb2;
          if (degL[row] > 0) v += vl;
          if (degR[row] > 0) v += vr;
          Ph[(size_t)row * 512 + col] = (f16)v;
        }
      }
  }
}

// ---------------- MFMA output GEMM: out(f32)[M,133] = h2h @ Wc2t^T + bc2 -------------
__global__ __launch_bounds__(256) void mfma_out(
    const f16* __restrict__ A, const f16* __restrict__ Bt,
    const float* __restrict__ bias, float* __restrict__ C, int M)
{
  __shared__ __align__(16) f16 As[64][40];
  __shared__ __align__(16) f16 Bs[128][40];
  const int t = threadIdx.x;
  const int wave = t >> 6, lane = t & 63;
  const int quad = lane >> 4, mrow = lane & 15;
  const int m0 = blockIdx.y * 64, n0 = blockIdx.x * 128;
  f32x4 acc[4][2];
  f32x4 zero4 = {0.f, 0.f, 0.f, 0.f};
#pragma unroll
  for (int i = 0; i < 4; i++)
#pragma unroll
    for (int j = 0; j < 2; j++) acc[i][j] = zero4;
  const int ar = t >> 2, ac = (t & 3) * 8;
  for (int k0 = 0; k0 < 512; k0 += 32) {
    {
      int gm = m0 + ar;
      f16x8 v = {0, 0, 0, 0, 0, 0, 0, 0};
      if (gm < M) v = *(const f16x8*)(A + (size_t)gm * 512 + k0 + ac);
      *(f16x8*)&As[ar][ac] = v;
    }
#pragma unroll
    for (int i = 0; i < 2; i++) {
      int idx = t + i * 256;
      int r = idx >> 2, c = (idx & 3) * 8;
      f16x8 v = {0, 0, 0, 0, 0, 0, 0, 0};
      if (n0 + r < 133) v = *(const f16x8*)(Bt + (size_t)(n0 + r) * 512 + k0 + c);
      *(f16x8*)&Bs[r][c] = v;
    }
    __syncthreads();
    f16x8 af[4], bf[2];
#pragma unroll
    for (int mt = 0; mt < 4; mt++) af[mt] = *(const f16x8*)&As[mt * 16 + mrow][quad * 8];
#pragma unroll
    for (int nt = 0; nt < 2; nt++) bf[nt] = *(const f16x8*)&Bs[wave * 32 + nt * 16 + mrow][quad * 8];
#pragma unroll
    for (int mt = 0; mt < 4; mt++)
#pragma unroll
      for (int nt = 0; nt < 2; nt++)
        acc[mt][nt] = __builtin_amdgcn_mfma_f32_16x16x32_f16(af[mt], bf[nt], acc[mt][nt], 0, 0, 0);
    __syncthreads();
  }
#pragma unroll
  for (int mt = 0; mt < 4; mt++)
#pragma unroll
    for (int nt = 0; nt < 2; nt++) {
      int col = n0 + wave * 32 + nt * 16 + mrow;
      if (col >= 133) continue;
      float bb = bias[col];
#pragma unroll
      for (int reg = 0; reg < 4; reg++) {
        int row = m0 + mt * 16 + quad * 4 + reg;
        if (row < M) C[(size_t)row * 133 + col] = acc[mt][nt][reg] + bb;
      }
    }
}

// ------------- CSR scan (2 blocks; offA derived as offR + n) -------------------------
__global__ __launch_bounds__(1024) void scan_csr(
    const int* __restrict__ dL, const int* __restrict__ dR,
    int* __restrict__ oL, int* __restrict__ oR, int* __restrict__ oA)
{
  const int b = blockIdx.x;
  const int* deg = b == 0 ? dL : dR;
  __shared__ int part[1024];
  const int t = threadIdx.x;
  const int chunk = 20;
  int base = t * chunk;
  int sum = 0;
  for (int i = 0; i < chunk; i++) { int idx = base + i; if (idx < NN) sum += deg[idx]; }
  part[t] = sum;
  __syncthreads();
  for (int o = 1; o < 1024; o <<= 1) {
    int v = (t >= o) ? part[t - o] : 0;
    __syncthreads();
    part[t] += v;
    __syncthreads();
  }
  int run = part[t] - sum;
  if (b == 0) {
    for (int i = 0; i < chunk; i++) {
      int idx = base + i;
      if (idx < NN) { oL[idx] = run; run += deg[idx]; }
    }
    if (t == 0) oL[NN] = part[1023];
  } else {
    for (int i = 0; i < chunk; i++) {
      int idx = base + i;
      if (idx < NN) { oR[idx] = run; oA[idx] = run + idx; run += deg[idx]; }
    }
    if (t == 0) { oR[NN] = part[1023]; oA[NN] = part[1023] + NN; }
  }
}

// ------------- fill: 2 atomics/edge; self-loops atomic-free (slot 0 of A-segment) ----
__global__ __launch_bounds__(256) void fill_csr(
    const int* __restrict__ ei,
    const int* __restrict__ oL, const int* __restrict__ oR, const int* __restrict__ oA,
    int* __restrict__ cL, int* __restrict__ cR,
    int* __restrict__ eL, int* __restrict__ eR, int* __restrict__ snA)
{
  int e = blockIdx.x * 256 + threadIdx.x;
  if (e >= EE) return;
  if (e < NE) {
    int s = ei[e], d = ei[NE + e];
    int p = atomicAdd(&cL[s], 1); eL[oL[s] + p] = e;
    p = atomicAdd(&cR[d], 1);
    eR[oR[d] + p] = e;
    snA[oA[d] + 1 + p] = s;       // A-segment: [selfloop, dst-edges...]
  } else {
    int n = e - NE;
    snA[oA[n]] = n;
  }
}

// ------------- GAT layer 1 gather: WAVE-per-node, no LDS, no barriers ----------------
__global__ __launch_bounds__(256) void gat_gather1(
    const int* __restrict__ snA, const int* __restrict__ offA,
    const float* __restrict__ s1, const float* __restrict__ d1,
    const f16* __restrict__ xlh, const float* __restrict__ b1,
    const float* __restrict__ ws2, const float* __restrict__ wd2,
    f16* __restrict__ x1h, float* __restrict__ s2, float* __restrict__ d2)
{
  const int t = threadIdx.x;
  const int wave = t >> 6, lane = t & 63;
  const int n = blockIdx.x * 4 + wave;             // 20000 = 5000*4 exact
  const int hf = lane >> 3;
  const float dnw = d1[n * 8 + hf];
  const int beg = offA[n], deg = offA[n + 1] - beg;
  float acc[8] = {0.f};
  float den = 0.f;
  for (int base = 0; base < deg; base += 64) {
    const int m = min(64, deg - base);
    int me = 0;
    if (lane < m) me = snA[beg + base + lane];
    const int ms = __builtin_amdgcn_readfirstlane(m);
    int s = 0;
    for (; s + 4 <= ms; s += 4) {
      int sn[4]; float sv[4]; f16x8 row[4];
#pragma unroll
      for (int u = 0; u < 4; u++) sn[u] = __builtin_amdgcn_readlane(me, s + u);
#pragma unroll
      for (int u = 0; u < 4; u++) sv[u] = s1[sn[u] * 8 + hf];
#pragma unroll
      for (int u = 0; u < 4; u++) row[u] = *(const f16x8*)(xlh + (size_t)sn[u] * 512 + lane * 8);
#pragma unroll
      for (int u = 0; u < 4; u++) {
        float w = __expf(lrelu(sv[u] + dnw));
        den += w;
#pragma unroll
        for (int j = 0; j < 8; j++) acc[j] = fmaf(w, (float)row[u][j], acc[j]);
      }
    }
    for (; s < ms; ++s) {
      int sn = __builtin_amdgcn_readlane(me, s);
      float sv = s1[sn * 8 + hf];
      f16x8 row = *(const f16x8*)(xlh + (size_t)sn * 512 + lane * 8);
      float w = __expf(lrelu(sv + dnw));
      den += w;
#pragma unroll
      for (int j = 0; j < 8; j++) acc[j] = fmaf(w, (float)row[j], acc[j]);
    }
  }
  const float rh = 1.f / (den + 1e-16f);
  float4 bv0 = *(const float4*)(b1 + lane * 8);
  float4 bv1 = *(const float4*)(b1 + lane * 8 + 4);
  float bb[8] = {bv0.x, bv0.y, bv0.z, bv0.w, bv1.x, bv1.y, bv1.z, bv1.w};
  float4 wsa = *(const float4*)(ws2 + lane * 8);
  float4 wsb = *(const float4*)(ws2 + lane * 8 + 4);
  float4 wda = *(const float4*)(wd2 + lane * 8);
  float4 wdb = *(const float4*)(wd2 + lane * 8 + 4);
  float wsv[8] = {wsa.x, wsa.y, wsa.z, wsa.w, wsb.x, wsb.y, wsb.z, wsb.w};
  float wdv[8] = {wda.x, wda.y, wda.z, wda.w, wdb.x, wdb.y, wdb.z, wdb.w};
  f16x8 o;
  float ps = 0.f, pd = 0.f;
#pragma unroll
  for (int j = 0; j < 8; j++) {
    float v = acc[j] * rh + bb[j];
    v = v > 0.f ? v : (__expf(v) - 1.f);
    o[j] = (f16)v;
    ps = fmaf(v, wsv[j], ps);
    pd = fmaf(v, wdv[j], pd);
  }
  *(f16x8*)(x1h + (size_t)n * 512 + lane * 8) = o;
#pragma unroll
  for (int off = 32; off > 0; off >>= 1) {
    ps += __shfl_xor(ps, off);
    pd += __shfl_xor(pd, off);
  }
  if (lane == 0) { s2[n] = ps; d2[n] = pd; }
}

// ------------- GAT layer 2 gather: WAVE-per-node, no LDS, no barriers ----------------
__global__ __launch_bounds__(256) void gat_gather2(
    const int* __restrict__ snA, const int* __restrict__ offA,
    const float* __restrict__ s2, const float* __restrict__ d2,
    const f16* __restrict__ zh, const f16* __restrict__ Ph,
    f16* __restrict__ h2h)
{
  const int t = threadIdx.x;
  const int wave = t >> 6, lane = t & 63;
  const int n = blockIdx.x * 4 + wave;             // 20000 = 5000*4 exact
  const float dn = d2[n];
  const int beg = offA[n], deg = offA[n + 1] - beg;
  float acc[8] = {0.f};
  float den = 0.f;
  for (int base = 0; base < deg; base += 64) {
    const int m = min(64, deg - base);
    int me = 0;
    if (lane < m) me = snA[beg + base + lane];
    const int ms = __builtin_amdgcn_readfirstlane(m);
    int s = 0;
    for (; s + 4 <= ms; s += 4) {
      int sn[4]; float sv[4]; f16x8 row[4];
#pragma unroll
      for (int u = 0; u < 4; u++) sn[u] = __builtin_amdgcn_readlane(me, s + u);
#pragma unroll
      for (int u = 0; u < 4; u++) sv[u] = s2[sn[u]];
#pragma unroll
      for (int u = 0; u < 4; u++) row[u] = *(const f16x8*)(zh + (size_t)sn[u] * 512 + lane * 8);
#pragma unroll
      for (int u = 0; u < 4; u++) {
        float w = __expf(lrelu(sv[u] + dn));
        den += w;
#pragma unroll
        for (int j = 0; j < 8; j++) acc[j] = fmaf(w, (float)row[u][j], acc[j]);
      }
    }
    for (; s < ms; ++s) {
      int sn = __builtin_amdgcn_readlane(me, s);
      float sv = s2[sn];
      f16x8 row = *(const f16x8*)(zh + (size_t)sn * 512 + lane * 8);
      float w = __expf(lrelu(sv + dn));
      den += w;
#pragma unroll
      for (int j = 0; j < 8; j++) acc[j] = fmaf(w, (float)row[j], acc[j]);
    }
  }
  const float rn = 1.f / (den + 1e-16f);
  f16x8 pv = *(const f16x8*)(Ph + (size_t)n * 512 + lane * 8);
  f16x8 o;
#pragma unroll
  for (int j = 0; j < 8; j++) {
    float v = fmaxf(acc[j] * rn + (float)pv[j], 0.f);
    o[j] = (f16)v;
  }
  *(f16x8*)(h2h + (size_t)n * 512 + lane * 8) = o;
}

extern "C" void kernel_launch(void* const* d_in, const int* in_sizes, int n_in,
                              void* d_out, int out_size, void* d_ws, size_t ws_size,
                              hipStream_t stream) {
  const int*   edge_index = (const int*)d_in[0];
  const float* synapse    = (const float*)d_in[2];
  const float* x_param = (const float*)d_in[5];
  const float* W1      = (const float*)d_in[6];
  const float* as1     = (const float*)d_in[7];
  const float* ad1     = (const float*)d_in[8];
  const float* b1      = (const float*)d_in[9];
  const float* W2      = (const float*)d_in[10];
  const float* as2     = (const float*)d_in[11];
  const float* ad2     = (const float*)d_in[12];
  const float* b2      = (const float*)d_in[13];
  const float* We1     = (const float*)d_in[14];
  const float* be1     = (const float*)d_in[15];
  const float* We2     = (const float*)d_in[16];
  const float* be2     = (const float*)d_in[17];
  const float* Wc1     = (const float*)d_in[18];
  const float* bc1     = (const float*)d_in[19];
  const float* Wc2     = (const float*)d_in[20];
  const float* bc2     = (const float*)d_in[21];
  float* out_p = (float*)d_out;

  // ---- workspace layout (~125 MB) ----
  char* p = (char*)d_ws;
  float* xp    = (float*)p; p += (size_t)NE * 6 * 4;
  float* s1    = (float*)p; p += (size_t)NN * 8 * 4;
  float* d1    = (float*)p; p += (size_t)NN * 8 * 4;
  float* s2    = (float*)p; p += (size_t)NN * 4;
  float* d2    = (float*)p; p += (size_t)NN * 4;
  float* vB    = (float*)p; p += 512 * 4;
  float* vL    = (float*)p; p += 512 * 4;
  float* vR    = (float*)p; p += 512 * 4;
  float* ws2   = (float*)p; p += 512 * 4;
  float* wd2   = (float*)p; p += 512 * 4;
  f16* xph     = (f16*)p; p += (size_t)NN * FEAT * 2;
  f16* xl1h    = (f16*)p; p += (size_t)NN * 512 * 2;
  f16* x1h     = (f16*)p; p += (size_t)NN * 512 * 2;
  f16* zh      = (f16*)p; p += (size_t)NN * 512 * 2;
  f16* h2h     = (f16*)p; p += (size_t)NN * 512 * 2;
  f16* Phb     = (f16*)p; p += (size_t)NN * 512 * 2;
  f16* hlrh    = (f16*)p; p += (size_t)2 * NN * 256 * 2;
  f16* W1t     = (f16*)p; p += (size_t)512 * FEAT * 2;
  f16* WzAt    = (f16*)p; p += (size_t)512 * 512 * 2;
  f16* McatT   = (f16*)p; p += (size_t)512 * 512 * 2;
  f16* Wc2t    = (f16*)p; p += (size_t)133 * 512 * 2;
  int* degL    = (int*)p;                 // N  (zero group start)
  int* degR    = degL + NN;               // N
  int* curL    = degR + NN;               // N
  int* curR    = curL + NN;               // N  (zero group: 4N ints)
  int* offL    = curR + NN;               // N+1
  int* offR    = offL + NN + 1;           // N+1
  int* offA    = offR + NN + 1;           // N+1
  int* edgeL   = offA + NN + 1;           // E
  int* edgeR   = edgeL + NE;              // E
  int* snA     = edgeR + NE;              // EE

  hipMemsetAsync(degL, 0, (size_t)4 * NN * sizeof(int), stream);

  preamble<<<QB5, 256, 0, stream>>>(
      edge_index, synapse, W1, x_param, W2, We2, Wc1, Wc2, b2, be2, as2, ad2,
      degL, degR, xp, W1t, xph, WzAt, McatT, Wc2t, vB, vL, vR, ws2, wd2);
  scan_csr<<<2, 1024, 0, stream>>>(degL, degR, offL, offR, offA);
  fill_csr<<<(EE + 255) / 256, 256, 0, stream>>>(edge_index, offL, offR, offA,
                                                 curL, curR, edgeL, edgeR, snA);
  fused1<<<1252 + 2500, 256, 0, stream>>>(xph, W1t, xl1h, xp, We1, be1,
                                          offL, edgeL, offR, edgeR, hlrh,
                                          as1, ad1, s1, d1);
  gat_gather1<<<5000, 256, 0, stream>>>(snA, offA, s1, d1, xl1h, b1, ws2, wd2,
                                        x1h, s2, d2);
  fused2<<<1256, 256, 0, stream>>>(x1h, WzAt, zh, hlrh, McatT,
                                   degL, degR, bc1, vB, vL, vR, Phb);
  gat_gather2<<<5000, 256, 0, stream>>>(snA, offA, s2, d2, zh, Phb, h2h);
  mfma_out<<<dim3(2, 313), 256, 0, stream>>>(h2h, Wc2t, bc2, out_p, NN);
}

// Round 14
// 396.890 us; speedup vs baseline: 1.0706x; 1.0107x over previous
//
#include <hip/hip_runtime.h>
#include <cstddef>

// Problem constants (fixed by setup_inputs)
#define NN   20000     // nodes
#define FEAT 128
#define NH   8         // heads layer 1
#define NE   200000    // edges
#define EE   220000    // edges + self loops

typedef _Float16 f16;
typedef _Float16 f16x2 __attribute__((ext_vector_type(2)));
typedef _Float16 f16x4 __attribute__((ext_vector_type(4)));
typedef _Float16 f16x8 __attribute__((ext_vector_type(8)));
typedef float    f32x4 __attribute__((ext_vector_type(4)));

__device__ __forceinline__ float lrelu(float a) { return a > 0.f ? a : 0.2f * a; }
__device__ __forceinline__ float rdlane(float v, int l) {
  return __int_as_float(__builtin_amdgcn_readlane(__float_as_int(v), l));
}
// async global->LDS, 16B per lane; LDS dest = wave-uniform base + lane*16
__device__ __forceinline__ void gld_lds16(const f16* g, f16* l) {
  __builtin_amdgcn_global_load_lds(
      (const __attribute__((address_space(1))) void*)g,
      (__attribute__((address_space(3))) void*)l, 16, 0, 0);
}

// ================= preamble: ALL input-only precompute in one launch =================
// Ordered longest-latency-first so small late sections hide under the bulk:
// [0,QB0) gemm3in1 | [QB0,QB1) small_vec | [QB1,QB2) Wc2t | [QB2,QB3) W1t |
// [QB3,QB4) maxpool+count_deg (fused edge pass) | [QB4,QB5) xph cvt x8
#define QB0 128
#define QB1 (QB0 + 8)
#define QB2 (QB1 + 80)
#define QB3 (QB2 + 64)
#define QB4 (QB3 + 782)
#define QB5 (QB4 + 1250)
__global__ __launch_bounds__(256) void preamble(
    const int* __restrict__ ei, const float* __restrict__ syn,
    const float* __restrict__ W1, const float* __restrict__ xparam,
    const float* __restrict__ W2, const float* __restrict__ We2,
    const float* __restrict__ Wc1, const float* __restrict__ Wc2,
    const float* __restrict__ b2, const float* __restrict__ be2,
    const float* __restrict__ as2, const float* __restrict__ ad2,
    int* __restrict__ dL, int* __restrict__ dR,
    float* __restrict__ xp, f16* __restrict__ W1t, f16* __restrict__ xph,
    f16* __restrict__ WzAt, f16* __restrict__ McatT, f16* __restrict__ Wc2t,
    float* __restrict__ vB, float* __restrict__ vL, float* __restrict__ vR,
    float* __restrict__ ws2, float* __restrict__ wd2)
{
  __shared__ float smem[2112];
  const int b = blockIdx.x, t = threadIdx.x;
  if (b < QB0) {                                   // ---- gemm3in1 (folded weights) ----
    float (*As)[68] = (float(*)[68])smem;
    float (*Bs)[64] = (float(*)[64])(smem + 16 * 68);
    const int bb = b;
    const float* A; const float* B; f16* dst; int dstOff, m0, n0;
    if (bb < 64)      { A = W2;  B = Wc1;  dst = WzAt;  dstOff = 0;
                        m0 = (bb >> 3) * 64; n0 = (bb & 7) * 64; }
    else if (bb < 96) { int i = bb - 64; A = We2; B = Wc1 + (size_t)512 * 512;
                        dst = McatT; dstOff = 0;
                        m0 = (i >> 3) * 64; n0 = (i & 7) * 64; }
    else              { int i = bb - 96; A = We2; B = Wc1 + (size_t)1024 * 512;
                        dst = McatT; dstOff = 256;
                        m0 = (i >> 3) * 64; n0 = (i & 7) * 64; }
    const int tx = t & 15, ty = t >> 4;
    float acc[4][4] = {{0.f}};
    float pa[4], pb[4];
#pragma unroll
    for (int i = 0; i < 4; i++) {
      int idx = t + i * 256;
      pa[i] = A[(size_t)(m0 + (idx >> 4)) * 512 + (idx & 15)];
      pb[i] = B[(size_t)(idx >> 6) * 512 + n0 + (idx & 63)];
    }
    for (int k0 = 0; k0 < 512; k0 += 16) {
#pragma unroll
      for (int i = 0; i < 4; i++) {
        int idx = t + i * 256;
        As[idx & 15][idx >> 4] = pa[i];
        Bs[idx >> 6][idx & 63] = pb[i];
      }
      __syncthreads();
      if (k0 + 16 < 512) {
        int kn = k0 + 16;
#pragma unroll
        for (int i = 0; i < 4; i++) {
          int idx = t + i * 256;
          pa[i] = A[(size_t)(m0 + (idx >> 4)) * 512 + kn + (idx & 15)];
          pb[i] = B[(size_t)(kn + (idx >> 6)) * 512 + n0 + (idx & 63)];
        }
      }
#pragma unroll
      for (int kk = 0; kk < 16; kk++) {
        float4 a4 = *(const float4*)&As[kk][ty * 4];
        float4 b4 = *(const float4*)&Bs[kk][tx * 4];
        float av[4] = {a4.x, a4.y, a4.z, a4.w};
        float bv[4] = {b4.x, b4.y, b4.z, b4.w};
#pragma unroll
        for (int i = 0; i < 4; i++)
#pragma unroll
          for (int j = 0; j < 4; j++) acc[i][j] = fmaf(av[i], bv[j], acc[i][j]);
      }
      __syncthreads();
    }
#pragma unroll
    for (int i = 0; i < 4; i++)
#pragma unroll
      for (int j = 0; j < 4; j++)
        dst[(size_t)(n0 + tx * 4 + j) * 512 + dstOff + m0 + ty * 4 + i] = (f16)acc[i][j];
  } else if (b < QB1) {                            // ---- small_vec (4 segs) ----
    int g = (b - QB0) * 256 + t;
    int seg = g >> 9, j = g & 511;
    if (seg == 0) {
      float a = 0.f;
      for (int k = 0; k < 512; k++) a = fmaf(b2[k], Wc1[(size_t)k * 512 + j], a);
      vB[j] = a;
    } else if (seg == 1) {
      float a = 0.f;
      for (int k = 0; k < 512; k++) a = fmaf(be2[k], Wc1[(size_t)(512 + k) * 512 + j], a);
      vL[j] = a;
    } else if (seg == 2) {
      float a = 0.f;
      for (int k = 0; k < 512; k++) a = fmaf(be2[k], Wc1[(size_t)(1024 + k) * 512 + j], a);
      vR[j] = a;
    } else {
      float a = 0.f, c2 = 0.f;
      for (int c = 0; c < 512; c++) {
        float w = W2[(size_t)j * 512 + c];
        a = fmaf(w, as2[c], a);
        c2 = fmaf(w, ad2[c], c2);
      }
      ws2[j] = a; wd2[j] = c2;
    }
  } else if (b < QB2) {                            // ---- Wc2 transpose-cvt ----
    float (*tile)[33] = (float(*)[33])smem;
    int i0 = b - QB1;                              // 80 blocks: 5 n-tiles x 16 k-tiles
    const int n0 = (i0 % 5) * 32, k0 = (i0 / 5) * 32;
    const int tx = t & 31, ty = t >> 5;
#pragma unroll
    for (int i = 0; i < 4; i++) {
      int k = k0 + ty + i * 8, n = n0 + tx;
      tile[ty + i * 8][tx] = (n < 133) ? Wc2[(size_t)k * 133 + n] : 0.f;
    }
    __syncthreads();
#pragma unroll
    for (int i = 0; i < 4; i++) {
      int n = n0 + ty + i * 8, k = k0 + tx;
      if (n < 133) Wc2t[(size_t)n * 512 + k] = (f16)tile[tx][ty + i * 8];
    }
  } else if (b < QB3) {                            // ---- W1 transpose-cvt ----
    float (*tile)[33] = (float(*)[33])smem;
    int bb = b - QB2;
    const int n0 = (bb & 15) * 32, k0 = (bb >> 4) * 32;
    const int tx = t & 31, ty = t >> 5;
#pragma unroll
    for (int i = 0; i < 4; i++)
      tile[ty + i * 8][tx] = W1[(size_t)(k0 + ty + i * 8) * 512 + n0 + tx];
    __syncthreads();
#pragma unroll
    for (int i = 0; i < 4; i++)
      W1t[(size_t)(n0 + ty + i * 8) * 128 + k0 + tx] = (f16)tile[tx][ty + i * 8];
  } else if (b < QB4) {                            // ---- maxpool + count_deg fused ----
    int e = (b - QB3) * 256 + t;
    if (e >= NE) return;
    const float* p = syn + (size_t)e * 24;
    float v[24];
#pragma unroll
    for (int i = 0; i < 6; i++) {
      float4 q = *(const float4*)(p + i * 4);
      v[i*4+0] = q.x; v[i*4+1] = q.y; v[i*4+2] = q.z; v[i*4+3] = q.w;
    }
#pragma unroll
    for (int dd = 0; dd < 6; dd++)
      xp[(size_t)e * 6 + dd] = fmaxf(fmaxf(v[dd], v[6 + dd]), fmaxf(v[12 + dd], v[18 + dd]));
    atomicAdd(&dL[ei[e]], 1);
    atomicAdd(&dR[ei[NE + e]], 1);
  } else {                                         // ---- xph cvt, 8 elem/thread ----
    int idx = ((b - QB4) * 256 + t) * 8;           // NN*FEAT = 2,560,000 = 1250*2048
    float4 q0 = *(const float4*)(xparam + idx);
    float4 q1 = *(const float4*)(xparam + idx + 4);
    f16x8 o;
    o[0] = (f16)q0.x; o[1] = (f16)q0.y; o[2] = (f16)q0.z; o[3] = (f16)q0.w;
    o[4] = (f16)q1.x; o[5] = (f16)q1.y; o[6] = (f16)q1.z; o[7] = (f16)q1.w;
    *(f16x8*)(xph + idx) = o;
  }
}

// ================= fused1: xl1 MFMA-GEMM + FUSED attn dots + h1 packed gather ========
// GEMM epilogue computes s1/d1 from the f32 accumulators (each block's 128-col
// tile spans exactly 2 heads). Gather branch now uses PACKED f16 math: weights
// and bias as f16x2 pairs, edge features packed to 3 u32 at load (3 readlanes
// instead of 6), matvec = 12 v_pk_fma_f16 (was 24 f32 FMA), relu+acc packed.
// f16x2 accumulation precedented (R0 baseline, same absmax).
__global__ __launch_bounds__(256) void fused1(
    const f16* __restrict__ xph, const f16* __restrict__ W1t, f16* __restrict__ xl1h,
    const float* __restrict__ xp, const float* __restrict__ We1,
    const float* __restrict__ be1,
    const int* __restrict__ oL, const int* __restrict__ eL,
    const int* __restrict__ oR, const int* __restrict__ eR,
    f16* __restrict__ hlrh,
    const float* __restrict__ as1, const float* __restrict__ ad1,
    float* __restrict__ s1, float* __restrict__ d1)
{
  __shared__ __align__(16) f16 smem[7680];
  const int t = threadIdx.x;
  if (blockIdx.x < 1252) {
    f16 (*As)[40] = (f16(*)[40])smem;
    f16 (*Bs)[40] = (f16(*)[40])(smem + 64 * 40);
    const int wave = t >> 6, lane = t & 63;
    const int quad = lane >> 4, mrow = lane & 15;
    const int m0 = (blockIdx.x >> 2) * 64, n0 = (blockIdx.x & 3) * 128;
    f32x4 acc[4][2];
    f32x4 zero4 = {0.f, 0.f, 0.f, 0.f};
#pragma unroll
    for (int i = 0; i < 4; i++)
#pragma unroll
      for (int j = 0; j < 2; j++) acc[i][j] = zero4;
    const int ar = t >> 2, ac = (t & 3) * 8;
    for (int k0 = 0; k0 < FEAT; k0 += 32) {
      {
        int gm = m0 + ar;
        f16x8 v = {0, 0, 0, 0, 0, 0, 0, 0};
        if (gm < NN) v = *(const f16x8*)(xph + (size_t)gm * FEAT + k0 + ac);
        *(f16x8*)&As[ar][ac] = v;
      }
#pragma unroll
      for (int i = 0; i < 2; i++) {
        int idx = t + i * 256;
        int r = idx >> 2, c = (idx & 3) * 8;
        *(f16x8*)&Bs[r][c] = *(const f16x8*)(W1t + (size_t)(n0 + r) * FEAT + k0 + c);
      }
      __syncthreads();
      f16x8 af[4], bf[2];
#pragma unroll
      for (int mt = 0; mt < 4; mt++) af[mt] = *(const f16x8*)&As[mt * 16 + mrow][quad * 8];
#pragma unroll
      for (int nt = 0; nt < 2; nt++) bf[nt] = *(const f16x8*)&Bs[wave * 32 + nt * 16 + mrow][quad * 8];
#pragma unroll
      for (int mt = 0; mt < 4; mt++)
#pragma unroll
        for (int nt = 0; nt < 2; nt++)
          acc[mt][nt] = __builtin_amdgcn_mfma_f32_16x16x32_f16(af[mt], bf[nt], acc[mt][nt], 0, 0, 0);
      __syncthreads();
    }
#pragma unroll
    for (int mt = 0; mt < 4; mt++)
#pragma unroll
      for (int nt = 0; nt < 2; nt++) {
        int col = n0 + wave * 32 + nt * 16 + mrow;
#pragma unroll
        for (int reg = 0; reg < 4; reg++) {
          int row = m0 + mt * 16 + quad * 4 + reg;
          if (row < NN) xl1h[(size_t)row * 512 + col] = (f16)acc[mt][nt][reg];
        }
      }
    // ---- fused attn dots: s1/d1 for this block's 64 rows x 2 heads ----
    const int h = (n0 >> 6) + (wave >> 1);           // heads n0/64, n0/64+1
    float a1v[2], a2v[2];
#pragma unroll
    for (int nt = 0; nt < 2; nt++) {
      int cw = ((wave & 1) << 5) + nt * 16 + mrow;   // col within head [0,64)
      a1v[nt] = as1[h * 64 + cw];
      a2v[nt] = ad1[h * 64 + cw];
    }
    float myS[16], myD[16];
#pragma unroll
    for (int mt = 0; mt < 4; mt++)
#pragma unroll
      for (int reg = 0; reg < 4; reg++) {
        float ps = acc[mt][0][reg] * a1v[0] + acc[mt][1][reg] * a1v[1];
        float pd = acc[mt][0][reg] * a2v[0] + acc[mt][1][reg] * a2v[1];
        ps += __shfl_xor(ps, 1);  pd += __shfl_xor(pd, 1);
        ps += __shfl_xor(ps, 2);  pd += __shfl_xor(pd, 2);
        ps += __shfl_xor(ps, 4);  pd += __shfl_xor(pd, 4);
        ps += __shfl_xor(ps, 8);  pd += __shfl_xor(pd, 8);
        myS[mt * 4 + reg] = ps;   myD[mt * 4 + reg] = pd;
      }
    float* sred = (float*)smem;                      // reuse LDS (post-K-loop barrier)
    float* dred = sred + 128;                        // [2 heads][64 rows] each
    __syncthreads();
    if ((wave & 1) == 0 && mrow == 0) {
#pragma unroll
      for (int mt = 0; mt < 4; mt++)
#pragma unroll
        for (int reg = 0; reg < 4; reg++) {
          int rr = mt * 16 + quad * 4 + reg;
          sred[(wave >> 1) * 64 + rr] = myS[mt * 4 + reg];
          dred[(wave >> 1) * 64 + rr] = myD[mt * 4 + reg];
        }
    }
    __syncthreads();
    if ((wave & 1) == 1 && mrow == 0) {
#pragma unroll
      for (int mt = 0; mt < 4; mt++)
#pragma unroll
        for (int reg = 0; reg < 4; reg++) {
          int rr = mt * 16 + quad * 4 + reg;
          int row = m0 + rr;
          if (row < NN) {
            s1[row * 8 + h] = myS[mt * 4 + reg] + sred[(wave >> 1) * 64 + rr];
            d1[row * 8 + h] = myD[mt * 4 + reg] + dred[(wave >> 1) * 64 + rr];
          }
        }
    }
  } else {
    // ---- h1 mean-gather: packed-f16 readlane broadcast, 4 node-sides per wave ----
    const int wave = t >> 6, lane = t & 63;
    const int w = (blockIdx.x - 1252) * 4 + wave;        // 0..9999
    f16x2 wp[6][2];
    f16x2 bp[2];
#pragma unroll
    for (int j = 0; j < 6; j++) {
      float4 wj = *(const float4*)(We1 + j * 256 + 4 * lane);
      wp[j][0][0] = (f16)wj.x; wp[j][0][1] = (f16)wj.y;
      wp[j][1][0] = (f16)wj.z; wp[j][1][1] = (f16)wj.w;
    }
    {
      float4 bq = *(const float4*)(be1 + 4 * lane);
      bp[0][0] = (f16)bq.x; bp[0][1] = (f16)bq.y;
      bp[1][0] = (f16)bq.z; bp[1][1] = (f16)bq.w;
    }
    const f16 zf = (f16)0.f;
#pragma unroll 1
    for (int i = 0; i < 4; i++) {
      const int b = w + i * 10000;                       // node-side in [0, 2*NN)
      const int* off; const int* lst; int n;
      if (b < NN) { off = oL; lst = eL; n = b; } else { off = oR; lst = eR; n = b - NN; }
      const int beg = off[n], deg = off[n + 1] - beg;
      f16x2 a0; a0[0] = zf; a0[1] = zf;
      f16x2 a1; a1[0] = zf; a1[1] = zf;
      for (int base = 0; base < deg; base += 32) {
        const int m = min(32, deg - base);
        int pk0 = 0, pk1 = 0, pk2 = 0;
        if (lane < m) {
          const int e = lst[beg + base + lane];
          const float* pr = xp + (size_t)e * 6;
          float2 p0 = *(const float2*)pr;
          float2 p1 = *(const float2*)(pr + 2);
          float2 p2 = *(const float2*)(pr + 4);
          f16x2 t0; t0[0] = (f16)p0.x; t0[1] = (f16)p0.y; pk0 = *(int*)&t0;
          f16x2 t1; t1[0] = (f16)p1.x; t1[1] = (f16)p1.y; pk1 = *(int*)&t1;
          f16x2 t2; t2[0] = (f16)p2.x; t2[1] = (f16)p2.y; pk2 = *(int*)&t2;
        }
        const int ms = __builtin_amdgcn_readfirstlane(m);
        for (int s = 0; s < ms; ++s) {
          int q0 = __builtin_amdgcn_readlane(pk0, s);
          int q1 = __builtin_amdgcn_readlane(pk1, s);
          int q2 = __builtin_amdgcn_readlane(pk2, s);
          f16x2 x01 = *(f16x2*)&q0, x23 = *(f16x2*)&q1, x45 = *(f16x2*)&q2;
          f16x2 s0; s0[0] = x01[0]; s0[1] = x01[0];
          f16x2 s1v; s1v[0] = x01[1]; s1v[1] = x01[1];
          f16x2 s2; s2[0] = x23[0]; s2[1] = x23[0];
          f16x2 s3; s3[0] = x23[1]; s3[1] = x23[1];
          f16x2 s4; s4[0] = x45[0]; s4[1] = x45[0];
          f16x2 s5; s5[0] = x45[1]; s5[1] = x45[1];
          f16x2 v0 = bp[0], v1 = bp[1];
          v0 = s0 * wp[0][0] + v0;  v1 = s0 * wp[0][1] + v1;
          v0 = s1v * wp[1][0] + v0; v1 = s1v * wp[1][1] + v1;
          v0 = s2 * wp[2][0] + v0;  v1 = s2 * wp[2][1] + v1;
          v0 = s3 * wp[3][0] + v0;  v1 = s3 * wp[3][1] + v1;
          v0 = s4 * wp[4][0] + v0;  v1 = s4 * wp[4][1] + v1;
          v0 = s5 * wp[5][0] + v0;  v1 = s5 * wp[5][1] + v1;
          f16x2 r0, r1;
          r0[0] = v0[0] > zf ? v0[0] : zf; r0[1] = v0[1] > zf ? v0[1] : zf;
          r1[0] = v1[0] > zf ? v1[0] : zf; r1[1] = v1[1] > zf ? v1[1] : zf;
          a0 = a0 + r0;
          a1 = a1 + r1;
        }
      }
      const float rn = deg > 0 ? 1.f / (float)deg : 0.f;
      f16x4 o;
      o[0] = (f16)((float)a0[0] * rn); o[1] = (f16)((float)a0[1] * rn);
      o[2] = (f16)((float)a1[0] * rn); o[3] = (f16)((float)a1[1] * rn);
      *(f16x4*)(hlrh + (size_t)b * 256 + 4 * lane) = o;
    }
  }
}

// ================= fused2: z-GEMM + class_pre, BK=64 + st-swizzle (R9 best) =========
// 128x128 tile, BK=64 (8 K-steps), 32KB linear LDS staged via global_load_lds
// width=16, 2 barriers per K-step; source/read XOR swizzle (bank-conflict 0).
// NOTE: pipelining variants (dbuf __syncthreads, counted vmcnt+raw barrier) all
// REGRESSED vs this plain loop -- matches guide m131-m140; do not re-attempt.
__global__ __launch_bounds__(256) void fused2(
    const f16* __restrict__ x1h, const f16* __restrict__ WzAt, f16* __restrict__ zh,
    const f16* __restrict__ hlrh, const f16* __restrict__ McatT,
    const int* __restrict__ degL, const int* __restrict__ degR,
    const float* __restrict__ bc1, const float* __restrict__ vB,
    const float* __restrict__ vL, const float* __restrict__ vR, f16* __restrict__ Ph)
{
  __shared__ __align__(16) f16 smem[16384];        // As 8192 f16 | Bs 8192 f16
  const int t = threadIdx.x;
  const int logical = (blockIdx.x & 7) * 157 + (blockIdx.x >> 3);
  const bool isZ = logical < 628;
  const int bb = isZ ? logical : logical - 628;
  const int wave = t >> 6, lane = t & 63;
  const int wr = wave >> 1, wc = wave & 1;
  const int quad = lane >> 4, mrow = lane & 15;
  const int m0 = (bb >> 2) * 128, n0 = (bb & 3) * 128;
  const f16* Bt = isZ ? WzAt : McatT;
  const int srow = wave * 8 + (lane >> 3);           // 0..31 within issue block
  const int cs = (lane & 7) ^ ((lane >> 3) & 7);     // swizzled source chunk
  f16* ldsA = smem + wave * 512;                     // + i*2048 per issue
  f16* ldsB = smem + 8192 + wave * 512;
  const int mswz = mrow & 7;                         // read-side XOR key

  f32x4 acc[4][4];
  f32x4 zero4 = {0.f, 0.f, 0.f, 0.f};
#pragma unroll
  for (int i = 0; i < 4; i++)
#pragma unroll
    for (int j = 0; j < 4; j++) acc[i][j] = zero4;

#pragma unroll 1
  for (int it = 0; it < 8; ++it) {
    const int k0 = it * 64;
#pragma unroll
    for (int i = 0; i < 4; i++) {
      const int garow = m0 + i * 32 + srow;
      const f16* gA;
      if (isZ) {
        gA = x1h + (size_t)garow * 512 + k0 + cs * 8;
      } else {
        const int roff = (k0 >> 8) ? NN : 0;         // K half selects L/R hlrh bank
        gA = hlrh + (size_t)(garow + roff) * 256 + (k0 & 255) + cs * 8;
      }
      gld_lds16(gA, ldsA + i * 2048);
      const f16* gB = Bt + (size_t)(n0 + i * 32 + srow) * 512 + k0 + cs * 8;
      gld_lds16(gB, ldsB + i * 2048);
    }
    __syncthreads();
#pragma unroll
    for (int ksub = 0; ksub < 2; ++ksub) {
      f16x8 af[4], bf[4];
#pragma unroll
      for (int mt = 0; mt < 4; mt++)
        af[mt] = *(const f16x8*)(smem + (wr * 64 + mt * 16 + mrow) * 64 +
                                 ((ksub * 4 + quad) ^ mswz) * 8);
#pragma unroll
      for (int nt = 0; nt < 4; nt++)
        bf[nt] = *(const f16x8*)(smem + 8192 + (wc * 64 + nt * 16 + mrow) * 64 +
                                 ((ksub * 4 + quad) ^ mswz) * 8);
#pragma unroll
      for (int mt = 0; mt < 4; mt++)
#pragma unroll
        for (int nt = 0; nt < 4; nt++)
          acc[mt][nt] = __builtin_amdgcn_mfma_f32_16x16x32_f16(af[mt], bf[nt], acc[mt][nt], 0, 0, 0);
    }
    __syncthreads();
  }
  if (isZ) {
#pragma unroll
    for (int mt = 0; mt < 4; mt++)
#pragma unroll
      for (int nt = 0; nt < 4; nt++) {
        int col = n0 + wc * 64 + nt * 16 + mrow;
#pragma unroll
        for (int reg = 0; reg < 4; reg++) {
          int row = m0 + wr * 64 + mt * 16 + quad * 4 + reg;
          if (row < NN) zh[(size_t)row * 512 + col] = (f16)acc[mt][nt][reg];
        }
      }
  } else {
#pragma unroll
    for (int mt = 0; mt < 4; mt++)
#pragma unroll
      for (int nt = 0; nt < 4; nt++) {
        int col = n0 + wc * 64 + nt * 16 + mrow;
        float bb2 = bc1[col] + vB[col];
        float vl = vL[col], vr = vR[col];
#pragma unroll
        for (int reg = 0; reg < 4; reg++) {
          int row = m0 + wr * 64 + mt * 16 + quad * 4 + reg;
          if (row >= NN) continue;
          float v = acc[mt][nt][reg] + bb2;
          if (degL[row] > 0) v += vl;
          if (degR[row] > 0) v += vr;
          Ph[(size_t)row * 512 + col] = (f16)v;
        }
      }
  }
}

// ---------------- MFMA output GEMM: out(f32)[M,133] = h2h @ Wc2t^T + bc2 -------------
__global__ __launch_bounds__(256) void mfma_out(
    const f16* __restrict__ A, const f16* __restrict__ Bt,
    const float* __restrict__ bias, float* __restrict__ C, int M)
{
  __shared__ __align__(16) f16 As[64][40];
  __shared__ __align__(16) f16 Bs[128][40];
  const int t = threadIdx.x;
  const int wave = t >> 6, lane = t & 63;
  const int quad = lane >> 4, mrow = lane & 15;
  const int m0 = blockIdx.y * 64, n0 = blockIdx.x * 128;
  f32x4 acc[4][2];
  f32x4 zero4 = {0.f, 0.f, 0.f, 0.f};
#pragma unroll
  for (int i = 0; i < 4; i++)
#pragma unroll
    for (int j = 0; j < 2; j++) acc[i][j] = zero4;
  const int ar = t >> 2, ac = (t & 3) * 8;
  for (int k0 = 0; k0 < 512; k0 += 32) {
    {
      int gm = m0 + ar;
      f16x8 v = {0, 0, 0, 0, 0, 0, 0, 0};
      if (gm < M) v = *(const f16x8*)(A + (size_t)gm * 512 + k0 + ac);
      *(f16x8*)&As[ar][ac] = v;
    }
#pragma unroll
    for (int i = 0; i < 2; i++) {
      int idx = t + i * 256;
      int r = idx >> 2, c = (idx & 3) * 8;
      f16x8 v = {0, 0, 0, 0, 0, 0, 0, 0};
      if (n0 + r < 133) v = *(const f16x8*)(Bt + (size_t)(n0 + r) * 512 + k0 + c);
      *(f16x8*)&Bs[r][c] = v;
    }
    __syncthreads();
    f16x8 af[4], bf[2];
#pragma unroll
    for (int mt = 0; mt < 4; mt++) af[mt] = *(const f16x8*)&As[mt * 16 + mrow][quad * 8];
#pragma unroll
    for (int nt = 0; nt < 2; nt++) bf[nt] = *(const f16x8*)&Bs[wave * 32 + nt * 16 + mrow][quad * 8];
#pragma unroll
    for (int mt = 0; mt < 4; mt++)
#pragma unroll
      for (int nt = 0; nt < 2; nt++)
        acc[mt][nt] = __builtin_amdgcn_mfma_f32_16x16x32_f16(af[mt], bf[nt], acc[mt][nt], 0, 0, 0);
    __syncthreads();
  }
#pragma unroll
  for (int mt = 0; mt < 4; mt++)
#pragma unroll
    for (int nt = 0; nt < 2; nt++) {
      int col = n0 + wave * 32 + nt * 16 + mrow;
      if (col >= 133) continue;
      float bb = bias[col];
#pragma unroll
      for (int reg = 0; reg < 4; reg++) {
        int row = m0 + mt * 16 + quad * 4 + reg;
        if (row < M) C[(size_t)row * 133 + col] = acc[mt][nt][reg] + bb;
      }
    }
}

// ------------- CSR scan (2 blocks; offA derived as offR + n) -------------------------
__global__ __launch_bounds__(1024) void scan_csr(
    const int* __restrict__ dL, const int* __restrict__ dR,
    int* __restrict__ oL, int* __restrict__ oR, int* __restrict__ oA)
{
  const int b = blockIdx.x;
  const int* deg = b == 0 ? dL : dR;
  __shared__ int part[1024];
  const int t = threadIdx.x;
  const int chunk = 20;
  int base = t * chunk;
  int sum = 0;
  for (int i = 0; i < chunk; i++) { int idx = base + i; if (idx < NN) sum += deg[idx]; }
  part[t] = sum;
  __syncthreads();
  for (int o = 1; o < 1024; o <<= 1) {
    int v = (t >= o) ? part[t - o] : 0;
    __syncthreads();
    part[t] += v;
    __syncthreads();
  }
  int run = part[t] - sum;
  if (b == 0) {
    for (int i = 0; i < chunk; i++) {
      int idx = base + i;
      if (idx < NN) { oL[idx] = run; run += deg[idx]; }
    }
    if (t == 0) oL[NN] = part[1023];
  } else {
    for (int i = 0; i < chunk; i++) {
      int idx = base + i;
      if (idx < NN) { oR[idx] = run; oA[idx] = run + idx; run += deg[idx]; }
    }
    if (t == 0) { oR[NN] = part[1023]; oA[NN] = part[1023] + NN; }
  }
}

// ------------- fill: 2 atomics/edge; self-loops atomic-free (slot 0 of A-segment) ----
__global__ __launch_bounds__(256) void fill_csr(
    const int* __restrict__ ei,
    const int* __restrict__ oL, const int* __restrict__ oR, const int* __restrict__ oA,
    int* __restrict__ cL, int* __restrict__ cR,
    int* __restrict__ eL, int* __restrict__ eR, int* __restrict__ snA)
{
  int e = blockIdx.x * 256 + threadIdx.x;
  if (e >= EE) return;
  if (e < NE) {
    int s = ei[e], d = ei[NE + e];
    int p = atomicAdd(&cL[s], 1); eL[oL[s] + p] = e;
    p = atomicAdd(&cR[d], 1);
    eR[oR[d] + p] = e;
    snA[oA[d] + 1 + p] = s;       // A-segment: [selfloop, dst-edges...]
  } else {
    int n = e - NE;
    snA[oA[n]] = n;
  }
}

// ------------- GAT layer 1 gather: WAVE-per-node, no LDS, no barriers ----------------
__global__ __launch_bounds__(256) void gat_gather1(
    const int* __restrict__ snA, const int* __restrict__ offA,
    const float* __restrict__ s1, const float* __restrict__ d1,
    const f16* __restrict__ xlh, const float* __restrict__ b1,
    const float* __restrict__ ws2, const float* __restrict__ wd2,
    f16* __restrict__ x1h, float* __restrict__ s2, float* __restrict__ d2)
{
  const int t = threadIdx.x;
  const int wave = t >> 6, lane = t & 63;
  const int n = blockIdx.x * 4 + wave;             // 20000 = 5000*4 exact
  const int hf = lane >> 3;
  const float dnw = d1[n * 8 + hf];
  const int beg = offA[n], deg = offA[n + 1] - beg;
  float acc[8] = {0.f};
  float den = 0.f;
  for (int base = 0; base < deg; base += 64) {
    const int m = min(64, deg - base);
    int me = 0;
    if (lane < m) me = snA[beg + base + lane];
    const int ms = __builtin_amdgcn_readfirstlane(m);
    int s = 0;
    for (; s + 4 <= ms; s += 4) {
      int sn[4]; float sv[4]; f16x8 row[4];
#pragma unroll
      for (int u = 0; u < 4; u++) sn[u] = __builtin_amdgcn_readlane(me, s + u);
#pragma unroll
      for (int u = 0; u < 4; u++) sv[u] = s1[sn[u] * 8 + hf];
#pragma unroll
      for (int u = 0; u < 4; u++) row[u] = *(const f16x8*)(xlh + (size_t)sn[u] * 512 + lane * 8);
#pragma unroll
      for (int u = 0; u < 4; u++) {
        float w = __expf(lrelu(sv[u] + dnw));
        den += w;
#pragma unroll
        for (int j = 0; j < 8; j++) acc[j] = fmaf(w, (float)row[u][j], acc[j]);
      }
    }
    for (; s < ms; ++s) {
      int sn = __builtin_amdgcn_readlane(me, s);
      float sv = s1[sn * 8 + hf];
      f16x8 row = *(const f16x8*)(xlh + (size_t)sn * 512 + lane * 8);
      float w = __expf(lrelu(sv + dnw));
      den += w;
#pragma unroll
      for (int j = 0; j < 8; j++) acc[j] = fmaf(w, (float)row[j], acc[j]);
    }
  }
  const float rh = 1.f / (den + 1e-16f);
  float4 bv0 = *(const float4*)(b1 + lane * 8);
  float4 bv1 = *(const float4*)(b1 + lane * 8 + 4);
  float bb[8] = {bv0.x, bv0.y, bv0.z, bv0.w, bv1.x, bv1.y, bv1.z, bv1.w};
  float4 wsa = *(const float4*)(ws2 + lane * 8);
  float4 wsb = *(const float4*)(ws2 + lane * 8 + 4);
  float4 wda = *(const float4*)(wd2 + lane * 8);
  float4 wdb = *(const float4*)(wd2 + lane * 8 + 4);
  float wsv[8] = {wsa.x, wsa.y, wsa.z, wsa.w, wsb.x, wsb.y, wsb.z, wsb.w};
  float wdv[8] = {wda.x, wda.y, wda.z, wda.w, wdb.x, wdb.y, wdb.z, wdb.w};
  f16x8 o;
  float ps = 0.f, pd = 0.f;
#pragma unroll
  for (int j = 0; j < 8; j++) {
    float v = acc[j] * rh + bb[j];
    v = v > 0.f ? v : (__expf(v) - 1.f);
    o[j] = (f16)v;
    ps = fmaf(v, wsv[j], ps);
    pd = fmaf(v, wdv[j], pd);
  }
  *(f16x8*)(x1h + (size_t)n * 512 + lane * 8) = o;
#pragma unroll
  for (int off = 32; off > 0; off >>= 1) {
    ps += __shfl_xor(ps, off);
    pd += __shfl_xor(pd, off);
  }
  if (lane == 0) { s2[n] = ps; d2[n] = pd; }
}

// ------------- GAT layer 2 gather: WAVE-per-node, no LDS, no barriers ----------------
__global__ __launch_bounds__(256) void gat_gather2(
    const int* __restrict__ snA, const int* __restrict__ offA,
    const float* __restrict__ s2, const float* __restrict__ d2,
    const f16* __restrict__ zh, const f16* __restrict__ Ph,
    f16* __restrict__ h2h)
{
  const int t = threadIdx.x;
  const int wave = t >> 6, lane = t & 63;
  const int n = blockIdx.x * 4 + wave;             // 20000 = 5000*4 exact
  const float dn = d2[n];
  const int beg = offA[n], deg = offA[n + 1] - beg;
  float acc[8] = {0.f};
  float den = 0.f;
  for (int base = 0; base < deg; base += 64) {
    const int m = min(64, deg - base);
    int me = 0;
    if (lane < m) me = snA[beg + base + lane];
    const int ms = __builtin_amdgcn_readfirstlane(m);
    int s = 0;
    for (; s + 4 <= ms; s += 4) {
      int sn[4]; float sv[4]; f16x8 row[4];
#pragma unroll
      for (int u = 0; u < 4; u++) sn[u] = __builtin_amdgcn_readlane(me, s + u);
#pragma unroll
      for (int u = 0; u < 4; u++) sv[u] = s2[sn[u]];
#pragma unroll
      for (int u = 0; u < 4; u++) row[u] = *(const f16x8*)(zh + (size_t)sn[u] * 512 + lane * 8);
#pragma unroll
      for (int u = 0; u < 4; u++) {
        float w = __expf(lrelu(sv[u] + dn));
        den += w;
#pragma unroll
        for (int j = 0; j < 8; j++) acc[j] = fmaf(w, (float)row[u][j], acc[j]);
      }
    }
    for (; s < ms; ++s) {
      int sn = __builtin_amdgcn_readlane(me, s);
      float sv = s2[sn];
      f16x8 row = *(const f16x8*)(zh + (size_t)sn * 512 + lane * 8);
      float w = __expf(lrelu(sv + dn));
      den += w;
#pragma unroll
      for (int j = 0; j < 8; j++) acc[j] = fmaf(w, (float)row[j], acc[j]);
    }
  }
  const float rn = 1.f / (den + 1e-16f);
  f16x8 pv = *(const f16x8*)(Ph + (size_t)n * 512 + lane * 8);
  f16x8 o;
#pragma unroll
  for (int j = 0; j < 8; j++) {
    float v = fmaxf(acc[j] * rn + (float)pv[j], 0.f);
    o[j] = (f16)v;
  }
  *(f16x8*)(h2h + (size_t)n * 512 + lane * 8) = o;
}

extern "C" void kernel_launch(void* const* d_in, const int* in_sizes, int n_in,
                              void* d_out, int out_size, void* d_ws, size_t ws_size,
                              hipStream_t stream) {
  const int*   edge_index = (const int*)d_in[0];
  const float* synapse    = (const float*)d_in[2];
  const float* x_param = (const float*)d_in[5];
  const float* W1      = (const float*)d_in[6];
  const float* as1     = (const float*)d_in[7];
  const float* ad1     = (const float*)d_in[8];
  const float* b1      = (const float*)d_in[9];
  const float* W2      = (const float*)d_in[10];
  const float* as2     = (const float*)d_in[11];
  const float* ad2     = (const float*)d_in[12];
  const float* b2      = (const float*)d_in[13];
  const float* We1     = (const float*)d_in[14];
  const float* be1     = (const float*)d_in[15];
  const float* We2     = (const float*)d_in[16];
  const float* be2     = (const float*)d_in[17];
  const float* Wc1     = (const float*)d_in[18];
  const float* bc1     = (const float*)d_in[19];
  const float* Wc2     = (const float*)d_in[20];
  const float* bc2     = (const float*)d_in[21];
  float* out_p = (float*)d_out;

  // ---- workspace layout (~125 MB) ----
  char* p = (char*)d_ws;
  float* xp    = (float*)p; p += (size_t)NE * 6 * 4;
  float* s1    = (float*)p; p += (size_t)NN * 8 * 4;
  float* d1    = (float*)p; p += (size_t)NN * 8 * 4;
  float* s2    = (float*)p; p += (size_t)NN * 4;
  float* d2    = (float*)p; p += (size_t)NN * 4;
  float* vB    = (float*)p; p += 512 * 4;
  float* vL    = (float*)p; p += 512 * 4;
  float* vR    = (float*)p; p += 512 * 4;
  float* ws2   = (float*)p; p += 512 * 4;
  float* wd2   = (float*)p; p += 512 * 4;
  f16* xph     = (f16*)p; p += (size_t)NN * FEAT * 2;
  f16* xl1h    = (f16*)p; p += (size_t)NN * 512 * 2;
  f16* x1h     = (f16*)p; p += (size_t)NN * 512 * 2;
  f16* zh      = (f16*)p; p += (size_t)NN * 512 * 2;
  f16* h2h     = (f16*)p; p += (size_t)NN * 512 * 2;
  f16* Phb     = (f16*)p; p += (size_t)NN * 512 * 2;
  f16* hlrh    = (f16*)p; p += (size_t)2 * NN * 256 * 2;
  f16* W1t     = (f16*)p; p += (size_t)512 * FEAT * 2;
  f16* WzAt    = (f16*)p; p += (size_t)512 * 512 * 2;
  f16* McatT   = (f16*)p; p += (size_t)512 * 512 * 2;
  f16* Wc2t    = (f16*)p; p += (size_t)133 * 512 * 2;
  int* degL    = (int*)p;                 // N  (zero group start)
  int* degR    = degL + NN;               // N
  int* curL    = degR + NN;               // N
  int* curR    = curL + NN;               // N  (zero group: 4N ints)
  int* offL    = curR + NN;               // N+1
  int* offR    = offL + NN + 1;           // N+1
  int* offA    = offR + NN + 1;           // N+1
  int* edgeL   = offA + NN + 1;           // E
  int* edgeR   = edgeL + NE;              // E
  int* snA     = edgeR + NE;              // EE

  hipMemsetAsync(degL, 0, (size_t)4 * NN * sizeof(int), stream);

  preamble<<<QB5, 256, 0, stream>>>(
      edge_index, synapse, W1, x_param, W2, We2, Wc1, Wc2, b2, be2, as2, ad2,
      degL, degR, xp, W1t, xph, WzAt, McatT, Wc2t, vB, vL, vR, ws2, wd2);
  scan_csr<<<2, 1024, 0, stream>>>(degL, degR, offL, offR, offA);
  fill_csr<<<(EE + 255) / 256, 256, 0, stream>>>(edge_index, offL, offR, offA,
                                                 curL, curR, edgeL, edgeR, snA);
  fused1<<<1252 + 2500, 256, 0, stream>>>(xph, W1t, xl1h, xp, We1, be1,
                                          offL, edgeL, offR, edgeR, hlrh,
                                          as1, ad1, s1, d1);
  gat_gather1<<<5000, 256, 0, stream>>>(snA, offA, s1, d1, xl1h, b1, ws2, wd2,
                                        x1h, s2, d2);
  fused2<<<1256, 256, 0, stream>>>(x1h, WzAt, zh, hlrh, McatT,
                                   degL, degR, bc1, vB, vL, vR, Phb);
  gat_gather2<<<5000, 256, 0, stream>>>(snA, offA, s2, d2, zh, Phb, h2h);
  mfma_out<<<dim3(2, 313), 256, 0, stream>>>(h2h, Wc2t, bc2, out_p, NN);
}

// Round 15
// 395.090 us; speedup vs baseline: 1.0755x; 1.0046x over previous
//
#include <hip/hip_runtime.h>
#include <cstddef>

// Problem constants (fixed by setup_inputs)
#define NN   20000     // nodes
#define FEAT 128
#define NH   8         // heads layer 1
#define NE   200000    // edges
#define EE   220000    // edges + self loops

typedef _Float16 f16;
typedef _Float16 f16x2 __attribute__((ext_vector_type(2)));
typedef _Float16 f16x4 __attribute__((ext_vector_type(4)));
typedef _Float16 f16x8 __attribute__((ext_vector_type(8)));
typedef float    f32x4 __attribute__((ext_vector_type(4)));

__device__ __forceinline__ float lrelu(float a) { return a > 0.f ? a : 0.2f * a; }
__device__ __forceinline__ float rdlane(float v, int l) {
  return __int_as_float(__builtin_amdgcn_readlane(__float_as_int(v), l));
}
// async global->LDS, 16B per lane; LDS dest = wave-uniform base + lane*16
__device__ __forceinline__ void gld_lds16(const f16* g, f16* l) {
  __builtin_amdgcn_global_load_lds(
      (const __attribute__((address_space(1))) void*)g,
      (__attribute__((address_space(3))) void*)l, 16, 0, 0);
}

// ================= preamble: ALL input-only precompute in one launch =================
// Ordered longest-latency-first so small late sections hide under the bulk:
// [0,QB0) gemm3in1 | [QB0,QB1) small_vec | [QB1,QB2) Wc2t | [QB2,QB3) W1t |
// [QB3,QB4) maxpool+count_deg (fused edge pass) | [QB4,QB5) xph cvt x8
#define QB0 128
#define QB1 (QB0 + 8)
#define QB2 (QB1 + 80)
#define QB3 (QB2 + 64)
#define QB4 (QB3 + 782)
#define QB5 (QB4 + 1250)
__global__ __launch_bounds__(256) void preamble(
    const int* __restrict__ ei, const float* __restrict__ syn,
    const float* __restrict__ W1, const float* __restrict__ xparam,
    const float* __restrict__ W2, const float* __restrict__ We2,
    const float* __restrict__ Wc1, const float* __restrict__ Wc2,
    const float* __restrict__ b2, const float* __restrict__ be2,
    const float* __restrict__ as2, const float* __restrict__ ad2,
    int* __restrict__ dL, int* __restrict__ dR,
    float* __restrict__ xp, f16* __restrict__ W1t, f16* __restrict__ xph,
    f16* __restrict__ WzAt, f16* __restrict__ McatT, f16* __restrict__ Wc2t,
    float* __restrict__ vB, float* __restrict__ vL, float* __restrict__ vR,
    float* __restrict__ ws2, float* __restrict__ wd2)
{
  __shared__ float smem[2112];
  const int b = blockIdx.x, t = threadIdx.x;
  if (b < QB0) {                                   // ---- gemm3in1 (folded weights) ----
    float (*As)[68] = (float(*)[68])smem;
    float (*Bs)[64] = (float(*)[64])(smem + 16 * 68);
    const int bb = b;
    const float* A; const float* B; f16* dst; int dstOff, m0, n0;
    if (bb < 64)      { A = W2;  B = Wc1;  dst = WzAt;  dstOff = 0;
                        m0 = (bb >> 3) * 64; n0 = (bb & 7) * 64; }
    else if (bb < 96) { int i = bb - 64; A = We2; B = Wc1 + (size_t)512 * 512;
                        dst = McatT; dstOff = 0;
                        m0 = (i >> 3) * 64; n0 = (i & 7) * 64; }
    else              { int i = bb - 96; A = We2; B = Wc1 + (size_t)1024 * 512;
                        dst = McatT; dstOff = 256;
                        m0 = (i >> 3) * 64; n0 = (i & 7) * 64; }
    const int tx = t & 15, ty = t >> 4;
    float acc[4][4] = {{0.f}};
    float pa[4], pb[4];
#pragma unroll
    for (int i = 0; i < 4; i++) {
      int idx = t + i * 256;
      pa[i] = A[(size_t)(m0 + (idx >> 4)) * 512 + (idx & 15)];
      pb[i] = B[(size_t)(idx >> 6) * 512 + n0 + (idx & 63)];
    }
    for (int k0 = 0; k0 < 512; k0 += 16) {
#pragma unroll
      for (int i = 0; i < 4; i++) {
        int idx = t + i * 256;
        As[idx & 15][idx >> 4] = pa[i];
        Bs[idx >> 6][idx & 63] = pb[i];
      }
      __syncthreads();
      if (k0 + 16 < 512) {
        int kn = k0 + 16;
#pragma unroll
        for (int i = 0; i < 4; i++) {
          int idx = t + i * 256;
          pa[i] = A[(size_t)(m0 + (idx >> 4)) * 512 + kn + (idx & 15)];
          pb[i] = B[(size_t)(kn + (idx >> 6)) * 512 + n0 + (idx & 63)];
        }
      }
#pragma unroll
      for (int kk = 0; kk < 16; kk++) {
        float4 a4 = *(const float4*)&As[kk][ty * 4];
        float4 b4 = *(const float4*)&Bs[kk][tx * 4];
        float av[4] = {a4.x, a4.y, a4.z, a4.w};
        float bv[4] = {b4.x, b4.y, b4.z, b4.w};
#pragma unroll
        for (int i = 0; i < 4; i++)
#pragma unroll
          for (int j = 0; j < 4; j++) acc[i][j] = fmaf(av[i], bv[j], acc[i][j]);
      }
      __syncthreads();
    }
#pragma unroll
    for (int i = 0; i < 4; i++)
#pragma unroll
      for (int j = 0; j < 4; j++)
        dst[(size_t)(n0 + tx * 4 + j) * 512 + dstOff + m0 + ty * 4 + i] = (f16)acc[i][j];
  } else if (b < QB1) {                            // ---- small_vec (4 segs) ----
    int g = (b - QB0) * 256 + t;
    int seg = g >> 9, j = g & 511;
    if (seg == 0) {
      float a = 0.f;
      for (int k = 0; k < 512; k++) a = fmaf(b2[k], Wc1[(size_t)k * 512 + j], a);
      vB[j] = a;
    } else if (seg == 1) {
      float a = 0.f;
      for (int k = 0; k < 512; k++) a = fmaf(be2[k], Wc1[(size_t)(512 + k) * 512 + j], a);
      vL[j] = a;
    } else if (seg == 2) {
      float a = 0.f;
      for (int k = 0; k < 512; k++) a = fmaf(be2[k], Wc1[(size_t)(1024 + k) * 512 + j], a);
      vR[j] = a;
    } else {
      float a = 0.f, c2 = 0.f;
      for (int c = 0; c < 512; c++) {
        float w = W2[(size_t)j * 512 + c];
        a = fmaf(w, as2[c], a);
        c2 = fmaf(w, ad2[c], c2);
      }
      ws2[j] = a; wd2[j] = c2;
    }
  } else if (b < QB2) {                            // ---- Wc2 transpose-cvt ----
    float (*tile)[33] = (float(*)[33])smem;
    int i0 = b - QB1;                              // 80 blocks: 5 n-tiles x 16 k-tiles
    const int n0 = (i0 % 5) * 32, k0 = (i0 / 5) * 32;
    const int tx = t & 31, ty = t >> 5;
#pragma unroll
    for (int i = 0; i < 4; i++) {
      int k = k0 + ty + i * 8, n = n0 + tx;
      tile[ty + i * 8][tx] = (n < 133) ? Wc2[(size_t)k * 133 + n] : 0.f;
    }
    __syncthreads();
#pragma unroll
    for (int i = 0; i < 4; i++) {
      int n = n0 + ty + i * 8, k = k0 + tx;
      if (n < 133) Wc2t[(size_t)n * 512 + k] = (f16)tile[tx][ty + i * 8];
    }
  } else if (b < QB3) {                            // ---- W1 transpose-cvt ----
    float (*tile)[33] = (float(*)[33])smem;
    int bb = b - QB2;
    const int n0 = (bb & 15) * 32, k0 = (bb >> 4) * 32;
    const int tx = t & 31, ty = t >> 5;
#pragma unroll
    for (int i = 0; i < 4; i++)
      tile[ty + i * 8][tx] = W1[(size_t)(k0 + ty + i * 8) * 512 + n0 + tx];
    __syncthreads();
#pragma unroll
    for (int i = 0; i < 4; i++)
      W1t[(size_t)(n0 + ty + i * 8) * 128 + k0 + tx] = (f16)tile[tx][ty + i * 8];
  } else if (b < QB4) {                            // ---- maxpool + count_deg fused ----
    int e = (b - QB3) * 256 + t;
    if (e >= NE) return;
    const float* p = syn + (size_t)e * 24;
    float v[24];
#pragma unroll
    for (int i = 0; i < 6; i++) {
      float4 q = *(const float4*)(p + i * 4);
      v[i*4+0] = q.x; v[i*4+1] = q.y; v[i*4+2] = q.z; v[i*4+3] = q.w;
    }
#pragma unroll
    for (int dd = 0; dd < 6; dd++)
      xp[(size_t)e * 6 + dd] = fmaxf(fmaxf(v[dd], v[6 + dd]), fmaxf(v[12 + dd], v[18 + dd]));
    atomicAdd(&dL[ei[e]], 1);
    atomicAdd(&dR[ei[NE + e]], 1);
  } else {                                         // ---- xph cvt, 8 elem/thread ----
    int idx = ((b - QB4) * 256 + t) * 8;           // NN*FEAT = 2,560,000 = 1250*2048
    float4 q0 = *(const float4*)(xparam + idx);
    float4 q1 = *(const float4*)(xparam + idx + 4);
    f16x8 o;
    o[0] = (f16)q0.x; o[1] = (f16)q0.y; o[2] = (f16)q0.z; o[3] = (f16)q0.w;
    o[4] = (f16)q1.x; o[5] = (f16)q1.y; o[6] = (f16)q1.z; o[7] = (f16)q1.w;
    *(f16x8*)(xph + idx) = o;
  }
}

// ================= fused1: xl1 MFMA-GEMM + FUSED attn dots + h1 packed gather ========
// GEMM epilogue computes s1/d1 from the f32 accumulators (each block's 128-col
// tile spans exactly 2 heads). Gather branch uses PACKED f16 math: weights and
// bias as f16x2 pairs, edge features packed to 3 u32 at load (3 readlanes),
// matvec = 12 v_pk_fma_f16, relu+acc packed.
__global__ __launch_bounds__(256) void fused1(
    const f16* __restrict__ xph, const f16* __restrict__ W1t, f16* __restrict__ xl1h,
    const float* __restrict__ xp, const float* __restrict__ We1,
    const float* __restrict__ be1,
    const int* __restrict__ oL, const int* __restrict__ eL,
    const int* __restrict__ oR, const int* __restrict__ eR,
    f16* __restrict__ hlrh,
    const float* __restrict__ as1, const float* __restrict__ ad1,
    float* __restrict__ s1, float* __restrict__ d1)
{
  __shared__ __align__(16) f16 smem[7680];
  const int t = threadIdx.x;
  if (blockIdx.x < 1252) {
    f16 (*As)[40] = (f16(*)[40])smem;
    f16 (*Bs)[40] = (f16(*)[40])(smem + 64 * 40);
    const int wave = t >> 6, lane = t & 63;
    const int quad = lane >> 4, mrow = lane & 15;
    const int m0 = (blockIdx.x >> 2) * 64, n0 = (blockIdx.x & 3) * 128;
    f32x4 acc[4][2];
    f32x4 zero4 = {0.f, 0.f, 0.f, 0.f};
#pragma unroll
    for (int i = 0; i < 4; i++)
#pragma unroll
      for (int j = 0; j < 2; j++) acc[i][j] = zero4;
    const int ar = t >> 2, ac = (t & 3) * 8;
    for (int k0 = 0; k0 < FEAT; k0 += 32) {
      {
        int gm = m0 + ar;
        f16x8 v = {0, 0, 0, 0, 0, 0, 0, 0};
        if (gm < NN) v = *(const f16x8*)(xph + (size_t)gm * FEAT + k0 + ac);
        *(f16x8*)&As[ar][ac] = v;
      }
#pragma unroll
      for (int i = 0; i < 2; i++) {
        int idx = t + i * 256;
        int r = idx >> 2, c = (idx & 3) * 8;
        *(f16x8*)&Bs[r][c] = *(const f16x8*)(W1t + (size_t)(n0 + r) * FEAT + k0 + c);
      }
      __syncthreads();
      f16x8 af[4], bf[2];
#pragma unroll
      for (int mt = 0; mt < 4; mt++) af[mt] = *(const f16x8*)&As[mt * 16 + mrow][quad * 8];
#pragma unroll
      for (int nt = 0; nt < 2; nt++) bf[nt] = *(const f16x8*)&Bs[wave * 32 + nt * 16 + mrow][quad * 8];
#pragma unroll
      for (int mt = 0; mt < 4; mt++)
#pragma unroll
        for (int nt = 0; nt < 2; nt++)
          acc[mt][nt] = __builtin_amdgcn_mfma_f32_16x16x32_f16(af[mt], bf[nt], acc[mt][nt], 0, 0, 0);
      __syncthreads();
    }
#pragma unroll
    for (int mt = 0; mt < 4; mt++)
#pragma unroll
      for (int nt = 0; nt < 2; nt++) {
        int col = n0 + wave * 32 + nt * 16 + mrow;
#pragma unroll
        for (int reg = 0; reg < 4; reg++) {
          int row = m0 + mt * 16 + quad * 4 + reg;
          if (row < NN) xl1h[(size_t)row * 512 + col] = (f16)acc[mt][nt][reg];
        }
      }
    // ---- fused attn dots: s1/d1 for this block's 64 rows x 2 heads ----
    const int h = (n0 >> 6) + (wave >> 1);           // heads n0/64, n0/64+1
    float a1v[2], a2v[2];
#pragma unroll
    for (int nt = 0; nt < 2; nt++) {
      int cw = ((wave & 1) << 5) + nt * 16 + mrow;   // col within head [0,64)
      a1v[nt] = as1[h * 64 + cw];
      a2v[nt] = ad1[h * 64 + cw];
    }
    float myS[16], myD[16];
#pragma unroll
    for (int mt = 0; mt < 4; mt++)
#pragma unroll
      for (int reg = 0; reg < 4; reg++) {
        float ps = acc[mt][0][reg] * a1v[0] + acc[mt][1][reg] * a1v[1];
        float pd = acc[mt][0][reg] * a2v[0] + acc[mt][1][reg] * a2v[1];
        ps += __shfl_xor(ps, 1);  pd += __shfl_xor(pd, 1);
        ps += __shfl_xor(ps, 2);  pd += __shfl_xor(pd, 2);
        ps += __shfl_xor(ps, 4);  pd += __shfl_xor(pd, 4);
        ps += __shfl_xor(ps, 8);  pd += __shfl_xor(pd, 8);
        myS[mt * 4 + reg] = ps;   myD[mt * 4 + reg] = pd;
      }
    float* sred = (float*)smem;                      // reuse LDS (post-K-loop barrier)
    float* dred = sred + 128;                        // [2 heads][64 rows] each
    __syncthreads();
    if ((wave & 1) == 0 && mrow == 0) {
#pragma unroll
      for (int mt = 0; mt < 4; mt++)
#pragma unroll
        for (int reg = 0; reg < 4; reg++) {
          int rr = mt * 16 + quad * 4 + reg;
          sred[(wave >> 1) * 64 + rr] = myS[mt * 4 + reg];
          dred[(wave >> 1) * 64 + rr] = myD[mt * 4 + reg];
        }
    }
    __syncthreads();
    if ((wave & 1) == 1 && mrow == 0) {
#pragma unroll
      for (int mt = 0; mt < 4; mt++)
#pragma unroll
        for (int reg = 0; reg < 4; reg++) {
          int rr = mt * 16 + quad * 4 + reg;
          int row = m0 + rr;
          if (row < NN) {
            s1[row * 8 + h] = myS[mt * 4 + reg] + sred[(wave >> 1) * 64 + rr];
            d1[row * 8 + h] = myD[mt * 4 + reg] + dred[(wave >> 1) * 64 + rr];
          }
        }
    }
  } else {
    // ---- h1 mean-gather: packed-f16 readlane broadcast, 4 node-sides per wave ----
    const int wave = t >> 6, lane = t & 63;
    const int w = (blockIdx.x - 1252) * 4 + wave;        // 0..9999
    f16x2 wp[6][2];
    f16x2 bp[2];
#pragma unroll
    for (int j = 0; j < 6; j++) {
      float4 wj = *(const float4*)(We1 + j * 256 + 4 * lane);
      wp[j][0][0] = (f16)wj.x; wp[j][0][1] = (f16)wj.y;
      wp[j][1][0] = (f16)wj.z; wp[j][1][1] = (f16)wj.w;
    }
    {
      float4 bq = *(const float4*)(be1 + 4 * lane);
      bp[0][0] = (f16)bq.x; bp[0][1] = (f16)bq.y;
      bp[1][0] = (f16)bq.z; bp[1][1] = (f16)bq.w;
    }
    const f16 zf = (f16)0.f;
#pragma unroll 1
    for (int i = 0; i < 4; i++) {
      const int b = w + i * 10000;                       // node-side in [0, 2*NN)
      const int* off; const int* lst; int n;
      if (b < NN) { off = oL; lst = eL; n = b; } else { off = oR; lst = eR; n = b - NN; }
      const int beg = off[n], deg = off[n + 1] - beg;
      f16x2 a0; a0[0] = zf; a0[1] = zf;
      f16x2 a1; a1[0] = zf; a1[1] = zf;
      for (int base = 0; base < deg; base += 32) {
        const int m = min(32, deg - base);
        int pk0 = 0, pk1 = 0, pk2 = 0;
        if (lane < m) {
          const int e = lst[beg + base + lane];
          const float* pr = xp + (size_t)e * 6;
          float2 p0 = *(const float2*)pr;
          float2 p1 = *(const float2*)(pr + 2);
          float2 p2 = *(const float2*)(pr + 4);
          f16x2 t0; t0[0] = (f16)p0.x; t0[1] = (f16)p0.y; pk0 = *(int*)&t0;
          f16x2 t1; t1[0] = (f16)p1.x; t1[1] = (f16)p1.y; pk1 = *(int*)&t1;
          f16x2 t2; t2[0] = (f16)p2.x; t2[1] = (f16)p2.y; pk2 = *(int*)&t2;
        }
        const int ms = __builtin_amdgcn_readfirstlane(m);
        for (int s = 0; s < ms; ++s) {
          int q0 = __builtin_amdgcn_readlane(pk0, s);
          int q1 = __builtin_amdgcn_readlane(pk1, s);
          int q2 = __builtin_amdgcn_readlane(pk2, s);
          f16x2 x01 = *(f16x2*)&q0, x23 = *(f16x2*)&q1, x45 = *(f16x2*)&q2;
          f16x2 s0; s0[0] = x01[0]; s0[1] = x01[0];
          f16x2 s1v; s1v[0] = x01[1]; s1v[1] = x01[1];
          f16x2 s2; s2[0] = x23[0]; s2[1] = x23[0];
          f16x2 s3; s3[0] = x23[1]; s3[1] = x23[1];
          f16x2 s4; s4[0] = x45[0]; s4[1] = x45[0];
          f16x2 s5; s5[0] = x45[1]; s5[1] = x45[1];
          f16x2 v0 = bp[0], v1 = bp[1];
          v0 = s0 * wp[0][0] + v0;  v1 = s0 * wp[0][1] + v1;
          v0 = s1v * wp[1][0] + v0; v1 = s1v * wp[1][1] + v1;
          v0 = s2 * wp[2][0] + v0;  v1 = s2 * wp[2][1] + v1;
          v0 = s3 * wp[3][0] + v0;  v1 = s3 * wp[3][1] + v1;
          v0 = s4 * wp[4][0] + v0;  v1 = s4 * wp[4][1] + v1;
          v0 = s5 * wp[5][0] + v0;  v1 = s5 * wp[5][1] + v1;
          f16x2 r0, r1;
          r0[0] = v0[0] > zf ? v0[0] : zf; r0[1] = v0[1] > zf ? v0[1] : zf;
          r1[0] = v1[0] > zf ? v1[0] : zf; r1[1] = v1[1] > zf ? v1[1] : zf;
          a0 = a0 + r0;
          a1 = a1 + r1;
        }
      }
      const float rn = deg > 0 ? 1.f / (float)deg : 0.f;
      f16x4 o;
      o[0] = (f16)((float)a0[0] * rn); o[1] = (f16)((float)a0[1] * rn);
      o[2] = (f16)((float)a1[0] * rn); o[3] = (f16)((float)a1[1] * rn);
      *(f16x4*)(hlrh + (size_t)b * 256 + 4 * lane) = o;
    }
  }
}

// ================= fused2: z-GEMM + class_pre, BK=64 + st-swizzle (R9 best) =========
// 128x128 tile, BK=64 (8 K-steps), 32KB linear LDS staged via global_load_lds
// width=16, 2 barriers per K-step; source/read XOR swizzle (bank-conflict 0).
// NOTE: pipelining variants (dbuf __syncthreads, counted vmcnt+raw barrier) all
// REGRESSED vs this plain loop -- matches guide m131-m140; do not re-attempt.
__global__ __launch_bounds__(256) void fused2(
    const f16* __restrict__ x1h, const f16* __restrict__ WzAt, f16* __restrict__ zh,
    const f16* __restrict__ hlrh, const f16* __restrict__ McatT,
    const int* __restrict__ degL, const int* __restrict__ degR,
    const float* __restrict__ bc1, const float* __restrict__ vB,
    const float* __restrict__ vL, const float* __restrict__ vR, f16* __restrict__ Ph)
{
  __shared__ __align__(16) f16 smem[16384];        // As 8192 f16 | Bs 8192 f16
  const int t = threadIdx.x;
  const int logical = (blockIdx.x & 7) * 157 + (blockIdx.x >> 3);
  const bool isZ = logical < 628;
  const int bb = isZ ? logical : logical - 628;
  const int wave = t >> 6, lane = t & 63;
  const int wr = wave >> 1, wc = wave & 1;
  const int quad = lane >> 4, mrow = lane & 15;
  const int m0 = (bb >> 2) * 128, n0 = (bb & 3) * 128;
  const f16* Bt = isZ ? WzAt : McatT;
  const int srow = wave * 8 + (lane >> 3);           // 0..31 within issue block
  const int cs = (lane & 7) ^ ((lane >> 3) & 7);     // swizzled source chunk
  f16* ldsA = smem + wave * 512;                     // + i*2048 per issue
  f16* ldsB = smem + 8192 + wave * 512;
  const int mswz = mrow & 7;                         // read-side XOR key

  f32x4 acc[4][4];
  f32x4 zero4 = {0.f, 0.f, 0.f, 0.f};
#pragma unroll
  for (int i = 0; i < 4; i++)
#pragma unroll
    for (int j = 0; j < 4; j++) acc[i][j] = zero4;

#pragma unroll 1
  for (int it = 0; it < 8; ++it) {
    const int k0 = it * 64;
#pragma unroll
    for (int i = 0; i < 4; i++) {
      const int garow = m0 + i * 32 + srow;
      const f16* gA;
      if (isZ) {
        gA = x1h + (size_t)garow * 512 + k0 + cs * 8;
      } else {
        const int roff = (k0 >> 8) ? NN : 0;         // K half selects L/R hlrh bank
        gA = hlrh + (size_t)(garow + roff) * 256 + (k0 & 255) + cs * 8;
      }
      gld_lds16(gA, ldsA + i * 2048);
      const f16* gB = Bt + (size_t)(n0 + i * 32 + srow) * 512 + k0 + cs * 8;
      gld_lds16(gB, ldsB + i * 2048);
    }
    __syncthreads();
#pragma unroll
    for (int ksub = 0; ksub < 2; ++ksub) {
      f16x8 af[4], bf[4];
#pragma unroll
      for (int mt = 0; mt < 4; mt++)
        af[mt] = *(const f16x8*)(smem + (wr * 64 + mt * 16 + mrow) * 64 +
                                 ((ksub * 4 + quad) ^ mswz) * 8);
#pragma unroll
      for (int nt = 0; nt < 4; nt++)
        bf[nt] = *(const f16x8*)(smem + 8192 + (wc * 64 + nt * 16 + mrow) * 64 +
                                 ((ksub * 4 + quad) ^ mswz) * 8);
#pragma unroll
      for (int mt = 0; mt < 4; mt++)
#pragma unroll
        for (int nt = 0; nt < 4; nt++)
          acc[mt][nt] = __builtin_amdgcn_mfma_f32_16x16x32_f16(af[mt], bf[nt], acc[mt][nt], 0, 0, 0);
    }
    __syncthreads();
  }
  if (isZ) {
#pragma unroll
    for (int mt = 0; mt < 4; mt++)
#pragma unroll
      for (int nt = 0; nt < 4; nt++) {
        int col = n0 + wc * 64 + nt * 16 + mrow;
#pragma unroll
        for (int reg = 0; reg < 4; reg++) {
          int row = m0 + wr * 64 + mt * 16 + quad * 4 + reg;
          if (row < NN) zh[(size_t)row * 512 + col] = (f16)acc[mt][nt][reg];
        }
      }
  } else {
#pragma unroll
    for (int mt = 0; mt < 4; mt++)
#pragma unroll
      for (int nt = 0; nt < 4; nt++) {
        int col = n0 + wc * 64 + nt * 16 + mrow;
        float bb2 = bc1[col] + vB[col];
        float vl = vL[col], vr = vR[col];
#pragma unroll
        for (int reg = 0; reg < 4; reg++) {
          int row = m0 + wr * 64 + mt * 16 + quad * 4 + reg;
          if (row >= NN) continue;
          float v = acc[mt][nt][reg] + bb2;
          if (degL[row] > 0) v += vl;
          if (degR[row] > 0) v += vr;
          Ph[(size_t)row * 512 + col] = (f16)v;
        }
      }
  }
}

// ---------------- MFMA output GEMM: out(f32)[M,133] = h2h @ Wc2t^T + bc2 -------------
// N=133: the n0=128 column-block has only 5 valid cols (1 live fragment of 8).
// Wave-uniform liveness guards skip the dead af/bf ds_reads and MFMAs there
// (block 0 unchanged: all fragments live). Staging of A unchanged (shared).
__global__ __launch_bounds__(256) void mfma_out(
    const f16* __restrict__ A, const f16* __restrict__ Bt,
    const float* __restrict__ bias, float* __restrict__ C, int M)
{
  __shared__ __align__(16) f16 As[64][40];
  __shared__ __align__(16) f16 Bs[128][40];
  const int t = threadIdx.x;
  const int wave = t >> 6, lane = t & 63;
  const int quad = lane >> 4, mrow = lane & 15;
  const int m0 = blockIdx.y * 64, n0 = blockIdx.x * 128;
  const bool live0 = (n0 + wave * 32) < 133;        // nt=0 fragment live
  const bool live1 = (n0 + wave * 32 + 16) < 133;   // nt=1 fragment live
  f32x4 acc[4][2];
  f32x4 zero4 = {0.f, 0.f, 0.f, 0.f};
#pragma unroll
  for (int i = 0; i < 4; i++)
#pragma unroll
    for (int j = 0; j < 2; j++) acc[i][j] = zero4;
  const int ar = t >> 2, ac = (t & 3) * 8;
  for (int k0 = 0; k0 < 512; k0 += 32) {
    {
      int gm = m0 + ar;
      f16x8 v = {0, 0, 0, 0, 0, 0, 0, 0};
      if (gm < M) v = *(const f16x8*)(A + (size_t)gm * 512 + k0 + ac);
      *(f16x8*)&As[ar][ac] = v;
    }
#pragma unroll
    for (int i = 0; i < 2; i++) {
      int idx = t + i * 256;
      int r = idx >> 2, c = (idx & 3) * 8;
      f16x8 v = {0, 0, 0, 0, 0, 0, 0, 0};
      if (n0 + r < 133) v = *(const f16x8*)(Bt + (size_t)(n0 + r) * 512 + k0 + c);
      *(f16x8*)&Bs[r][c] = v;
    }
    __syncthreads();
    if (live0) {
      f16x8 af[4], bf[2];
#pragma unroll
      for (int mt = 0; mt < 4; mt++) af[mt] = *(const f16x8*)&As[mt * 16 + mrow][quad * 8];
      bf[0] = *(const f16x8*)&Bs[wave * 32 + mrow][quad * 8];
#pragma unroll
      for (int mt = 0; mt < 4; mt++)
        acc[mt][0] = __builtin_amdgcn_mfma_f32_16x16x32_f16(af[mt], bf[0], acc[mt][0], 0, 0, 0);
      if (live1) {
        bf[1] = *(const f16x8*)&Bs[wave * 32 + 16 + mrow][quad * 8];
#pragma unroll
        for (int mt = 0; mt < 4; mt++)
          acc[mt][1] = __builtin_amdgcn_mfma_f32_16x16x32_f16(af[mt], bf[1], acc[mt][1], 0, 0, 0);
      }
    }
    __syncthreads();
  }
#pragma unroll
  for (int mt = 0; mt < 4; mt++)
#pragma unroll
    for (int nt = 0; nt < 2; nt++) {
      int col = n0 + wave * 32 + nt * 16 + mrow;
      if (col >= 133) continue;
      float bb = bias[col];
#pragma unroll
      for (int reg = 0; reg < 4; reg++) {
        int row = m0 + mt * 16 + quad * 4 + reg;
        if (row < M) C[(size_t)row * 133 + col] = acc[mt][nt][reg] + bb;
      }
    }
}

// ------------- CSR scan (2 blocks; offA derived as offR + n) -------------------------
__global__ __launch_bounds__(1024) void scan_csr(
    const int* __restrict__ dL, const int* __restrict__ dR,
    int* __restrict__ oL, int* __restrict__ oR, int* __restrict__ oA)
{
  const int b = blockIdx.x;
  const int* deg = b == 0 ? dL : dR;
  __shared__ int part[1024];
  const int t = threadIdx.x;
  const int chunk = 20;
  int base = t * chunk;
  int sum = 0;
  for (int i = 0; i < chunk; i++) { int idx = base + i; if (idx < NN) sum += deg[idx]; }
  part[t] = sum;
  __syncthreads();
  for (int o = 1; o < 1024; o <<= 1) {
    int v = (t >= o) ? part[t - o] : 0;
    __syncthreads();
    part[t] += v;
    __syncthreads();
  }
  int run = part[t] - sum;
  if (b == 0) {
    for (int i = 0; i < chunk; i++) {
      int idx = base + i;
      if (idx < NN) { oL[idx] = run; run += deg[idx]; }
    }
    if (t == 0) oL[NN] = part[1023];
  } else {
    for (int i = 0; i < chunk; i++) {
      int idx = base + i;
      if (idx < NN) { oR[idx] = run; oA[idx] = run + idx; run += deg[idx]; }
    }
    if (t == 0) { oR[NN] = part[1023]; oA[NN] = part[1023] + NN; }
  }
}

// ------------- fill: 2 atomics/edge; self-loops atomic-free (slot 0 of A-segment) ----
__global__ __launch_bounds__(256) void fill_csr(
    const int* __restrict__ ei,
    const int* __restrict__ oL, const int* __restrict__ oR, const int* __restrict__ oA,
    int* __restrict__ cL, int* __restrict__ cR,
    int* __restrict__ eL, int* __restrict__ eR, int* __restrict__ snA)
{
  int e = blockIdx.x * 256 + threadIdx.x;
  if (e >= EE) return;
  if (e < NE) {
    int s = ei[e], d = ei[NE + e];
    int p = atomicAdd(&cL[s], 1); eL[oL[s] + p] = e;
    p = atomicAdd(&cR[d], 1);
    eR[oR[d] + p] = e;
    snA[oA[d] + 1 + p] = s;       // A-segment: [selfloop, dst-edges...]
  } else {
    int n = e - NE;
    snA[oA[n]] = n;
  }
}

// ------------- GAT layer 1 gather: WAVE-per-node, no LDS, no barriers ----------------
__global__ __launch_bounds__(256) void gat_gather1(
    const int* __restrict__ snA, const int* __restrict__ offA,
    const float* __restrict__ s1, const float* __restrict__ d1,
    const f16* __restrict__ xlh, const float* __restrict__ b1,
    const float* __restrict__ ws2, const float* __restrict__ wd2,
    f16* __restrict__ x1h, float* __restrict__ s2, float* __restrict__ d2)
{
  const int t = threadIdx.x;
  const int wave = t >> 6, lane = t & 63;
  const int n = blockIdx.x * 4 + wave;             // 20000 = 5000*4 exact
  const int hf = lane >> 3;
  const float dnw = d1[n * 8 + hf];
  const int beg = offA[n], deg = offA[n + 1] - beg;
  float acc[8] = {0.f};
  float den = 0.f;
  for (int base = 0; base < deg; base += 64) {
    const int m = min(64, deg - base);
    int me = 0;
    if (lane < m) me = snA[beg + base + lane];
    const int ms = __builtin_amdgcn_readfirstlane(m);
    int s = 0;
    for (; s + 4 <= ms; s += 4) {
      int sn[4]; float sv[4]; f16x8 row[4];
#pragma unroll
      for (int u = 0; u < 4; u++) sn[u] = __builtin_amdgcn_readlane(me, s + u);
#pragma unroll
      for (int u = 0; u < 4; u++) sv[u] = s1[sn[u] * 8 + hf];
#pragma unroll
      for (int u = 0; u < 4; u++) row[u] = *(const f16x8*)(xlh + (size_t)sn[u] * 512 + lane * 8);
#pragma unroll
      for (int u = 0; u < 4; u++) {
        float w = __expf(lrelu(sv[u] + dnw));
        den += w;
#pragma unroll
        for (int j = 0; j < 8; j++) acc[j] = fmaf(w, (float)row[u][j], acc[j]);
      }
    }
    for (; s < ms; ++s) {
      int sn = __builtin_amdgcn_readlane(me, s);
      float sv = s1[sn * 8 + hf];
      f16x8 row = *(const f16x8*)(xlh + (size_t)sn * 512 + lane * 8);
      float w = __expf(lrelu(sv + dnw));
      den += w;
#pragma unroll
      for (int j = 0; j < 8; j++) acc[j] = fmaf(w, (float)row[j], acc[j]);
    }
  }
  const float rh = 1.f / (den + 1e-16f);
  float4 bv0 = *(const float4*)(b1 + lane * 8);
  float4 bv1 = *(const float4*)(b1 + lane * 8 + 4);
  float bb[8] = {bv0.x, bv0.y, bv0.z, bv0.w, bv1.x, bv1.y, bv1.z, bv1.w};
  float4 wsa = *(const float4*)(ws2 + lane * 8);
  float4 wsb = *(const float4*)(ws2 + lane * 8 + 4);
  float4 wda = *(const float4*)(wd2 + lane * 8);
  float4 wdb = *(const float4*)(wd2 + lane * 8 + 4);
  float wsv[8] = {wsa.x, wsa.y, wsa.z, wsa.w, wsb.x, wsb.y, wsb.z, wsb.w};
  float wdv[8] = {wda.x, wda.y, wda.z, wda.w, wdb.x, wdb.y, wdb.z, wdb.w};
  f16x8 o;
  float ps = 0.f, pd = 0.f;
#pragma unroll
  for (int j = 0; j < 8; j++) {
    float v = acc[j] * rh + bb[j];
    v = v > 0.f ? v : (__expf(v) - 1.f);
    o[j] = (f16)v;
    ps = fmaf(v, wsv[j], ps);
    pd = fmaf(v, wdv[j], pd);
  }
  *(f16x8*)(x1h + (size_t)n * 512 + lane * 8) = o;
#pragma unroll
  for (int off = 32; off > 0; off >>= 1) {
    ps += __shfl_xor(ps, off);
    pd += __shfl_xor(pd, off);
  }
  if (lane == 0) { s2[n] = ps; d2[n] = pd; }
}

// ------------- GAT layer 2 gather: WAVE-per-node, no LDS, no barriers ----------------
__global__ __launch_bounds__(256) void gat_gather2(
    const int* __restrict__ snA, const int* __restrict__ offA,
    const float* __restrict__ s2, const float* __restrict__ d2,
    const f16* __restrict__ zh, const f16* __restrict__ Ph,
    f16* __restrict__ h2h)
{
  const int t = threadIdx.x;
  const int wave = t >> 6, lane = t & 63;
  const int n = blockIdx.x * 4 + wave;             // 20000 = 5000*4 exact
  const float dn = d2[n];
  const int beg = offA[n], deg = offA[n + 1] - beg;
  float acc[8] = {0.f};
  float den = 0.f;
  for (int base = 0; base < deg; base += 64) {
    const int m = min(64, deg - base);
    int me = 0;
    if (lane < m) me = snA[beg + base + lane];
    const int ms = __builtin_amdgcn_readfirstlane(m);
    int s = 0;
    for (; s + 4 <= ms; s += 4) {
      int sn[4]; float sv[4]; f16x8 row[4];
#pragma unroll
      for (int u = 0; u < 4; u++) sn[u] = __builtin_amdgcn_readlane(me, s + u);
#pragma unroll
      for (int u = 0; u < 4; u++) sv[u] = s2[sn[u]];
#pragma unroll
      for (int u = 0; u < 4; u++) row[u] = *(const f16x8*)(zh + (size_t)sn[u] * 512 + lane * 8);
#pragma unroll
      for (int u = 0; u < 4; u++) {
        float w = __expf(lrelu(sv[u] + dn));
        den += w;
#pragma unroll
        for (int j = 0; j < 8; j++) acc[j] = fmaf(w, (float)row[u][j], acc[j]);
      }
    }
    for (; s < ms; ++s) {
      int sn = __builtin_amdgcn_readlane(me, s);
      float sv = s2[sn];
      f16x8 row = *(const f16x8*)(zh + (size_t)sn * 512 + lane * 8);
      float w = __expf(lrelu(sv + dn));
      den += w;
#pragma unroll
      for (int j = 0; j < 8; j++) acc[j] = fmaf(w, (float)row[j], acc[j]);
    }
  }
  const float rn = 1.f / (den + 1e-16f);
  f16x8 pv = *(const f16x8*)(Ph + (size_t)n * 512 + lane * 8);
  f16x8 o;
#pragma unroll
  for (int j = 0; j < 8; j++) {
    float v = fmaxf(acc[j] * rn + (float)pv[j], 0.f);
    o[j] = (f16)v;
  }
  *(f16x8*)(h2h + (size_t)n * 512 + lane * 8) = o;
}

extern "C" void kernel_launch(void* const* d_in, const int* in_sizes, int n_in,
                              void* d_out, int out_size, void* d_ws, size_t ws_size,
                              hipStream_t stream) {
  const int*   edge_index = (const int*)d_in[0];
  const float* synapse    = (const float*)d_in[2];
  const float* x_param = (const float*)d_in[5];
  const float* W1      = (const float*)d_in[6];
  const float* as1     = (const float*)d_in[7];
  const float* ad1     = (const float*)d_in[8];
  const float* b1      = (const float*)d_in[9];
  const float* W2      = (const float*)d_in[10];
  const float* as2     = (const float*)d_in[11];
  const float* ad2     = (const float*)d_in[12];
  const float* b2      = (const float*)d_in[13];
  const float* We1     = (const float*)d_in[14];
  const float* be1     = (const float*)d_in[15];
  const float* We2     = (const float*)d_in[16];
  const float* be2     = (const float*)d_in[17];
  const float* Wc1     = (const float*)d_in[18];
  const float* bc1     = (const float*)d_in[19];
  const float* Wc2     = (const float*)d_in[20];
  const float* bc2     = (const float*)d_in[21];
  float* out_p = (float*)d_out;

  // ---- workspace layout (~125 MB) ----
  char* p = (char*)d_ws;
  float* xp    = (float*)p; p += (size_t)NE * 6 * 4;
  float* s1    = (float*)p; p += (size_t)NN * 8 * 4;
  float* d1    = (float*)p; p += (size_t)NN * 8 * 4;
  float* s2    = (float*)p; p += (size_t)NN * 4;
  float* d2    = (float*)p; p += (size_t)NN * 4;
  float* vB    = (float*)p; p += 512 * 4;
  float* vL    = (float*)p; p += 512 * 4;
  float* vR    = (float*)p; p += 512 * 4;
  float* ws2   = (float*)p; p += 512 * 4;
  float* wd2   = (float*)p; p += 512 * 4;
  f16* xph     = (f16*)p; p += (size_t)NN * FEAT * 2;
  f16* xl1h    = (f16*)p; p += (size_t)NN * 512 * 2;
  f16* x1h     = (f16*)p; p += (size_t)NN * 512 * 2;
  f16* zh      = (f16*)p; p += (size_t)NN * 512 * 2;
  f16* h2h     = (f16*)p; p += (size_t)NN * 512 * 2;
  f16* Phb     = (f16*)p; p += (size_t)NN * 512 * 2;
  f16* hlrh    = (f16*)p; p += (size_t)2 * NN * 256 * 2;
  f16* W1t     = (f16*)p; p += (size_t)512 * FEAT * 2;
  f16* WzAt    = (f16*)p; p += (size_t)512 * 512 * 2;
  f16* McatT   = (f16*)p; p += (size_t)512 * 512 * 2;
  f16* Wc2t    = (f16*)p; p += (size_t)133 * 512 * 2;
  int* degL    = (int*)p;                 // N  (zero group start)
  int* degR    = degL + NN;               // N
  int* curL    = degR + NN;               // N
  int* curR    = curL + NN;               // N  (zero group: 4N ints)
  int* offL    = curR + NN;               // N+1
  int* offR    = offL + NN + 1;           // N+1
  int* offA    = offR + NN + 1;           // N+1
  int* edgeL   = offA + NN + 1;           // E
  int* edgeR   = edgeL + NE;              // E
  int* snA     = edgeR + NE;              // EE

  hipMemsetAsync(degL, 0, (size_t)4 * NN * sizeof(int), stream);

  preamble<<<QB5, 256, 0, stream>>>(
      edge_index, synapse, W1, x_param, W2, We2, Wc1, Wc2, b2, be2, as2, ad2,
      degL, degR, xp, W1t, xph, WzAt, McatT, Wc2t, vB, vL, vR, ws2, wd2);
  scan_csr<<<2, 1024, 0, stream>>>(degL, degR, offL, offR, offA);
  fill_csr<<<(EE + 255) / 256, 256, 0, stream>>>(edge_index, offL, offR, offA,
                                                 curL, curR, edgeL, edgeR, snA);
  fused1<<<1252 + 2500, 256, 0, stream>>>(xph, W1t, xl1h, xp, We1, be1,
                                          offL, edgeL, offR, edgeR, hlrh,
                                          as1, ad1, s1, d1);
  gat_gather1<<<5000, 256, 0, stream>>>(snA, offA, s1, d1, xl1h, b1, ws2, wd2,
                                        x1h, s2, d2);
  fused2<<<1256, 256, 0, stream>>>(x1h, WzAt, zh, hlrh, McatT,
                                   degL, degR, bc1, vB, vL, vR, Phb);
  gat_gather2<<<5000, 256, 0, stream>>>(snA, offA, s2, d2, zh, Phb, h2h);
  mfma_out<<<dim3(2, 313), 256, 0, stream>>>(h2h, Wc2t, bc2, out_p, NN);
}